// Round 1
// 539.197 us; speedup vs baseline: 1.0987x; 1.0987x over previous
//
#include <hip/hip_runtime.h>
#include <stdint.h>

#define NDIM 1152
#define NEXP 4
#define NHID 768
#define NHEAD 8
#define HDIM 144
#define NB 2
#define NS 1024
#define NSC 128
#define NTOK 2048
#define NCAP 256

typedef _Float16 f16;
typedef _Float16 f16x4 __attribute__((ext_vector_type(4)));
typedef _Float16 f16x8 __attribute__((ext_vector_type(8)));
typedef float f32x4 __attribute__((ext_vector_type(4)));

#define MFMA16(a, b, c) __builtin_amdgcn_mfma_f32_16x16x32_f16(a, b, c, 0, 0, 0)

// ---------------- Threefry2x32 (exact JAX replication) ----------------
__device__ inline uint2 tfry(uint32_t k0, uint32_t k1, uint32_t x0, uint32_t x1) {
  uint32_t k2 = k0 ^ k1 ^ 0x1BD11BDAu;
#define RND(r) { x0 += x1; x1 = (x1 << r) | (x1 >> (32 - r)); x1 ^= x0; }
  x0 += k0; x1 += k1;
  RND(13) RND(15) RND(26) RND(6)
  x0 += k1; x1 += k2 + 1u;
  RND(17) RND(29) RND(16) RND(24)
  x0 += k2; x1 += k0 + 2u;
  RND(13) RND(15) RND(26) RND(6)
  x0 += k0; x1 += k1 + 3u;
  RND(17) RND(29) RND(16) RND(24)
  x0 += k1; x1 += k2 + 4u;
  RND(13) RND(15) RND(26) RND(6)
  x0 += k2; x1 += k0 + 5u;
#undef RND
  return make_uint2(x0, x1);
}

__device__ inline float b2g(uint32_t bits) {
  uint32_t fb = (bits >> 9) | 0x3f800000u;
  float f = __uint_as_float(fb) - 1.0f;
  const float tiny = 1.1754943508222875e-38f;
  float u = f * 1.0f + tiny;
  u = fmaxf(tiny, u);
  return -logf(-logf(u));
}

// ---------------- prep: keys, gumbels, time-logits ----------------
__global__ void k_prep(const float* __restrict__ timep, const float* __restrict__ hlw,
                       const float* __restrict__ hlb,
                       float* __restrict__ g1, float* __restrict__ g2, float* __restrict__ g3,
                       float* __restrict__ tl) {
  int t = threadIdx.x;  // 256
  uint2 k1 = tfry(0u, 42u, 0u, 0u);
  uint2 k2 = tfry(0u, 42u, 0u, 1u);
  uint2 k3 = tfry(0u, 42u, 0u, 2u);
  for (int p = t; p < 4096; p += 256) {
    uint2 o = tfry(k1.x, k1.y, 0u, (uint32_t)p);
    g1[p] = b2g(o.x ^ o.y);
  }
  for (int p = t; p < 8192; p += 256) {
    uint2 o2 = tfry(k2.x, k2.y, 0u, (uint32_t)p);
    g2[p] = b2g(o2.x ^ o2.y);
    uint2 o3 = tfry(k3.x, k3.y, 0u, (uint32_t)p);
    g3[p] = b2g(o3.x ^ o3.y);
  }
  int wv = t >> 6, lane = t & 63;
  {
    int b = wv >> 1, j = wv & 1;
    float s = 0.f;
    for (int k = lane; k < NDIM; k += 64) s += timep[b * NDIM + k] * hlw[j * NDIM + k];
    for (int m = 32; m; m >>= 1) s += __shfl_xor(s, m);
    if (lane == 0) tl[b * 2 + j] = s + hlb[j];
  }
}

// ---------------- generic 4-logit head: out[n,e] = in[n,:]·w[e,:] + b[e] ----------------
__global__ void k_ac_logits(const float* __restrict__ ac, const float* __restrict__ agw,
                            const float* __restrict__ agb, float* __restrict__ al) {
  int wv = threadIdx.x >> 6, lane = threadIdx.x & 63;
  int n = blockIdx.x * 4 + wv;
  float s[NEXP] = {0.f, 0.f, 0.f, 0.f};
  for (int d = lane; d < NDIM; d += 64) {
    float a = ac[(size_t)n * NDIM + d];
#pragma unroll
    for (int e = 0; e < NEXP; ++e) s[e] += a * agw[e * NDIM + d];
  }
#pragma unroll
  for (int e = 0; e < NEXP; ++e)
    for (int m = 32; m; m >>= 1) s[e] += __shfl_xor(s[e], m);
  if (lane == 0) {
#pragma unroll
    for (int e = 0; e < NEXP; ++e) al[n * NEXP + e] = s[e] + agb[e];
  }
}

// ---------------- fp32 -> fp16 convert (plain) ----------------
__global__ void k_cvt(const float* __restrict__ src, f16* __restrict__ dst, int n) {
  int i = (blockIdx.x * 256 + threadIdx.x) * 4;
  if (i + 3 < n) {
    float4 v = *(const float4*)(src + i);
    f16x4 h; h[0] = (f16)v.x; h[1] = (f16)v.y; h[2] = (f16)v.z; h[3] = (f16)v.w;
    *(f16x4*)(dst + i) = h;
  }
}

// ---------------- fp32 -> fp16 hi/lo split convert (lo pre-scaled by 2048) ----------------
__global__ void k_cvt_split(const float* __restrict__ src, f16* __restrict__ hi,
                            f16* __restrict__ lo, int n) {
  int i = (blockIdx.x * 256 + threadIdx.x) * 4;
  if (i + 3 < n) {
    float4 v = *(const float4*)(src + i);
    f16x4 h, l;
    h[0] = (f16)v.x; l[0] = (f16)((v.x - (float)h[0]) * 2048.f);
    h[1] = (f16)v.y; l[1] = (f16)((v.y - (float)h[1]) * 2048.f);
    h[2] = (f16)v.z; l[2] = (f16)((v.z - (float)h[2]) * 2048.f);
    h[3] = (f16)v.w; l[3] = (f16)((v.w - (float)h[3]) * 2048.f);
    *(f16x4*)(hi + i) = h;
    *(f16x4*)(lo + i) = l;
  }
}

// ---------------- QKV projection, split-fp16 (~fp32 accurate) ----------------
// z==2 (V) now emits transposed split-fp16: vT[b][dd (0..1151)][kv (0..127)]
__global__ __launch_bounds__(256) void k_gemm_qkv(
    const f16* __restrict__ xhi, const f16* __restrict__ xlo,
    const f16* __restrict__ caphi, const f16* __restrict__ caplo,
    const float* __restrict__ inw, const float* __restrict__ inb,
    f16* __restrict__ qhi, f16* __restrict__ qlo,
    f16* __restrict__ khi, f16* __restrict__ klo,
    f16* __restrict__ vthi, f16* __restrict__ vtlo) {
  int z = blockIdx.z;
  int M = (z == 0) ? NTOK : NCAP;
  int mt = blockIdx.y, nt = blockIdx.x;
  if (mt * 64 >= M) return;
  const f16* Ah_g = (z == 0) ? xhi : caphi;
  const f16* Al_g = (z == 0) ? xlo : caplo;
  __shared__ f16 Ash[64 * 72];
  __shared__ f16 Asl[64 * 72];
  __shared__ f16 Bsh[64 * 72];
  __shared__ f16 Bsl[64 * 72];
  int t = threadIdx.x;
  int wv = t >> 6, lane = t & 63, m16 = lane & 15, quad = lane >> 4;
  int r0 = t >> 3, ak = (t & 7) * 8;
  size_t a0o = (size_t)(mt * 64 + r0) * NDIM;
  size_t a1o = (size_t)(mt * 64 + r0 + 32) * NDIM;
  f32x4 zf = {0.f, 0.f, 0.f, 0.f};
  f32x4 ah[2][2] = {{zf, zf}, {zf, zf}};
  f32x4 am[2][2] = {{zf, zf}, {zf, zf}};
  for (int kc = 0; kc < NDIM; kc += 64) {
    __syncthreads();
    *(uint4*)&Ash[r0 * 72 + ak] = *(const uint4*)(Ah_g + a0o + kc + ak);
    *(uint4*)&Ash[(r0 + 32) * 72 + ak] = *(const uint4*)(Ah_g + a1o + kc + ak);
    *(uint4*)&Asl[r0 * 72 + ak] = *(const uint4*)(Al_g + a0o + kc + ak);
    *(uint4*)&Asl[(r0 + 32) * 72 + ak] = *(const uint4*)(Al_g + a1o + kc + ak);
#pragma unroll
    for (int uu = 0; uu < 4; ++uu) {
      int u = t + uu * 256;
      int rr = u >> 4, kp = (u & 15) * 4;
      float4 fv = *(const float4*)(inw + (size_t)(z * NDIM + nt * 64 + rr) * NDIM + kc + kp);
      f16x4 hb, lb;
      hb[0] = (f16)fv.x; lb[0] = (f16)((fv.x - (float)hb[0]) * 2048.f);
      hb[1] = (f16)fv.y; lb[1] = (f16)((fv.y - (float)hb[1]) * 2048.f);
      hb[2] = (f16)fv.z; lb[2] = (f16)((fv.z - (float)hb[2]) * 2048.f);
      hb[3] = (f16)fv.w; lb[3] = (f16)((fv.w - (float)hb[3]) * 2048.f);
      *(f16x4*)&Bsh[rr * 72 + kp] = hb;
      *(f16x4*)&Bsl[rr * 72 + kp] = lb;
    }
    __syncthreads();
#pragma unroll
    for (int ks = 0; ks < 2; ++ks) {
      int aoff = ((wv & 1) * 32 + m16) * 72 + ks * 32 + quad * 8;
      int boff = ((wv >> 1) * 32 + m16) * 72 + ks * 32 + quad * 8;
      f16x8 a0h = *(const f16x8*)&Ash[aoff];
      f16x8 a1h = *(const f16x8*)&Ash[aoff + 16 * 72];
      f16x8 a0l = *(const f16x8*)&Asl[aoff];
      f16x8 a1l = *(const f16x8*)&Asl[aoff + 16 * 72];
      f16x8 b0h = *(const f16x8*)&Bsh[boff];
      f16x8 b1h = *(const f16x8*)&Bsh[boff + 16 * 72];
      f16x8 b0l = *(const f16x8*)&Bsl[boff];
      f16x8 b1l = *(const f16x8*)&Bsl[boff + 16 * 72];
      ah[0][0] = MFMA16(a0h, b0h, ah[0][0]);
      ah[0][1] = MFMA16(a0h, b1h, ah[0][1]);
      ah[1][0] = MFMA16(a1h, b0h, ah[1][0]);
      ah[1][1] = MFMA16(a1h, b1h, ah[1][1]);
      am[0][0] = MFMA16(a0h, b0l, am[0][0]);
      am[0][1] = MFMA16(a0h, b1l, am[0][1]);
      am[1][0] = MFMA16(a1h, b0l, am[1][0]);
      am[1][1] = MFMA16(a1h, b1l, am[1][1]);
      am[0][0] = MFMA16(a0l, b0h, am[0][0]);
      am[0][1] = MFMA16(a0l, b1h, am[0][1]);
      am[1][0] = MFMA16(a1l, b0h, am[1][0]);
      am[1][1] = MFMA16(a1l, b1h, am[1][1]);
    }
  }
#pragma unroll
  for (int mi = 0; mi < 2; ++mi)
#pragma unroll
    for (int ni = 0; ni < 2; ++ni)
#pragma unroll
      for (int r = 0; r < 4; ++r) {
        int row = mt * 64 + (wv & 1) * 32 + mi * 16 + quad * 4 + r;
        int col = nt * 64 + (wv >> 1) * 32 + ni * 16 + m16;
        float v = ah[mi][ni][r] + am[mi][ni][r] * (1.f / 2048.f) + inb[z * NDIM + col];
        size_t idx = (size_t)row * NDIM + col;
        if (z == 0) {
          f16 hq = (f16)v;
          qhi[idx] = hq;
          qlo[idx] = (f16)((v - (float)hq) * 2048.f);
        } else if (z == 1) {
          f16 hk = (f16)v;
          khi[idx] = hk;
          klo[idx] = (f16)((v - (float)hk) * 2048.f);
        } else {
          f16 hv = (f16)v;
          int bb = row >> 7, kv = row & 127;
          size_t ti = (size_t)(bb * NDIM + col) * NSC + kv;
          vthi[ti] = hv;
          vtlo[ti] = (f16)((v - (float)hv) * 2048.f);
        }
      }
}

// ---------------- fused attention: QK^T + softmax + PV, split-fp16, writes o hi/lo ----
// grid (mt=16, bh=16), 256 thr. Per block: 64 q-rows x full 128 kv for one (b,h).
__global__ __launch_bounds__(256) void k_attn(
    const f16* __restrict__ qhi, const f16* __restrict__ qlo,
    const f16* __restrict__ khi, const f16* __restrict__ klo,
    const f16* __restrict__ vthi, const f16* __restrict__ vtlo,
    f16* __restrict__ ohi, f16* __restrict__ olo) {
  int mt = blockIdx.x, bh = blockIdx.y;
  int b = bh >> 3, h = bh & 7;
  __shared__ f16 Ah[64 * 160];
  __shared__ f16 Al[64 * 160];
  __shared__ f16 Bh[32 * 160];
  __shared__ f16 Bl[32 * 160];
  __shared__ f16 Ph[64 * 136];
  __shared__ f16 Pl[64 * 136];
  int t = threadIdx.x;
  int wv = t >> 6, lane = t & 63, m16 = lane & 15, quad = lane >> 4;
  // stage Q tile (64 x 144, zero-padded to 160)
  for (int u = t; u < 64 * 20; u += 256) {
    int r = u / 20, kp = (u % 20) * 8;
    uint4 vh = make_uint4(0u, 0u, 0u, 0u), vl = vh;
    if (kp < HDIM) {
      size_t gi = (size_t)(b * NS + mt * 64 + r) * NDIM + h * HDIM + kp;
      vh = *(const uint4*)&qhi[gi];
      vl = *(const uint4*)&qlo[gi];
    }
    *(uint4*)&Ah[r * 160 + kp] = vh;
    *(uint4*)&Al[r * 160 + kp] = vl;
  }
  __syncthreads();
  f16x8 ahf[5], alf[5];
#pragma unroll
  for (int ks = 0; ks < 5; ++ks) {
    int ao = (wv * 16 + m16) * 160 + ks * 32 + quad * 8;
    ahf[ks] = *(const f16x8*)&Ah[ao];
    alf[ks] = *(const f16x8*)&Al[ao];
  }
  f32x4 zf = {0.f, 0.f, 0.f, 0.f};
  f32x4 sh_[4][2], sm_[4][2];
#pragma unroll
  for (int kt = 0; kt < 4; ++kt)
#pragma unroll
    for (int ni = 0; ni < 2; ++ni) { sh_[kt][ni] = zf; sm_[kt][ni] = zf; }
  // ---- QK^T over 4 chunks of 32 kv ----
  for (int kt = 0; kt < 4; ++kt) {
    if (kt) __syncthreads();
    for (int u = t; u < 32 * 20; u += 256) {
      int r = u / 20, kp = (u % 20) * 8;
      uint4 vh = make_uint4(0u, 0u, 0u, 0u), vl = vh;
      if (kp < HDIM) {
        size_t gi = (size_t)(b * NSC + kt * 32 + r) * NDIM + h * HDIM + kp;
        vh = *(const uint4*)&khi[gi];
        vl = *(const uint4*)&klo[gi];
      }
      *(uint4*)&Bh[r * 160 + kp] = vh;
      *(uint4*)&Bl[r * 160 + kp] = vl;
    }
    __syncthreads();
#pragma unroll
    for (int ks = 0; ks < 5; ++ks) {
#pragma unroll
      for (int ni = 0; ni < 2; ++ni) {
        int bo = (ni * 16 + m16) * 160 + ks * 32 + quad * 8;
        f16x8 bhf = *(const f16x8*)&Bh[bo];
        f16x8 blf = *(const f16x8*)&Bl[bo];
        sh_[kt][ni] = MFMA16(ahf[ks], bhf, sh_[kt][ni]);
        sm_[kt][ni] = MFMA16(ahf[ks], blf, sm_[kt][ni]);
        sm_[kt][ni] = MFMA16(alf[ks], bhf, sm_[kt][ni]);
      }
    }
  }
  // ---- softmax in-register: lane holds rows quad*4+r, cols kt*32+ni*16+m16 ----
  float sv[4][2][4];
  float mx[4] = {-1e30f, -1e30f, -1e30f, -1e30f};
#pragma unroll
  for (int kt = 0; kt < 4; ++kt)
#pragma unroll
    for (int ni = 0; ni < 2; ++ni)
#pragma unroll
      for (int r = 0; r < 4; ++r) {
        float s = (sh_[kt][ni][r] + sm_[kt][ni][r] * (1.f / 2048.f)) * (1.f / 12.f);
        sv[kt][ni][r] = s;
        mx[r] = fmaxf(mx[r], s);
      }
#pragma unroll
  for (int r = 0; r < 4; ++r) {
    mx[r] = fmaxf(mx[r], __shfl_xor(mx[r], 1));
    mx[r] = fmaxf(mx[r], __shfl_xor(mx[r], 2));
    mx[r] = fmaxf(mx[r], __shfl_xor(mx[r], 4));
    mx[r] = fmaxf(mx[r], __shfl_xor(mx[r], 8));
  }
  float sum[4] = {0.f, 0.f, 0.f, 0.f};
#pragma unroll
  for (int kt = 0; kt < 4; ++kt)
#pragma unroll
    for (int ni = 0; ni < 2; ++ni)
#pragma unroll
      for (int r = 0; r < 4; ++r) {
        float e = expf(sv[kt][ni][r] - mx[r]);
        sv[kt][ni][r] = e;
        sum[r] += e;
      }
  float inv[4];
#pragma unroll
  for (int r = 0; r < 4; ++r) {
    sum[r] += __shfl_xor(sum[r], 1);
    sum[r] += __shfl_xor(sum[r], 2);
    sum[r] += __shfl_xor(sum[r], 4);
    sum[r] += __shfl_xor(sum[r], 8);
    inv[r] = 1.0f / sum[r];
  }
  // store P hi/lo to LDS (each wave owns its 16 rows; same-wave write->read, no barrier)
#pragma unroll
  for (int kt = 0; kt < 4; ++kt)
#pragma unroll
    for (int ni = 0; ni < 2; ++ni)
#pragma unroll
      for (int r = 0; r < 4; ++r) {
        float p = sv[kt][ni][r] * inv[r];
        int row = wv * 16 + quad * 4 + r;
        int col = kt * 32 + ni * 16 + m16;
        f16 ph = (f16)p;
        Ph[row * 136 + col] = ph;
        Pl[row * 136 + col] = (f16)((p - (float)ph) * 2048.f);
      }
  // ---- PV: o[16 rows x 144] per wave via MFMA, V^T fragments from global ----
  const f16* vbh = vthi + (size_t)(b * NDIM + h * HDIM) * NSC;
  const f16* vbl = vtlo + (size_t)(b * NDIM + h * HDIM) * NSC;
  f32x4 oh_[9], om_[9];
#pragma unroll
  for (int nb = 0; nb < 9; ++nb) { oh_[nb] = zf; om_[nb] = zf; }
#pragma unroll
  for (int ks = 0; ks < 4; ++ks) {
    int po = (wv * 16 + m16) * 136 + ks * 32 + quad * 8;
    f16x8 pah = *(const f16x8*)&Ph[po];
    f16x8 pal = *(const f16x8*)&Pl[po];
#pragma unroll
    for (int nb = 0; nb < 9; ++nb) {
      size_t vo = (size_t)(nb * 16 + m16) * NSC + ks * 32 + quad * 8;
      f16x8 bvh = *(const f16x8*)&vbh[vo];
      f16x8 bvl = *(const f16x8*)&vbl[vo];
      oh_[nb] = MFMA16(pah, bvh, oh_[nb]);
      om_[nb] = MFMA16(pah, bvl, om_[nb]);
      om_[nb] = MFMA16(pal, bvh, om_[nb]);
    }
  }
  // ---- epilogue: split-fp16 o ----
#pragma unroll
  for (int nb = 0; nb < 9; ++nb)
#pragma unroll
    for (int r = 0; r < 4; ++r) {
      int row = mt * 64 + wv * 16 + quad * 4 + r;
      int col = h * HDIM + nb * 16 + m16;
      float v = oh_[nb][r] + om_[nb][r] * (1.f / 2048.f);
      size_t idx = (size_t)(b * NS + row) * NDIM + col;
      f16 hv = (f16)v;
      ohi[idx] = hv;
      olo[idx] = (f16)((v - (float)hv) * 2048.f);
    }
}

// ---------------- ca = o @ out_w^T + out_b  (split-fp16, fp32 out) ----------------
__global__ __launch_bounds__(256) void k_ca(
    const f16* __restrict__ ohi, const f16* __restrict__ olo,
    const float* __restrict__ ow, const float* __restrict__ ob,
    float* __restrict__ ca) {
  int mt = blockIdx.y, nt = blockIdx.x;
  __shared__ f16 Ash[64 * 72];
  __shared__ f16 Asl[64 * 72];
  __shared__ f16 Bsh[64 * 72];
  __shared__ f16 Bsl[64 * 72];
  int t = threadIdx.x;
  int wv = t >> 6, lane = t & 63, m16 = lane & 15, quad = lane >> 4;
  int r0 = t >> 3, ak = (t & 7) * 8;
  size_t a0o = (size_t)(mt * 64 + r0) * NDIM;
  size_t a1o = (size_t)(mt * 64 + r0 + 32) * NDIM;
  f32x4 zf = {0.f, 0.f, 0.f, 0.f};
  f32x4 ah[2][2] = {{zf, zf}, {zf, zf}};
  f32x4 am[2][2] = {{zf, zf}, {zf, zf}};
  for (int kc = 0; kc < NDIM; kc += 64) {
    __syncthreads();
    *(uint4*)&Ash[r0 * 72 + ak] = *(const uint4*)(ohi + a0o + kc + ak);
    *(uint4*)&Ash[(r0 + 32) * 72 + ak] = *(const uint4*)(ohi + a1o + kc + ak);
    *(uint4*)&Asl[r0 * 72 + ak] = *(const uint4*)(olo + a0o + kc + ak);
    *(uint4*)&Asl[(r0 + 32) * 72 + ak] = *(const uint4*)(olo + a1o + kc + ak);
#pragma unroll
    for (int uu = 0; uu < 4; ++uu) {
      int u = t + uu * 256;
      int rr = u >> 4, kp = (u & 15) * 4;
      float4 fv = *(const float4*)(ow + (size_t)(nt * 64 + rr) * NDIM + kc + kp);
      f16x4 hb, lb;
      hb[0] = (f16)fv.x; lb[0] = (f16)((fv.x - (float)hb[0]) * 2048.f);
      hb[1] = (f16)fv.y; lb[1] = (f16)((fv.y - (float)hb[1]) * 2048.f);
      hb[2] = (f16)fv.z; lb[2] = (f16)((fv.z - (float)hb[2]) * 2048.f);
      hb[3] = (f16)fv.w; lb[3] = (f16)((fv.w - (float)hb[3]) * 2048.f);
      *(f16x4*)&Bsh[rr * 72 + kp] = hb;
      *(f16x4*)&Bsl[rr * 72 + kp] = lb;
    }
    __syncthreads();
#pragma unroll
    for (int ks = 0; ks < 2; ++ks) {
      int aoff = ((wv & 1) * 32 + m16) * 72 + ks * 32 + quad * 8;
      int boff = ((wv >> 1) * 32 + m16) * 72 + ks * 32 + quad * 8;
      f16x8 a0h = *(const f16x8*)&Ash[aoff];
      f16x8 a1h = *(const f16x8*)&Ash[aoff + 16 * 72];
      f16x8 a0l = *(const f16x8*)&Asl[aoff];
      f16x8 a1l = *(const f16x8*)&Asl[aoff + 16 * 72];
      f16x8 b0h = *(const f16x8*)&Bsh[boff];
      f16x8 b1h = *(const f16x8*)&Bsh[boff + 16 * 72];
      f16x8 b0l = *(const f16x8*)&Bsl[boff];
      f16x8 b1l = *(const f16x8*)&Bsl[boff + 16 * 72];
      ah[0][0] = MFMA16(a0h, b0h, ah[0][0]);
      ah[0][1] = MFMA16(a0h, b1h, ah[0][1]);
      ah[1][0] = MFMA16(a1h, b0h, ah[1][0]);
      ah[1][1] = MFMA16(a1h, b1h, ah[1][1]);
      am[0][0] = MFMA16(a0h, b0l, am[0][0]);
      am[0][1] = MFMA16(a0h, b1l, am[0][1]);
      am[1][0] = MFMA16(a1h, b0l, am[1][0]);
      am[1][1] = MFMA16(a1h, b1l, am[1][1]);
      am[0][0] = MFMA16(a0l, b0h, am[0][0]);
      am[0][1] = MFMA16(a0l, b1h, am[0][1]);
      am[1][0] = MFMA16(a1l, b0h, am[1][0]);
      am[1][1] = MFMA16(a1l, b1h, am[1][1]);
    }
  }
#pragma unroll
  for (int mi = 0; mi < 2; ++mi)
#pragma unroll
    for (int ni = 0; ni < 2; ++ni)
#pragma unroll
      for (int r = 0; r < 4; ++r) {
        int row = mt * 64 + (wv & 1) * 32 + mi * 16 + quad * 4 + r;
        int col = nt * 64 + (wv >> 1) * 32 + ni * 16 + m16;
        ca[(size_t)row * NDIM + col] =
            ah[mi][ni][r] + am[mi][ni][r] * (1.f / 2048.f) + ob[col];
      }
}

// ---------------- routing: argmax gates, cm/am, lists, loss ----------------
__global__ __launch_bounds__(1024) void k_route(
    const float* __restrict__ cl, const float* __restrict__ al,
    const float* __restrict__ g1, const float* __restrict__ g2,
    const float* __restrict__ g3, const float* __restrict__ tl,
    float* __restrict__ cmv, float* __restrict__ amv,
    int* __restrict__ lists, int* __restrict__ counts, float* __restrict__ out_loss) {
  __shared__ int lcnt[8];
  __shared__ float bins[8];
  __shared__ float ssum[2];
  int t = threadIdx.x;
  if (t < 8) { lcnt[t] = 0; bins[t] = 0.f; }
  if (t < 2) ssum[t] = 0.f;
  __syncthreads();
  for (int n = t; n < NTOK; n += 1024) {
    float lc[NEXP];
#pragma unroll
    for (int e = 0; e < NEXP; ++e) lc[e] = cl[n * NEXP + e] + g2[n * 4 + e];
    int ec = 0; float bv = lc[0];
#pragma unroll
    for (int e = 1; e < NEXP; ++e) if (lc[e] > bv) { bv = lc[e]; ec = e; }
    float la[NEXP];
#pragma unroll
    for (int e = 0; e < NEXP; ++e) la[e] = al[n * NEXP + e] + g3[n * 4 + e];
    int ea = 0; float bva = la[0];
#pragma unroll
    for (int e = 1; e < NEXP; ++e) if (la[e] > bva) { bva = la[e]; ea = e; }
    int b = n >> 10;
    float a0 = tl[b * 2 + 0] + g1[n * 2 + 0];
    float a1 = tl[b * 2 + 1] + g1[n * 2 + 1];
    float mx = fmaxf(a0, a1);
    float e0 = expf(a0 - mx), e1 = expf(a1 - mx);
    float cm = e0 / (e0 + e1), am = e1 / (e0 + e1);
    cmv[n] = cm; amv[n] = am;
    int p0 = atomicAdd(&lcnt[ec], 1);
    lists[ec * NTOK + p0] = n;
    int p1 = atomicAdd(&lcnt[4 + ea], 1);
    lists[(4 + ea) * NTOK + p1] = n;
    atomicAdd(&bins[ec], cm);
    atomicAdd(&bins[4 + ea], am);
    atomicAdd(&ssum[0], cm);
    atomicAdd(&ssum[1], am);
  }
  __syncthreads();
  if (t < 8) counts[t] = lcnt[t];
  if (t == 0) {
    float denom = 4.f * (ssum[0] + ssum[1]) + 1e-10f;
    float acc = 0.f;
    for (int j = 0; j < 8; ++j) {
      float u = bins[j] / denom;
      acc += u * logf(u + 1e-10f);
    }
    out_loss[0] = acc / 8.f;
  }
}

// ---------------- GEMM1: dual-B (w1,w3) + silu*mul -> t16 ----------------
__global__ __launch_bounds__(256) void k_gemm1(
    const f16* __restrict__ x16, const f16* __restrict__ y16,
    const float* __restrict__ cw1, const float* __restrict__ cw3,
    const float* __restrict__ aw1, const float* __restrict__ aw3,
    const float* __restrict__ fw1, const float* __restrict__ fw3,
    const int* __restrict__ lists, const int* __restrict__ counts,
    f16* __restrict__ tbuf, int gbase) {
  int g = blockIdx.z + gbase;
  int mt = blockIdx.y, nt = blockIdx.x;
  const f16* A; const float* B1; const float* B3; f16* tout;
  const int* list = nullptr;
  int cnt, koff, K;
  if (g < 8) {
    int e = g & 3;
    cnt = counts[g];
    list = lists + g * NTOK;
    A = x16; koff = 0; K = NDIM;
    const float* w1s = (g < 4) ? cw1 : aw1;
    const float* w3s = (g < 4) ? cw3 : aw3;
    B1 = w1s + (size_t)e * NHID * NDIM;
    B3 = w3s + (size_t)e * NHID * NDIM;
    tout = tbuf + (size_t)g * NTOK * NHID;
  } else {
    int e = g - 8;
    cnt = NTOK;
    A = y16; koff = e * 288; K = 288;
    B1 = fw1 + (size_t)e * NHID * NDIM + koff;
    B3 = fw3 + (size_t)e * NHID * NDIM + koff;
    tout = tbuf + (size_t)e * NTOK * NHID;
  }
  if (mt * 64 >= cnt) return;
  int t = threadIdx.x;
  int wv = t >> 6, lane = t & 63, m16 = lane & 15, quad = lane >> 4;
  int r0 = t >> 3, ak = (t & 7) * 8;
  int m0 = mt * 64 + r0, m1 = m0 + 32;
  int tok0, tok1;
  if (list) { tok0 = list[min(m0, cnt - 1)]; tok1 = list[min(m1, cnt - 1)]; }
  else { tok0 = m0; tok1 = m1; }
  const f16* ar0 = A + (size_t)tok0 * NDIM + koff;
  const f16* ar1 = A + (size_t)tok1 * NDIM + koff;
  __shared__ f16 As[64 * 72];
  __shared__ f16 Bs1[64 * 72];
  __shared__ f16 Bs2[64 * 72];
  f32x4 zf = {0.f, 0.f, 0.f, 0.f};
  f32x4 ac1[2][2] = {{zf, zf}, {zf, zf}};
  f32x4 ac2[2][2] = {{zf, zf}, {zf, zf}};
  for (int kc = 0; kc < K; kc += 64) {
    __syncthreads();
    {
      uint4 v0 = make_uint4(0u, 0u, 0u, 0u), v1 = v0;
      if (kc + ak < K) {
        v0 = *(const uint4*)(ar0 + kc + ak);
        v1 = *(const uint4*)(ar1 + kc + ak);
      }
      *(uint4*)&As[r0 * 72 + ak] = v0;
      *(uint4*)&As[(r0 + 32) * 72 + ak] = v1;
    }
#pragma unroll
    for (int uu = 0; uu < 4; ++uu) {
      int u = t + uu * 256;
      int rr = u >> 4, kp = (u & 15) * 4;
      f16x4 hb1 = {(f16)0.f, (f16)0.f, (f16)0.f, (f16)0.f};
      f16x4 hb3 = hb1;
      if (kc + kp < K) {
        float4 f1 = *(const float4*)(B1 + (size_t)(nt * 64 + rr) * NDIM + kc + kp);
        float4 f3 = *(const float4*)(B3 + (size_t)(nt * 64 + rr) * NDIM + kc + kp);
        hb1[0] = (f16)f1.x; hb1[1] = (f16)f1.y; hb1[2] = (f16)f1.z; hb1[3] = (f16)f1.w;
        hb3[0] = (f16)f3.x; hb3[1] = (f16)f3.y; hb3[2] = (f16)f3.z; hb3[3] = (f16)f3.w;
      }
      *(f16x4*)&Bs1[rr * 72 + kp] = hb1;
      *(f16x4*)&Bs2[rr * 72 + kp] = hb3;
    }
    __syncthreads();
#pragma unroll
    for (int ks = 0; ks < 2; ++ks) {
      int aoff = ((wv & 1) * 32 + m16) * 72 + ks * 32 + quad * 8;
      int boff = ((wv >> 1) * 32 + m16) * 72 + ks * 32 + quad * 8;
      f16x8 a0 = *(const f16x8*)&As[aoff];
      f16x8 a1 = *(const f16x8*)&As[aoff + 16 * 72];
      f16x8 b10 = *(const f16x8*)&Bs1[boff];
      f16x8 b11 = *(const f16x8*)&Bs1[boff + 16 * 72];
      f16x8 b30 = *(const f16x8*)&Bs2[boff];
      f16x8 b31 = *(const f16x8*)&Bs2[boff + 16 * 72];
      ac1[0][0] = MFMA16(a0, b10, ac1[0][0]);
      ac1[0][1] = MFMA16(a0, b11, ac1[0][1]);
      ac1[1][0] = MFMA16(a1, b10, ac1[1][0]);
      ac1[1][1] = MFMA16(a1, b11, ac1[1][1]);
      ac2[0][0] = MFMA16(a0, b30, ac2[0][0]);
      ac2[0][1] = MFMA16(a0, b31, ac2[0][1]);
      ac2[1][0] = MFMA16(a1, b30, ac2[1][0]);
      ac2[1][1] = MFMA16(a1, b31, ac2[1][1]);
    }
  }
#pragma unroll
  for (int mi = 0; mi < 2; ++mi)
#pragma unroll
    for (int ni = 0; ni < 2; ++ni)
#pragma unroll
      for (int r = 0; r < 4; ++r) {
        int row = mt * 64 + (wv & 1) * 32 + mi * 16 + quad * 4 + r;
        int col = nt * 64 + (wv >> 1) * 32 + ni * 16 + m16;
        float h1 = ac1[mi][ni][r];
        float h3 = ac2[mi][ni][r];
        float sl = h1 / (1.0f + expf(-h1));
        tout[(size_t)row * NHID + col] = (f16)(sl * h3);
      }
}

// ---------------- GEMM2 (MoE): t16 @ w2^T * cm/am -> y ----------------
__global__ __launch_bounds__(256) void k_gemm2(
    const f16* __restrict__ tbuf, const float* __restrict__ cw2, const float* __restrict__ aw2,
    const int* __restrict__ lists, const int* __restrict__ counts,
    const float* __restrict__ cmv, const float* __restrict__ amv,
    float* __restrict__ y, int gbase) {
  int g = blockIdx.z + gbase;
  int e = g & 3;
  int mt = blockIdx.y, nt = blockIdx.x;
  int cnt = counts[g];
  if (mt * 64 >= cnt) return;
  const int* list = lists + g * NTOK;
  const f16* A = tbuf + (size_t)g * NTOK * NHID;
  const float* Bw = ((g < 4) ? cw2 : aw2) + (size_t)e * NDIM * NHID;
  const float* sc = (g < 4) ? cmv : amv;
  int t = threadIdx.x;
  int wv = t >> 6, lane = t & 63, m16 = lane & 15, quad = lane >> 4;
  int r0 = t >> 3, ak = (t & 7) * 8;
  const f16* ar0 = A + (size_t)(mt * 64 + r0) * NHID;
  const f16* ar1 = A + (size_t)(mt * 64 + r0 + 32) * NHID;
  __shared__ f16 As[64 * 72];
  __shared__ f16 Bs[64 * 72];
  f32x4 zf = {0.f, 0.f, 0.f, 0.f};
  f32x4 acc[2][2] = {{zf, zf}, {zf, zf}};
  for (int kc = 0; kc < NHID; kc += 64) {
    __syncthreads();
    *(uint4*)&As[r0 * 72 + ak] = *(const uint4*)(ar0 + kc + ak);
    *(uint4*)&As[(r0 + 32) * 72 + ak] = *(const uint4*)(ar1 + kc + ak);
#pragma unroll
    for (int uu = 0; uu < 4; ++uu) {
      int u = t + uu * 256;
      int rr = u >> 4, kp = (u & 15) * 4;
      float4 fv = *(const float4*)(Bw + (size_t)(nt * 64 + rr) * NHID + kc + kp);
      f16x4 hb; hb[0] = (f16)fv.x; hb[1] = (f16)fv.y; hb[2] = (f16)fv.z; hb[3] = (f16)fv.w;
      *(f16x4*)&Bs[rr * 72 + kp] = hb;
    }
    __syncthreads();
#pragma unroll
    for (int ks = 0; ks < 2; ++ks) {
      int aoff = ((wv & 1) * 32 + m16) * 72 + ks * 32 + quad * 8;
      int boff = ((wv >> 1) * 32 + m16) * 72 + ks * 32 + quad * 8;
      f16x8 a0 = *(const f16x8*)&As[aoff];
      f16x8 a1 = *(const f16x8*)&As[aoff + 16 * 72];
      f16x8 b0 = *(const f16x8*)&Bs[boff];
      f16x8 b1 = *(const f16x8*)&Bs[boff + 16 * 72];
      acc[0][0] = MFMA16(a0, b0, acc[0][0]);
      acc[0][1] = MFMA16(a0, b1, acc[0][1]);
      acc[1][0] = MFMA16(a1, b0, acc[1][0]);
      acc[1][1] = MFMA16(a1, b1, acc[1][1]);
    }
  }
#pragma unroll
  for (int mi = 0; mi < 2; ++mi)
#pragma unroll
    for (int ni = 0; ni < 2; ++ni)
#pragma unroll
      for (int r = 0; r < 4; ++r) {
        int mg = mt * 64 + (wv & 1) * 32 + mi * 16 + quad * 4 + r;
        if (mg < cnt) {
          int tok = list[mg];
          int col = nt * 64 + (wv >> 1) * 32 + ni * 16 + m16;
          float v = acc[mi][ni][r] * sc[tok];
          size_t oi = (size_t)tok * NDIM + col;
          if (gbase == 0) y[oi] = v;
          else y[oi] += v;
        }
      }
}

// ---------------- GEMM2 (fr): t16 @ fr_w2[e][e*288:(e+1)*288,:]^T -> z slice ----------------
__global__ __launch_bounds__(256) void k_gemm2_fr(
    const f16* __restrict__ tbuf, const float* __restrict__ fw2, float* __restrict__ zz) {
  int e = blockIdx.z;
  int mt = blockIdx.y, nt = blockIdx.x;
  const f16* A = tbuf + (size_t)e * NTOK * NHID;
  const float* Bw = fw2 + (size_t)e * NDIM * NHID;
  int t = threadIdx.x;
  int wv = t >> 6, lane = t & 63, m16 = lane & 15, quad = lane >> 4;
  int r0 = t >> 3, ak = (t & 7) * 8;
  const f16* ar0 = A + (size_t)(mt * 64 + r0) * NHID;
  const f16* ar1 = A + (size_t)(mt * 64 + r0 + 32) * NHID;
  __shared__ f16 As[64 * 72];
  __shared__ f16 Bs[64 * 72];
  f32x4 zf = {0.f, 0.f, 0.f, 0.f};
  f32x4 acc[2][2] = {{zf, zf}, {zf, zf}};
  for (int kc = 0; kc < NHID; kc += 64) {
    __syncthreads();
    *(uint4*)&As[r0 * 72 + ak] = *(const uint4*)(ar0 + kc + ak);
    *(uint4*)&As[(r0 + 32) * 72 + ak] = *(const uint4*)(ar1 + kc + ak);
#pragma unroll
    for (int uu = 0; uu < 4; ++uu) {
      int u = t + uu * 256;
      int rr = u >> 4, kp = (u & 15) * 4;
      int ne = min(nt * 64 + rr, 287);
      float4 fv = *(const float4*)(Bw + (size_t)(e * 288 + ne) * NHID + kc + kp);
      f16x4 hb; hb[0] = (f16)fv.x; hb[1] = (f16)fv.y; hb[2] = (f16)fv.z; hb[3] = (f16)fv.w;
      *(f16x4*)&Bs[rr * 72 + kp] = hb;
    }
    __syncthreads();
#pragma unroll
    for (int ks = 0; ks < 2; ++ks) {
      int aoff = ((wv & 1) * 32 + m16) * 72 + ks * 32 + quad * 8;
      int boff = ((wv >> 1) * 32 + m16) * 72 + ks * 32 + quad * 8;
      f16x8 a0 = *(const f16x8*)&As[aoff];
      f16x8 a1 = *(const f16x8*)&As[aoff + 16 * 72];
      f16x8 b0 = *(const f16x8*)&Bs[boff];
      f16x8 b1 = *(const f16x8*)&Bs[boff + 16 * 72];
      acc[0][0] = MFMA16(a0, b0, acc[0][0]);
      acc[0][1] = MFMA16(a0, b1, acc[0][1]);
      acc[1][0] = MFMA16(a1, b0, acc[1][0]);
      acc[1][1] = MFMA16(a1, b1, acc[1][1]);
    }
  }
#pragma unroll
  for (int mi = 0; mi < 2; ++mi)
#pragma unroll
    for (int ni = 0; ni < 2; ++ni)
#pragma unroll
      for (int r = 0; r < 4; ++r) {
        int cg = nt * 64 + (wv >> 1) * 32 + ni * 16 + m16;
        if (cg < 288) {
          int row = mt * 64 + (wv & 1) * 32 + mi * 16 + quad * 4 + r;
          zz[(size_t)row * NDIM + e * 288 + cg] = acc[mi][ni][r];
        }
      }
}

// ---------------- host ----------------
extern "C" void kernel_launch(void* const* d_in, const int* in_sizes, int n_in,
                              void* d_out, int out_size, void* d_ws, size_t ws_size,
                              hipStream_t stream) {
  const float* x          = (const float*)d_in[0];
  const float* timep      = (const float*)d_in[1];
  const float* caption    = (const float*)d_in[2];
  const float* acoustic   = (const float*)d_in[3];
  const float* attn_in_w  = (const float*)d_in[4];
  const float* attn_in_b  = (const float*)d_in[5];
  const float* attn_out_w = (const float*)d_in[6];
  const float* attn_out_b = (const float*)d_in[7];
  const float* hl_w       = (const float*)d_in[8];
  const float* hl_b       = (const float*)d_in[9];
  const float* cap_gate_w = (const float*)d_in[10];
  const float* cap_gate_b = (const float*)d_in[11];
  const float* ac_gate_w  = (const float*)d_in[12];
  const float* ac_gate_b  = (const float*)d_in[13];
  const float* cap_w1     = (const float*)d_in[14];
  const float* cap_w2     = (const float*)d_in[15];
  const float* cap_w3     = (const float*)d_in[16];
  const float* ac_w1      = (const float*)d_in[17];
  const float* ac_w2      = (const float*)d_in[18];
  const float* ac_w3      = (const float*)d_in[19];
  const float* fr_w1      = (const float*)d_in[20];
  const float* fr_w2      = (const float*)d_in[21];
  const float* fr_w3      = (const float*)d_in[22];
  (void)in_sizes; (void)n_in; (void)out_size; (void)ws_size;

  float* zout = (float*)d_out;
  float* loss = zout + (size_t)NTOK * NDIM;

  char* wsb = (char*)d_ws;
  size_t off = 0;
  auto alloc = [&](size_t bytes) -> void* {
    void* p = wsb + off;
    off = (off + bytes + 255) & ~(size_t)255;
    return p;
  };
  // persistent small + xhi
  float* g1     = (float*)alloc(4096 * 4);
  float* g2     = (float*)alloc(8192 * 4);
  float* g3     = (float*)alloc(8192 * 4);
  float* tl     = (float*)alloc(4 * 4);
  float* al     = (float*)alloc((size_t)NTOK * NEXP * 4);
  float* cl     = (float*)alloc((size_t)NTOK * NEXP * 4);
  float* cmv    = (float*)alloc((size_t)NTOK * 4);
  float* amv    = (float*)alloc((size_t)NTOK * 4);
  int*   lists  = (int*)alloc((size_t)8 * NTOK * 4);
  int*   counts = (int*)alloc(8 * 4);
  f16*   xhi    = (f16*)alloc((size_t)NTOK * NDIM * 2);
  size_t region = off;
  // phase 1 (attention / routing inputs)
  f16*   xlo    = (f16*)alloc((size_t)NTOK * NDIM * 2);
  f16*   caphi  = (f16*)alloc((size_t)NCAP * NDIM * 2);
  f16*   caplo  = (f16*)alloc((size_t)NCAP * NDIM * 2);
  f16*   qhi    = (f16*)alloc((size_t)NTOK * NDIM * 2);
  f16*   qlo    = (f16*)alloc((size_t)NTOK * NDIM * 2);
  f16*   khi    = (f16*)alloc((size_t)NCAP * NDIM * 2);
  f16*   klo    = (f16*)alloc((size_t)NCAP * NDIM * 2);
  f16*   vthi   = (f16*)alloc((size_t)NB * NDIM * NSC * 2);
  f16*   vtlo   = (f16*)alloc((size_t)NB * NDIM * NSC * 2);
  f16*   ohi    = (f16*)alloc((size_t)NTOK * NDIM * 2);
  f16*   olo    = (f16*)alloc((size_t)NTOK * NDIM * 2);
  float* ca32   = (float*)alloc((size_t)NTOK * NDIM * 4);
  // phase 2 (MoE / fr) — reuses phase-1 region (all phase-1 buffers dead)
  off = region;
  f16*   tbuf   = (f16*)alloc((size_t)8 * NTOK * NHID * 2);
  float* yb     = (float*)alloc((size_t)NTOK * NDIM * 4);
  f16*   y16    = (f16*)alloc((size_t)NTOK * NDIM * 2);

  k_prep<<<dim3(1), dim3(256), 0, stream>>>(timep, hl_w, hl_b, g1, g2, g3, tl);
  k_ac_logits<<<dim3(512), dim3(256), 0, stream>>>(acoustic, ac_gate_w, ac_gate_b, al);
  k_cvt_split<<<dim3(2304), dim3(256), 0, stream>>>(x, xhi, xlo, NTOK * NDIM);
  k_cvt_split<<<dim3(288), dim3(256), 0, stream>>>(caption, caphi, caplo, NCAP * NDIM);
  k_gemm_qkv<<<dim3(18, 32, 3), dim3(256), 0, stream>>>(xhi, xlo, caphi, caplo,
                                                        attn_in_w, attn_in_b,
                                                        qhi, qlo, khi, klo, vthi, vtlo);
  k_attn<<<dim3(16, 16), dim3(256), 0, stream>>>(qhi, qlo, khi, klo, vthi, vtlo, ohi, olo);
  k_ca<<<dim3(18, 32), dim3(256), 0, stream>>>(ohi, olo, attn_out_w, attn_out_b, ca32);
  k_ac_logits<<<dim3(512), dim3(256), 0, stream>>>(ca32, cap_gate_w, cap_gate_b, cl);
  k_route<<<dim3(1), dim3(1024), 0, stream>>>(cl, al, g1, g2, g3, tl,
                                              cmv, amv, lists, counts, loss);
  k_gemm1<<<dim3(12, 32, 8), dim3(256), 0, stream>>>(xhi, y16, cap_w1, cap_w3, ac_w1, ac_w3,
                                                     fr_w1, fr_w3, lists, counts, tbuf, 0);
  k_gemm2<<<dim3(18, 32, 4), dim3(256), 0, stream>>>(tbuf, cap_w2, ac_w2, lists, counts,
                                                     cmv, amv, yb, 0);
  k_gemm2<<<dim3(18, 32, 4), dim3(256), 0, stream>>>(tbuf, cap_w2, ac_w2, lists, counts,
                                                     cmv, amv, yb, 4);
  k_cvt<<<dim3(2304), dim3(256), 0, stream>>>(yb, y16, NTOK * NDIM);
  k_gemm1<<<dim3(12, 32, 4), dim3(256), 0, stream>>>(xhi, y16, cap_w1, cap_w3, ac_w1, ac_w3,
                                                     fr_w1, fr_w3, lists, counts, tbuf, 8);
  k_gemm2_fr<<<dim3(5, 32, 4), dim3(256), 0, stream>>>(tbuf, fr_w2, zout);
}

// Round 2
// 525.829 us; speedup vs baseline: 1.1267x; 1.0254x over previous
//
#include <hip/hip_runtime.h>
#include <stdint.h>

#define NDIM 1152
#define NEXP 4
#define NHID 768
#define NHEAD 8
#define HDIM 144
#define NB 2
#define NS 1024
#define NSC 128
#define NTOK 2048
#define NCAP 256

typedef _Float16 f16;
typedef _Float16 f16x4 __attribute__((ext_vector_type(4)));
typedef _Float16 f16x8 __attribute__((ext_vector_type(8)));
typedef float f32x4 __attribute__((ext_vector_type(4)));

#define MFMA16(a, b, c) __builtin_amdgcn_mfma_f32_16x16x32_f16(a, b, c, 0, 0, 0)

// ---------------- Threefry2x32 (exact JAX replication) ----------------
__device__ inline uint2 tfry(uint32_t k0, uint32_t k1, uint32_t x0, uint32_t x1) {
  uint32_t k2 = k0 ^ k1 ^ 0x1BD11BDAu;
#define RND(r) { x0 += x1; x1 = (x1 << r) | (x1 >> (32 - r)); x1 ^= x0; }
  x0 += k0; x1 += k1;
  RND(13) RND(15) RND(26) RND(6)
  x0 += k1; x1 += k2 + 1u;
  RND(17) RND(29) RND(16) RND(24)
  x0 += k2; x1 += k0 + 2u;
  RND(13) RND(15) RND(26) RND(6)
  x0 += k0; x1 += k1 + 3u;
  RND(17) RND(29) RND(16) RND(24)
  x0 += k1; x1 += k2 + 4u;
  RND(13) RND(15) RND(26) RND(6)
  x0 += k2; x1 += k0 + 5u;
#undef RND
  return make_uint2(x0, x1);
}

__device__ inline float b2g(uint32_t bits) {
  uint32_t fb = (bits >> 9) | 0x3f800000u;
  float f = __uint_as_float(fb) - 1.0f;
  const float tiny = 1.1754943508222875e-38f;
  float u = f * 1.0f + tiny;
  u = fmaxf(tiny, u);
  return -logf(-logf(u));
}

// ---------------- prep: keys, gumbels, time-logits ----------------
__global__ void k_prep(const float* __restrict__ timep, const float* __restrict__ hlw,
                       const float* __restrict__ hlb,
                       float* __restrict__ g1, float* __restrict__ g2, float* __restrict__ g3,
                       float* __restrict__ tl) {
  int t = threadIdx.x;  // 256
  uint2 k1 = tfry(0u, 42u, 0u, 0u);
  uint2 k2 = tfry(0u, 42u, 0u, 1u);
  uint2 k3 = tfry(0u, 42u, 0u, 2u);
  for (int p = t; p < 4096; p += 256) {
    uint2 o = tfry(k1.x, k1.y, 0u, (uint32_t)p);
    g1[p] = b2g(o.x ^ o.y);
  }
  for (int p = t; p < 8192; p += 256) {
    uint2 o2 = tfry(k2.x, k2.y, 0u, (uint32_t)p);
    g2[p] = b2g(o2.x ^ o2.y);
    uint2 o3 = tfry(k3.x, k3.y, 0u, (uint32_t)p);
    g3[p] = b2g(o3.x ^ o3.y);
  }
  int wv = t >> 6, lane = t & 63;
  {
    int b = wv >> 1, j = wv & 1;
    float s = 0.f;
    for (int k = lane; k < NDIM; k += 64) s += timep[b * NDIM + k] * hlw[j * NDIM + k];
    for (int m = 32; m; m >>= 1) s += __shfl_xor(s, m);
    if (lane == 0) tl[b * 2 + j] = s + hlb[j];
  }
}

// ---------------- generic 4-logit head: out[n,e] = in[n,:]·w[e,:] + b[e] ----------------
__global__ void k_ac_logits(const float* __restrict__ ac, const float* __restrict__ agw,
                            const float* __restrict__ agb, float* __restrict__ al) {
  int wv = threadIdx.x >> 6, lane = threadIdx.x & 63;
  int n = blockIdx.x * 4 + wv;
  float s[NEXP] = {0.f, 0.f, 0.f, 0.f};
  for (int d = lane; d < NDIM; d += 64) {
    float a = ac[(size_t)n * NDIM + d];
#pragma unroll
    for (int e = 0; e < NEXP; ++e) s[e] += a * agw[e * NDIM + d];
  }
#pragma unroll
  for (int e = 0; e < NEXP; ++e)
    for (int m = 32; m; m >>= 1) s[e] += __shfl_xor(s[e], m);
  if (lane == 0) {
#pragma unroll
    for (int e = 0; e < NEXP; ++e) al[n * NEXP + e] = s[e] + agb[e];
  }
}

// ---------------- fp32 + fp32 -> fp16 convert (fused add) ----------------
__global__ void k_cvt_add(const float* __restrict__ srca, const float* __restrict__ srcb,
                          f16* __restrict__ dst, int n) {
  int i = (blockIdx.x * 256 + threadIdx.x) * 4;
  if (i + 3 < n) {
    float4 va = *(const float4*)(srca + i);
    float4 vb = *(const float4*)(srcb + i);
    f16x4 h;
    h[0] = (f16)(va.x + vb.x); h[1] = (f16)(va.y + vb.y);
    h[2] = (f16)(va.z + vb.z); h[3] = (f16)(va.w + vb.w);
    *(f16x4*)(dst + i) = h;
  }
}

// ---------------- fp32 -> fp16 hi/lo split convert (lo pre-scaled by 2048) ----------------
__global__ void k_cvt_split(const float* __restrict__ src, f16* __restrict__ hi,
                            f16* __restrict__ lo, int n) {
  int i = (blockIdx.x * 256 + threadIdx.x) * 4;
  if (i + 3 < n) {
    float4 v = *(const float4*)(src + i);
    f16x4 h, l;
    h[0] = (f16)v.x; l[0] = (f16)((v.x - (float)h[0]) * 2048.f);
    h[1] = (f16)v.y; l[1] = (f16)((v.y - (float)h[1]) * 2048.f);
    h[2] = (f16)v.z; l[2] = (f16)((v.z - (float)h[2]) * 2048.f);
    h[3] = (f16)v.w; l[3] = (f16)((v.w - (float)h[3]) * 2048.f);
    *(f16x4*)(hi + i) = h;
    *(f16x4*)(lo + i) = l;
  }
}

// ---------------- QKV projection, split-fp16 (~fp32 accurate), 2-phase prefetch ------
// z==2 (V) emits transposed split-fp16: vT[b][dd (0..1151)][kv (0..127)]
__global__ __launch_bounds__(256) void k_gemm_qkv(
    const f16* __restrict__ xhi, const f16* __restrict__ xlo,
    const f16* __restrict__ caphi, const f16* __restrict__ caplo,
    const float* __restrict__ inw, const float* __restrict__ inb,
    f16* __restrict__ qhi, f16* __restrict__ qlo,
    f16* __restrict__ khi, f16* __restrict__ klo,
    f16* __restrict__ vthi, f16* __restrict__ vtlo) {
  int z = blockIdx.z;
  int M = (z == 0) ? NTOK : NCAP;
  int mt = blockIdx.y, nt = blockIdx.x;
  if (mt * 64 >= M) return;
  const f16* Ah_g = (z == 0) ? xhi : caphi;
  const f16* Al_g = (z == 0) ? xlo : caplo;
  __shared__ f16 Ash[64 * 72];
  __shared__ f16 Asl[64 * 72];
  __shared__ f16 Bsh[64 * 72];
  __shared__ f16 Bsl[64 * 72];
  int t = threadIdx.x;
  int wv = t >> 6, lane = t & 63, m16 = lane & 15, quad = lane >> 4;
  int r0 = t >> 3, ak = (t & 7) * 8;
  size_t a0o = (size_t)(mt * 64 + r0) * NDIM;
  size_t a1o = (size_t)(mt * 64 + r0 + 32) * NDIM;
  f32x4 zf = {0.f, 0.f, 0.f, 0.f};
  f32x4 ah[2][2] = {{zf, zf}, {zf, zf}};
  f32x4 am[2][2] = {{zf, zf}, {zf, zf}};
  // prefetch regs
  uint4 rah0, rah1, ral0, ral1;
  float4 rbw[4];
  rah0 = *(const uint4*)(Ah_g + a0o + ak);
  rah1 = *(const uint4*)(Ah_g + a1o + ak);
  ral0 = *(const uint4*)(Al_g + a0o + ak);
  ral1 = *(const uint4*)(Al_g + a1o + ak);
#pragma unroll
  for (int uu = 0; uu < 4; ++uu) {
    int u = t + uu * 256;
    int rr = u >> 4, kp = (u & 15) * 4;
    rbw[uu] = *(const float4*)(inw + (size_t)(z * NDIM + nt * 64 + rr) * NDIM + kp);
  }
  for (int kc = 0; kc < NDIM; kc += 64) {
    __syncthreads();
    *(uint4*)&Ash[r0 * 72 + ak] = rah0;
    *(uint4*)&Ash[(r0 + 32) * 72 + ak] = rah1;
    *(uint4*)&Asl[r0 * 72 + ak] = ral0;
    *(uint4*)&Asl[(r0 + 32) * 72 + ak] = ral1;
#pragma unroll
    for (int uu = 0; uu < 4; ++uu) {
      int u = t + uu * 256;
      int rr = u >> 4, kp = (u & 15) * 4;
      f16x4 hb, lb;
      hb[0] = (f16)rbw[uu].x; lb[0] = (f16)((rbw[uu].x - (float)hb[0]) * 2048.f);
      hb[1] = (f16)rbw[uu].y; lb[1] = (f16)((rbw[uu].y - (float)hb[1]) * 2048.f);
      hb[2] = (f16)rbw[uu].z; lb[2] = (f16)((rbw[uu].z - (float)hb[2]) * 2048.f);
      hb[3] = (f16)rbw[uu].w; lb[3] = (f16)((rbw[uu].w - (float)hb[3]) * 2048.f);
      *(f16x4*)&Bsh[rr * 72 + kp] = hb;
      *(f16x4*)&Bsl[rr * 72 + kp] = lb;
    }
    __syncthreads();
    int kn = kc + 64;
    if (kn < NDIM) {
      rah0 = *(const uint4*)(Ah_g + a0o + kn + ak);
      rah1 = *(const uint4*)(Ah_g + a1o + kn + ak);
      ral0 = *(const uint4*)(Al_g + a0o + kn + ak);
      ral1 = *(const uint4*)(Al_g + a1o + kn + ak);
#pragma unroll
      for (int uu = 0; uu < 4; ++uu) {
        int u = t + uu * 256;
        int rr = u >> 4, kp = (u & 15) * 4;
        rbw[uu] = *(const float4*)(inw + (size_t)(z * NDIM + nt * 64 + rr) * NDIM + kn + kp);
      }
    }
#pragma unroll
    for (int ks = 0; ks < 2; ++ks) {
      int aoff = ((wv & 1) * 32 + m16) * 72 + ks * 32 + quad * 8;
      int boff = ((wv >> 1) * 32 + m16) * 72 + ks * 32 + quad * 8;
      f16x8 a0h = *(const f16x8*)&Ash[aoff];
      f16x8 a1h = *(const f16x8*)&Ash[aoff + 16 * 72];
      f16x8 a0l = *(const f16x8*)&Asl[aoff];
      f16x8 a1l = *(const f16x8*)&Asl[aoff + 16 * 72];
      f16x8 b0h = *(const f16x8*)&Bsh[boff];
      f16x8 b1h = *(const f16x8*)&Bsh[boff + 16 * 72];
      f16x8 b0l = *(const f16x8*)&Bsl[boff];
      f16x8 b1l = *(const f16x8*)&Bsl[boff + 16 * 72];
      ah[0][0] = MFMA16(a0h, b0h, ah[0][0]);
      ah[0][1] = MFMA16(a0h, b1h, ah[0][1]);
      ah[1][0] = MFMA16(a1h, b0h, ah[1][0]);
      ah[1][1] = MFMA16(a1h, b1h, ah[1][1]);
      am[0][0] = MFMA16(a0h, b0l, am[0][0]);
      am[0][1] = MFMA16(a0h, b1l, am[0][1]);
      am[1][0] = MFMA16(a1h, b0l, am[1][0]);
      am[1][1] = MFMA16(a1h, b1l, am[1][1]);
      am[0][0] = MFMA16(a0l, b0h, am[0][0]);
      am[0][1] = MFMA16(a0l, b1h, am[0][1]);
      am[1][0] = MFMA16(a1l, b0h, am[1][0]);
      am[1][1] = MFMA16(a1l, b1h, am[1][1]);
    }
  }
#pragma unroll
  for (int mi = 0; mi < 2; ++mi)
#pragma unroll
    for (int ni = 0; ni < 2; ++ni)
#pragma unroll
      for (int r = 0; r < 4; ++r) {
        int row = mt * 64 + (wv & 1) * 32 + mi * 16 + quad * 4 + r;
        int col = nt * 64 + (wv >> 1) * 32 + ni * 16 + m16;
        float v = ah[mi][ni][r] + am[mi][ni][r] * (1.f / 2048.f) + inb[z * NDIM + col];
        size_t idx = (size_t)row * NDIM + col;
        if (z == 0) {
          f16 hq = (f16)v;
          qhi[idx] = hq;
          qlo[idx] = (f16)((v - (float)hq) * 2048.f);
        } else if (z == 1) {
          f16 hk = (f16)v;
          khi[idx] = hk;
          klo[idx] = (f16)((v - (float)hk) * 2048.f);
        } else {
          f16 hv = (f16)v;
          int bb = row >> 7, kv = row & 127;
          size_t ti = (size_t)(bb * NDIM + col) * NSC + kv;
          vthi[ti] = hv;
          vtlo[ti] = (f16)((v - (float)hv) * 2048.f);
        }
      }
}

// ---------------- fused attention: QK^T + softmax + PV, split-fp16, writes o hi/lo ----
// grid (mt=16, bh=16), 256 thr. Per block: 64 q-rows x full 128 kv for one (b,h).
__global__ __launch_bounds__(256) void k_attn(
    const f16* __restrict__ qhi, const f16* __restrict__ qlo,
    const f16* __restrict__ khi, const f16* __restrict__ klo,
    const f16* __restrict__ vthi, const f16* __restrict__ vtlo,
    f16* __restrict__ ohi, f16* __restrict__ olo) {
  int mt = blockIdx.x, bh = blockIdx.y;
  int b = bh >> 3, h = bh & 7;
  __shared__ f16 Ah[64 * 160];
  __shared__ f16 Al[64 * 160];
  __shared__ f16 Bh[32 * 160];
  __shared__ f16 Bl[32 * 160];
  __shared__ f16 Ph[64 * 136];
  __shared__ f16 Pl[64 * 136];
  int t = threadIdx.x;
  int wv = t >> 6, lane = t & 63, m16 = lane & 15, quad = lane >> 4;
  // stage Q tile (64 x 144, zero-padded to 160)
  for (int u = t; u < 64 * 20; u += 256) {
    int r = u / 20, kp = (u % 20) * 8;
    uint4 vh = make_uint4(0u, 0u, 0u, 0u), vl = vh;
    if (kp < HDIM) {
      size_t gi = (size_t)(b * NS + mt * 64 + r) * NDIM + h * HDIM + kp;
      vh = *(const uint4*)&qhi[gi];
      vl = *(const uint4*)&qlo[gi];
    }
    *(uint4*)&Ah[r * 160 + kp] = vh;
    *(uint4*)&Al[r * 160 + kp] = vl;
  }
  __syncthreads();
  f16x8 ahf[5], alf[5];
#pragma unroll
  for (int ks = 0; ks < 5; ++ks) {
    int ao = (wv * 16 + m16) * 160 + ks * 32 + quad * 8;
    ahf[ks] = *(const f16x8*)&Ah[ao];
    alf[ks] = *(const f16x8*)&Al[ao];
  }
  f32x4 zf = {0.f, 0.f, 0.f, 0.f};
  f32x4 sh_[4][2], sm_[4][2];
#pragma unroll
  for (int kt = 0; kt < 4; ++kt)
#pragma unroll
    for (int ni = 0; ni < 2; ++ni) { sh_[kt][ni] = zf; sm_[kt][ni] = zf; }
  // ---- QK^T over 4 chunks of 32 kv ----
  for (int kt = 0; kt < 4; ++kt) {
    if (kt) __syncthreads();
    for (int u = t; u < 32 * 20; u += 256) {
      int r = u / 20, kp = (u % 20) * 8;
      uint4 vh = make_uint4(0u, 0u, 0u, 0u), vl = vh;
      if (kp < HDIM) {
        size_t gi = (size_t)(b * NSC + kt * 32 + r) * NDIM + h * HDIM + kp;
        vh = *(const uint4*)&khi[gi];
        vl = *(const uint4*)&klo[gi];
      }
      *(uint4*)&Bh[r * 160 + kp] = vh;
      *(uint4*)&Bl[r * 160 + kp] = vl;
    }
    __syncthreads();
#pragma unroll
    for (int ks = 0; ks < 5; ++ks) {
#pragma unroll
      for (int ni = 0; ni < 2; ++ni) {
        int bo = (ni * 16 + m16) * 160 + ks * 32 + quad * 8;
        f16x8 bhf = *(const f16x8*)&Bh[bo];
        f16x8 blf = *(const f16x8*)&Bl[bo];
        sh_[kt][ni] = MFMA16(ahf[ks], bhf, sh_[kt][ni]);
        sm_[kt][ni] = MFMA16(ahf[ks], blf, sm_[kt][ni]);
        sm_[kt][ni] = MFMA16(alf[ks], bhf, sm_[kt][ni]);
      }
    }
  }
  // ---- softmax in-register: lane holds rows quad*4+r, cols kt*32+ni*16+m16 ----
  float sv[4][2][4];
  float mx[4] = {-1e30f, -1e30f, -1e30f, -1e30f};
#pragma unroll
  for (int kt = 0; kt < 4; ++kt)
#pragma unroll
    for (int ni = 0; ni < 2; ++ni)
#pragma unroll
      for (int r = 0; r < 4; ++r) {
        float s = (sh_[kt][ni][r] + sm_[kt][ni][r] * (1.f / 2048.f)) * (1.f / 12.f);
        sv[kt][ni][r] = s;
        mx[r] = fmaxf(mx[r], s);
      }
#pragma unroll
  for (int r = 0; r < 4; ++r) {
    mx[r] = fmaxf(mx[r], __shfl_xor(mx[r], 1));
    mx[r] = fmaxf(mx[r], __shfl_xor(mx[r], 2));
    mx[r] = fmaxf(mx[r], __shfl_xor(mx[r], 4));
    mx[r] = fmaxf(mx[r], __shfl_xor(mx[r], 8));
  }
  float sum[4] = {0.f, 0.f, 0.f, 0.f};
#pragma unroll
  for (int kt = 0; kt < 4; ++kt)
#pragma unroll
    for (int ni = 0; ni < 2; ++ni)
#pragma unroll
      for (int r = 0; r < 4; ++r) {
        float e = expf(sv[kt][ni][r] - mx[r]);
        sv[kt][ni][r] = e;
        sum[r] += e;
      }
  float inv[4];
#pragma unroll
  for (int r = 0; r < 4; ++r) {
    sum[r] += __shfl_xor(sum[r], 1);
    sum[r] += __shfl_xor(sum[r], 2);
    sum[r] += __shfl_xor(sum[r], 4);
    sum[r] += __shfl_xor(sum[r], 8);
    inv[r] = 1.0f / sum[r];
  }
  // store P hi/lo to LDS (each wave owns its 16 rows; same-wave write->read, no barrier)
#pragma unroll
  for (int kt = 0; kt < 4; ++kt)
#pragma unroll
    for (int ni = 0; ni < 2; ++ni)
#pragma unroll
      for (int r = 0; r < 4; ++r) {
        float p = sv[kt][ni][r] * inv[r];
        int row = wv * 16 + quad * 4 + r;
        int col = kt * 32 + ni * 16 + m16;
        f16 ph = (f16)p;
        Ph[row * 136 + col] = ph;
        Pl[row * 136 + col] = (f16)((p - (float)ph) * 2048.f);
      }
  // ---- PV: o[16 rows x 144] per wave via MFMA, V^T fragments from global ----
  const f16* vbh = vthi + (size_t)(b * NDIM + h * HDIM) * NSC;
  const f16* vbl = vtlo + (size_t)(b * NDIM + h * HDIM) * NSC;
  f32x4 oh_[9], om_[9];
#pragma unroll
  for (int nb = 0; nb < 9; ++nb) { oh_[nb] = zf; om_[nb] = zf; }
#pragma unroll
  for (int ks = 0; ks < 4; ++ks) {
    int po = (wv * 16 + m16) * 136 + ks * 32 + quad * 8;
    f16x8 pah = *(const f16x8*)&Ph[po];
    f16x8 pal = *(const f16x8*)&Pl[po];
#pragma unroll
    for (int nb = 0; nb < 9; ++nb) {
      size_t vo = (size_t)(nb * 16 + m16) * NSC + ks * 32 + quad * 8;
      f16x8 bvh = *(const f16x8*)&vbh[vo];
      f16x8 bvl = *(const f16x8*)&vbl[vo];
      oh_[nb] = MFMA16(pah, bvh, oh_[nb]);
      om_[nb] = MFMA16(pah, bvl, om_[nb]);
      om_[nb] = MFMA16(pal, bvh, om_[nb]);
    }
  }
  // ---- epilogue: split-fp16 o ----
#pragma unroll
  for (int nb = 0; nb < 9; ++nb)
#pragma unroll
    for (int r = 0; r < 4; ++r) {
      int row = mt * 64 + wv * 16 + quad * 4 + r;
      int col = h * HDIM + nb * 16 + m16;
      float v = oh_[nb][r] + om_[nb][r] * (1.f / 2048.f);
      size_t idx = (size_t)(b * NS + row) * NDIM + col;
      f16 hv = (f16)v;
      ohi[idx] = hv;
      olo[idx] = (f16)((v - (float)hv) * 2048.f);
    }
}

// ---------------- ca = o @ out_w^T + out_b  (split-fp16, fp32 out), 2-phase prefetch --
__global__ __launch_bounds__(256) void k_ca(
    const f16* __restrict__ ohi, const f16* __restrict__ olo,
    const float* __restrict__ ow, const float* __restrict__ ob,
    float* __restrict__ ca) {
  int mt = blockIdx.y, nt = blockIdx.x;
  __shared__ f16 Ash[64 * 72];
  __shared__ f16 Asl[64 * 72];
  __shared__ f16 Bsh[64 * 72];
  __shared__ f16 Bsl[64 * 72];
  int t = threadIdx.x;
  int wv = t >> 6, lane = t & 63, m16 = lane & 15, quad = lane >> 4;
  int r0 = t >> 3, ak = (t & 7) * 8;
  size_t a0o = (size_t)(mt * 64 + r0) * NDIM;
  size_t a1o = (size_t)(mt * 64 + r0 + 32) * NDIM;
  f32x4 zf = {0.f, 0.f, 0.f, 0.f};
  f32x4 ah[2][2] = {{zf, zf}, {zf, zf}};
  f32x4 am[2][2] = {{zf, zf}, {zf, zf}};
  uint4 rah0, rah1, ral0, ral1;
  float4 rbw[4];
  rah0 = *(const uint4*)(ohi + a0o + ak);
  rah1 = *(const uint4*)(ohi + a1o + ak);
  ral0 = *(const uint4*)(olo + a0o + ak);
  ral1 = *(const uint4*)(olo + a1o + ak);
#pragma unroll
  for (int uu = 0; uu < 4; ++uu) {
    int u = t + uu * 256;
    int rr = u >> 4, kp = (u & 15) * 4;
    rbw[uu] = *(const float4*)(ow + (size_t)(nt * 64 + rr) * NDIM + kp);
  }
  for (int kc = 0; kc < NDIM; kc += 64) {
    __syncthreads();
    *(uint4*)&Ash[r0 * 72 + ak] = rah0;
    *(uint4*)&Ash[(r0 + 32) * 72 + ak] = rah1;
    *(uint4*)&Asl[r0 * 72 + ak] = ral0;
    *(uint4*)&Asl[(r0 + 32) * 72 + ak] = ral1;
#pragma unroll
    for (int uu = 0; uu < 4; ++uu) {
      int u = t + uu * 256;
      int rr = u >> 4, kp = (u & 15) * 4;
      f16x4 hb, lb;
      hb[0] = (f16)rbw[uu].x; lb[0] = (f16)((rbw[uu].x - (float)hb[0]) * 2048.f);
      hb[1] = (f16)rbw[uu].y; lb[1] = (f16)((rbw[uu].y - (float)hb[1]) * 2048.f);
      hb[2] = (f16)rbw[uu].z; lb[2] = (f16)((rbw[uu].z - (float)hb[2]) * 2048.f);
      hb[3] = (f16)rbw[uu].w; lb[3] = (f16)((rbw[uu].w - (float)hb[3]) * 2048.f);
      *(f16x4*)&Bsh[rr * 72 + kp] = hb;
      *(f16x4*)&Bsl[rr * 72 + kp] = lb;
    }
    __syncthreads();
    int kn = kc + 64;
    if (kn < NDIM) {
      rah0 = *(const uint4*)(ohi + a0o + kn + ak);
      rah1 = *(const uint4*)(ohi + a1o + kn + ak);
      ral0 = *(const uint4*)(olo + a0o + kn + ak);
      ral1 = *(const uint4*)(olo + a1o + kn + ak);
#pragma unroll
      for (int uu = 0; uu < 4; ++uu) {
        int u = t + uu * 256;
        int rr = u >> 4, kp = (u & 15) * 4;
        rbw[uu] = *(const float4*)(ow + (size_t)(nt * 64 + rr) * NDIM + kn + kp);
      }
    }
#pragma unroll
    for (int ks = 0; ks < 2; ++ks) {
      int aoff = ((wv & 1) * 32 + m16) * 72 + ks * 32 + quad * 8;
      int boff = ((wv >> 1) * 32 + m16) * 72 + ks * 32 + quad * 8;
      f16x8 a0h = *(const f16x8*)&Ash[aoff];
      f16x8 a1h = *(const f16x8*)&Ash[aoff + 16 * 72];
      f16x8 a0l = *(const f16x8*)&Asl[aoff];
      f16x8 a1l = *(const f16x8*)&Asl[aoff + 16 * 72];
      f16x8 b0h = *(const f16x8*)&Bsh[boff];
      f16x8 b1h = *(const f16x8*)&Bsh[boff + 16 * 72];
      f16x8 b0l = *(const f16x8*)&Bsl[boff];
      f16x8 b1l = *(const f16x8*)&Bsl[boff + 16 * 72];
      ah[0][0] = MFMA16(a0h, b0h, ah[0][0]);
      ah[0][1] = MFMA16(a0h, b1h, ah[0][1]);
      ah[1][0] = MFMA16(a1h, b0h, ah[1][0]);
      ah[1][1] = MFMA16(a1h, b1h, ah[1][1]);
      am[0][0] = MFMA16(a0h, b0l, am[0][0]);
      am[0][1] = MFMA16(a0h, b1l, am[0][1]);
      am[1][0] = MFMA16(a1h, b0l, am[1][0]);
      am[1][1] = MFMA16(a1h, b1l, am[1][1]);
      am[0][0] = MFMA16(a0l, b0h, am[0][0]);
      am[0][1] = MFMA16(a0l, b1h, am[0][1]);
      am[1][0] = MFMA16(a1l, b0h, am[1][0]);
      am[1][1] = MFMA16(a1l, b1h, am[1][1]);
    }
  }
#pragma unroll
  for (int mi = 0; mi < 2; ++mi)
#pragma unroll
    for (int ni = 0; ni < 2; ++ni)
#pragma unroll
      for (int r = 0; r < 4; ++r) {
        int row = mt * 64 + (wv & 1) * 32 + mi * 16 + quad * 4 + r;
        int col = nt * 64 + (wv >> 1) * 32 + ni * 16 + m16;
        ca[(size_t)row * NDIM + col] =
            ah[mi][ni][r] + am[mi][ni][r] * (1.f / 2048.f) + ob[col];
      }
}

// ---------------- routing: argmax gates, cm/am, lists, loss ----------------
__global__ __launch_bounds__(1024) void k_route(
    const float* __restrict__ cl, const float* __restrict__ al,
    const float* __restrict__ g1, const float* __restrict__ g2,
    const float* __restrict__ g3, const float* __restrict__ tl,
    float* __restrict__ cmv, float* __restrict__ amv,
    int* __restrict__ lists, int* __restrict__ counts, float* __restrict__ out_loss) {
  __shared__ int lcnt[8];
  __shared__ float bins[8];
  __shared__ float ssum[2];
  int t = threadIdx.x;
  if (t < 8) { lcnt[t] = 0; bins[t] = 0.f; }
  if (t < 2) ssum[t] = 0.f;
  __syncthreads();
  for (int n = t; n < NTOK; n += 1024) {
    float lc[NEXP];
#pragma unroll
    for (int e = 0; e < NEXP; ++e) lc[e] = cl[n * NEXP + e] + g2[n * 4 + e];
    int ec = 0; float bv = lc[0];
#pragma unroll
    for (int e = 1; e < NEXP; ++e) if (lc[e] > bv) { bv = lc[e]; ec = e; }
    float la[NEXP];
#pragma unroll
    for (int e = 0; e < NEXP; ++e) la[e] = al[n * NEXP + e] + g3[n * 4 + e];
    int ea = 0; float bva = la[0];
#pragma unroll
    for (int e = 1; e < NEXP; ++e) if (la[e] > bva) { bva = la[e]; ea = e; }
    int b = n >> 10;
    float a0 = tl[b * 2 + 0] + g1[n * 2 + 0];
    float a1 = tl[b * 2 + 1] + g1[n * 2 + 1];
    float mx = fmaxf(a0, a1);
    float e0 = expf(a0 - mx), e1 = expf(a1 - mx);
    float cm = e0 / (e0 + e1), am = e1 / (e0 + e1);
    cmv[n] = cm; amv[n] = am;
    int p0 = atomicAdd(&lcnt[ec], 1);
    lists[ec * NTOK + p0] = n;
    int p1 = atomicAdd(&lcnt[4 + ea], 1);
    lists[(4 + ea) * NTOK + p1] = n;
    atomicAdd(&bins[ec], cm);
    atomicAdd(&bins[4 + ea], am);
    atomicAdd(&ssum[0], cm);
    atomicAdd(&ssum[1], am);
  }
  __syncthreads();
  if (t < 8) counts[t] = lcnt[t];
  if (t == 0) {
    float denom = 4.f * (ssum[0] + ssum[1]) + 1e-10f;
    float acc = 0.f;
    for (int j = 0; j < 8; ++j) {
      float u = bins[j] / denom;
      acc += u * logf(u + 1e-10f);
    }
    out_loss[0] = acc / 8.f;
  }
}

// ---------------- GEMM1: M-tile 128, dual-B (w1,w3) + silu*mul -> t16, 2-phase --------
__global__ __launch_bounds__(256) void k_gemm1(
    const f16* __restrict__ x16, const f16* __restrict__ y16,
    const float* __restrict__ cw1, const float* __restrict__ cw3,
    const float* __restrict__ aw1, const float* __restrict__ aw3,
    const float* __restrict__ fw1, const float* __restrict__ fw3,
    const int* __restrict__ lists, const int* __restrict__ counts,
    f16* __restrict__ tbuf, int gbase) {
  int g = blockIdx.z + gbase;
  int mt = blockIdx.y, nt = blockIdx.x;
  const f16* A; const float* B1; const float* B3; f16* tout;
  const int* list = nullptr;
  int cnt, koff, K;
  if (g < 8) {
    int e = g & 3;
    cnt = counts[g];
    list = lists + g * NTOK;
    A = x16; koff = 0; K = NDIM;
    const float* w1s = (g < 4) ? cw1 : aw1;
    const float* w3s = (g < 4) ? cw3 : aw3;
    B1 = w1s + (size_t)e * NHID * NDIM;
    B3 = w3s + (size_t)e * NHID * NDIM;
    tout = tbuf + (size_t)g * NTOK * NHID;
  } else {
    int e = g - 8;
    cnt = NTOK;
    A = y16; koff = e * 288; K = 288;
    B1 = fw1 + (size_t)e * NHID * NDIM + koff;
    B3 = fw3 + (size_t)e * NHID * NDIM + koff;
    tout = tbuf + (size_t)e * NTOK * NHID;
  }
  if (mt * 128 >= cnt) return;
  int t = threadIdx.x;
  int wv = t >> 6, lane = t & 63, m16 = lane & 15, quad = lane >> 4;
  int r0 = t >> 3, ak = (t & 7) * 8;
  const f16* arj[4];
#pragma unroll
  for (int j = 0; j < 4; ++j) {
    int m = mt * 128 + r0 + 32 * j;
    int tok = list ? list[min(m, cnt - 1)] : min(m, cnt - 1);
    arj[j] = A + (size_t)tok * NDIM + koff;
  }
  __shared__ f16 As[128 * 72];
  __shared__ f16 Bs1[64 * 72];
  __shared__ f16 Bs2[64 * 72];
  f32x4 zf = {0.f, 0.f, 0.f, 0.f};
  f32x4 ac1[2][4], ac2[2][4];
#pragma unroll
  for (int mi = 0; mi < 2; ++mi)
#pragma unroll
    for (int ni = 0; ni < 4; ++ni) { ac1[mi][ni] = zf; ac2[mi][ni] = zf; }
  uint4 ra[4];
  float4 rb1[4], rb3[4];
  uint4 z4u = make_uint4(0u, 0u, 0u, 0u);
  float4 z4f = make_float4(0.f, 0.f, 0.f, 0.f);
#pragma unroll
  for (int j = 0; j < 4; ++j) ra[j] = (ak < K) ? *(const uint4*)(arj[j] + ak) : z4u;
#pragma unroll
  for (int uu = 0; uu < 4; ++uu) {
    int u = t + uu * 256;
    int rr = u >> 4, kp = (u & 15) * 4;
    rb1[uu] = (kp < K) ? *(const float4*)(B1 + (size_t)(nt * 64 + rr) * NDIM + kp) : z4f;
    rb3[uu] = (kp < K) ? *(const float4*)(B3 + (size_t)(nt * 64 + rr) * NDIM + kp) : z4f;
  }
  for (int kc = 0; kc < K; kc += 64) {
    __syncthreads();
#pragma unroll
    for (int j = 0; j < 4; ++j) *(uint4*)&As[(r0 + 32 * j) * 72 + ak] = ra[j];
#pragma unroll
    for (int uu = 0; uu < 4; ++uu) {
      int u = t + uu * 256;
      int rr = u >> 4, kp = (u & 15) * 4;
      f16x4 h1, h3;
      h1[0] = (f16)rb1[uu].x; h1[1] = (f16)rb1[uu].y; h1[2] = (f16)rb1[uu].z; h1[3] = (f16)rb1[uu].w;
      h3[0] = (f16)rb3[uu].x; h3[1] = (f16)rb3[uu].y; h3[2] = (f16)rb3[uu].z; h3[3] = (f16)rb3[uu].w;
      *(f16x4*)&Bs1[rr * 72 + kp] = h1;
      *(f16x4*)&Bs2[rr * 72 + kp] = h3;
    }
    __syncthreads();
    int kn = kc + 64;
    if (kn < K) {
#pragma unroll
      for (int j = 0; j < 4; ++j)
        ra[j] = (kn + ak < K) ? *(const uint4*)(arj[j] + kn + ak) : z4u;
#pragma unroll
      for (int uu = 0; uu < 4; ++uu) {
        int u = t + uu * 256;
        int rr = u >> 4, kp = (u & 15) * 4;
        rb1[uu] = (kn + kp < K) ? *(const float4*)(B1 + (size_t)(nt * 64 + rr) * NDIM + kn + kp) : z4f;
        rb3[uu] = (kn + kp < K) ? *(const float4*)(B3 + (size_t)(nt * 64 + rr) * NDIM + kn + kp) : z4f;
      }
    }
#pragma unroll
    for (int ks = 0; ks < 2; ++ks) {
      f16x8 af[2], b1f[4], b3f[4];
#pragma unroll
      for (int mi = 0; mi < 2; ++mi)
        af[mi] = *(const f16x8*)&As[(wv * 32 + mi * 16 + m16) * 72 + ks * 32 + quad * 8];
#pragma unroll
      for (int ni = 0; ni < 4; ++ni) {
        b1f[ni] = *(const f16x8*)&Bs1[(ni * 16 + m16) * 72 + ks * 32 + quad * 8];
        b3f[ni] = *(const f16x8*)&Bs2[(ni * 16 + m16) * 72 + ks * 32 + quad * 8];
      }
#pragma unroll
      for (int mi = 0; mi < 2; ++mi)
#pragma unroll
        for (int ni = 0; ni < 4; ++ni) {
          ac1[mi][ni] = MFMA16(af[mi], b1f[ni], ac1[mi][ni]);
          ac2[mi][ni] = MFMA16(af[mi], b3f[ni], ac2[mi][ni]);
        }
    }
  }
#pragma unroll
  for (int mi = 0; mi < 2; ++mi)
#pragma unroll
    for (int ni = 0; ni < 4; ++ni)
#pragma unroll
      for (int r = 0; r < 4; ++r) {
        int row = mt * 128 + wv * 32 + mi * 16 + quad * 4 + r;
        int col = nt * 64 + ni * 16 + m16;
        float h1 = ac1[mi][ni][r];
        float h3 = ac2[mi][ni][r];
        float sl = h1 / (1.0f + expf(-h1));
        tout[(size_t)row * NHID + col] = (f16)(sl * h3);
      }
}

// ---------------- GEMM2 (MoE): t16 @ w2^T * cm/am -> ybc/yba (pure write), 2-phase ----
__global__ __launch_bounds__(256) void k_gemm2(
    const f16* __restrict__ tbuf, const float* __restrict__ cw2, const float* __restrict__ aw2,
    const int* __restrict__ lists, const int* __restrict__ counts,
    const float* __restrict__ cmv, const float* __restrict__ amv,
    float* __restrict__ yc, float* __restrict__ ya) {
  int g = blockIdx.z;
  int e = g & 3;
  int mt = blockIdx.y, nt = blockIdx.x;
  int cnt = counts[g];
  if (mt * 64 >= cnt) return;
  const int* list = lists + g * NTOK;
  const f16* A = tbuf + (size_t)g * NTOK * NHID;
  const float* Bw = ((g < 4) ? cw2 : aw2) + (size_t)e * NDIM * NHID;
  const float* sc = (g < 4) ? cmv : amv;
  float* y = (g < 4) ? yc : ya;
  int t = threadIdx.x;
  int wv = t >> 6, lane = t & 63, m16 = lane & 15, quad = lane >> 4;
  int r0 = t >> 3, ak = (t & 7) * 8;
  const f16* ar0 = A + (size_t)(mt * 64 + r0) * NHID;
  const f16* ar1 = A + (size_t)(mt * 64 + r0 + 32) * NHID;
  __shared__ f16 As[64 * 72];
  __shared__ f16 Bs[64 * 72];
  f32x4 zf = {0.f, 0.f, 0.f, 0.f};
  f32x4 acc[2][2] = {{zf, zf}, {zf, zf}};
  uint4 ra0, ra1;
  float4 rb[4];
  ra0 = *(const uint4*)(ar0 + ak);
  ra1 = *(const uint4*)(ar1 + ak);
#pragma unroll
  for (int uu = 0; uu < 4; ++uu) {
    int u = t + uu * 256;
    int rr = u >> 4, kp = (u & 15) * 4;
    rb[uu] = *(const float4*)(Bw + (size_t)(nt * 64 + rr) * NHID + kp);
  }
  for (int kc = 0; kc < NHID; kc += 64) {
    __syncthreads();
    *(uint4*)&As[r0 * 72 + ak] = ra0;
    *(uint4*)&As[(r0 + 32) * 72 + ak] = ra1;
#pragma unroll
    for (int uu = 0; uu < 4; ++uu) {
      int u = t + uu * 256;
      int rr = u >> 4, kp = (u & 15) * 4;
      f16x4 hb;
      hb[0] = (f16)rb[uu].x; hb[1] = (f16)rb[uu].y; hb[2] = (f16)rb[uu].z; hb[3] = (f16)rb[uu].w;
      *(f16x4*)&Bs[rr * 72 + kp] = hb;
    }
    __syncthreads();
    int kn = kc + 64;
    if (kn < NHID) {
      ra0 = *(const uint4*)(ar0 + kn + ak);
      ra1 = *(const uint4*)(ar1 + kn + ak);
#pragma unroll
      for (int uu = 0; uu < 4; ++uu) {
        int u = t + uu * 256;
        int rr = u >> 4, kp = (u & 15) * 4;
        rb[uu] = *(const float4*)(Bw + (size_t)(nt * 64 + rr) * NHID + kn + kp);
      }
    }
#pragma unroll
    for (int ks = 0; ks < 2; ++ks) {
      int aoff = ((wv & 1) * 32 + m16) * 72 + ks * 32 + quad * 8;
      int boff = ((wv >> 1) * 32 + m16) * 72 + ks * 32 + quad * 8;
      f16x8 a0 = *(const f16x8*)&As[aoff];
      f16x8 a1 = *(const f16x8*)&As[aoff + 16 * 72];
      f16x8 b0 = *(const f16x8*)&Bs[boff];
      f16x8 b1 = *(const f16x8*)&Bs[boff + 16 * 72];
      acc[0][0] = MFMA16(a0, b0, acc[0][0]);
      acc[0][1] = MFMA16(a0, b1, acc[0][1]);
      acc[1][0] = MFMA16(a1, b0, acc[1][0]);
      acc[1][1] = MFMA16(a1, b1, acc[1][1]);
    }
  }
#pragma unroll
  for (int mi = 0; mi < 2; ++mi)
#pragma unroll
    for (int ni = 0; ni < 2; ++ni)
#pragma unroll
      for (int r = 0; r < 4; ++r) {
        int mg = mt * 64 + (wv & 1) * 32 + mi * 16 + quad * 4 + r;
        if (mg < cnt) {
          int tok = list[mg];
          int col = nt * 64 + (wv >> 1) * 32 + ni * 16 + m16;
          float v = acc[mi][ni][r] * sc[tok];
          y[(size_t)tok * NDIM + col] = v;
        }
      }
}

// ---------------- GEMM2 (fr): t16 @ fr_w2[e][e*288:(e+1)*288,:]^T -> z slice, 2-phase -
__global__ __launch_bounds__(256) void k_gemm2_fr(
    const f16* __restrict__ tbuf, const float* __restrict__ fw2, float* __restrict__ zz) {
  int e = blockIdx.z;
  int mt = blockIdx.y, nt = blockIdx.x;
  const f16* A = tbuf + (size_t)e * NTOK * NHID;
  const float* Bw = fw2 + (size_t)e * NDIM * NHID;
  int t = threadIdx.x;
  int wv = t >> 6, lane = t & 63, m16 = lane & 15, quad = lane >> 4;
  int r0 = t >> 3, ak = (t & 7) * 8;
  const f16* ar0 = A + (size_t)(mt * 64 + r0) * NHID;
  const f16* ar1 = A + (size_t)(mt * 64 + r0 + 32) * NHID;
  __shared__ f16 As[64 * 72];
  __shared__ f16 Bs[64 * 72];
  f32x4 zf = {0.f, 0.f, 0.f, 0.f};
  f32x4 acc[2][2] = {{zf, zf}, {zf, zf}};
  uint4 ra0, ra1;
  float4 rb[4];
  ra0 = *(const uint4*)(ar0 + ak);
  ra1 = *(const uint4*)(ar1 + ak);
#pragma unroll
  for (int uu = 0; uu < 4; ++uu) {
    int u = t + uu * 256;
    int rr = u >> 4, kp = (u & 15) * 4;
    int ne = min(nt * 64 + rr, 287);
    rb[uu] = *(const float4*)(Bw + (size_t)(e * 288 + ne) * NHID + kp);
  }
  for (int kc = 0; kc < NHID; kc += 64) {
    __syncthreads();
    *(uint4*)&As[r0 * 72 + ak] = ra0;
    *(uint4*)&As[(r0 + 32) * 72 + ak] = ra1;
#pragma unroll
    for (int uu = 0; uu < 4; ++uu) {
      int u = t + uu * 256;
      int rr = u >> 4, kp = (u & 15) * 4;
      f16x4 hb;
      hb[0] = (f16)rb[uu].x; hb[1] = (f16)rb[uu].y; hb[2] = (f16)rb[uu].z; hb[3] = (f16)rb[uu].w;
      *(f16x4*)&Bs[rr * 72 + kp] = hb;
    }
    __syncthreads();
    int kn = kc + 64;
    if (kn < NHID) {
      ra0 = *(const uint4*)(ar0 + kn + ak);
      ra1 = *(const uint4*)(ar1 + kn + ak);
#pragma unroll
      for (int uu = 0; uu < 4; ++uu) {
        int u = t + uu * 256;
        int rr = u >> 4, kp = (u & 15) * 4;
        int ne = min(nt * 64 + rr, 287);
        rb[uu] = *(const float4*)(Bw + (size_t)(e * 288 + ne) * NHID + kn + kp);
      }
    }
#pragma unroll
    for (int ks = 0; ks < 2; ++ks) {
      int aoff = ((wv & 1) * 32 + m16) * 72 + ks * 32 + quad * 8;
      int boff = ((wv >> 1) * 32 + m16) * 72 + ks * 32 + quad * 8;
      f16x8 a0 = *(const f16x8*)&As[aoff];
      f16x8 a1 = *(const f16x8*)&As[aoff + 16 * 72];
      f16x8 b0 = *(const f16x8*)&Bs[boff];
      f16x8 b1 = *(const f16x8*)&Bs[boff + 16 * 72];
      acc[0][0] = MFMA16(a0, b0, acc[0][0]);
      acc[0][1] = MFMA16(a0, b1, acc[0][1]);
      acc[1][0] = MFMA16(a1, b0, acc[1][0]);
      acc[1][1] = MFMA16(a1, b1, acc[1][1]);
    }
  }
#pragma unroll
  for (int mi = 0; mi < 2; ++mi)
#pragma unroll
    for (int ni = 0; ni < 2; ++ni)
#pragma unroll
      for (int r = 0; r < 4; ++r) {
        int cg = nt * 64 + (wv >> 1) * 32 + ni * 16 + m16;
        if (cg < 288) {
          int row = mt * 64 + (wv & 1) * 32 + mi * 16 + quad * 4 + r;
          zz[(size_t)row * NDIM + e * 288 + cg] = acc[mi][ni][r];
        }
      }
}

// ---------------- host ----------------
extern "C" void kernel_launch(void* const* d_in, const int* in_sizes, int n_in,
                              void* d_out, int out_size, void* d_ws, size_t ws_size,
                              hipStream_t stream) {
  const float* x          = (const float*)d_in[0];
  const float* timep      = (const float*)d_in[1];
  const float* caption    = (const float*)d_in[2];
  const float* acoustic   = (const float*)d_in[3];
  const float* attn_in_w  = (const float*)d_in[4];
  const float* attn_in_b  = (const float*)d_in[5];
  const float* attn_out_w = (const float*)d_in[6];
  const float* attn_out_b = (const float*)d_in[7];
  const float* hl_w       = (const float*)d_in[8];
  const float* hl_b       = (const float*)d_in[9];
  const float* cap_gate_w = (const float*)d_in[10];
  const float* cap_gate_b = (const float*)d_in[11];
  const float* ac_gate_w  = (const float*)d_in[12];
  const float* ac_gate_b  = (const float*)d_in[13];
  const float* cap_w1     = (const float*)d_in[14];
  const float* cap_w2     = (const float*)d_in[15];
  const float* cap_w3     = (const float*)d_in[16];
  const float* ac_w1      = (const float*)d_in[17];
  const float* ac_w2      = (const float*)d_in[18];
  const float* ac_w3      = (const float*)d_in[19];
  const float* fr_w1      = (const float*)d_in[20];
  const float* fr_w2      = (const float*)d_in[21];
  const float* fr_w3      = (const float*)d_in[22];
  (void)in_sizes; (void)n_in; (void)out_size; (void)ws_size;

  float* zout = (float*)d_out;
  float* loss = zout + (size_t)NTOK * NDIM;

  char* wsb = (char*)d_ws;
  size_t off = 0;
  auto alloc = [&](size_t bytes) -> void* {
    void* p = wsb + off;
    off = (off + bytes + 255) & ~(size_t)255;
    return p;
  };
  // persistent small + xhi
  float* g1     = (float*)alloc(4096 * 4);
  float* g2     = (float*)alloc(8192 * 4);
  float* g3     = (float*)alloc(8192 * 4);
  float* tl     = (float*)alloc(4 * 4);
  float* al     = (float*)alloc((size_t)NTOK * NEXP * 4);
  float* cl     = (float*)alloc((size_t)NTOK * NEXP * 4);
  float* cmv    = (float*)alloc((size_t)NTOK * 4);
  float* amv    = (float*)alloc((size_t)NTOK * 4);
  int*   lists  = (int*)alloc((size_t)8 * NTOK * 4);
  int*   counts = (int*)alloc(8 * 4);
  f16*   xhi    = (f16*)alloc((size_t)NTOK * NDIM * 2);
  size_t region = off;
  // phase 1 (attention / routing inputs)
  f16*   xlo    = (f16*)alloc((size_t)NTOK * NDIM * 2);
  f16*   caphi  = (f16*)alloc((size_t)NCAP * NDIM * 2);
  f16*   caplo  = (f16*)alloc((size_t)NCAP * NDIM * 2);
  f16*   qhi    = (f16*)alloc((size_t)NTOK * NDIM * 2);
  f16*   qlo    = (f16*)alloc((size_t)NTOK * NDIM * 2);
  f16*   khi    = (f16*)alloc((size_t)NCAP * NDIM * 2);
  f16*   klo    = (f16*)alloc((size_t)NCAP * NDIM * 2);
  f16*   vthi   = (f16*)alloc((size_t)NB * NDIM * NSC * 2);
  f16*   vtlo   = (f16*)alloc((size_t)NB * NDIM * NSC * 2);
  f16*   ohi    = (f16*)alloc((size_t)NTOK * NDIM * 2);
  f16*   olo    = (f16*)alloc((size_t)NTOK * NDIM * 2);
  float* ca32   = (float*)alloc((size_t)NTOK * NDIM * 4);
  // phase 2 (MoE / fr) — reuses phase-1 region (all phase-1 buffers dead)
  off = region;
  f16*   tbuf   = (f16*)alloc((size_t)8 * NTOK * NHID * 2);
  float* ybc    = (float*)alloc((size_t)NTOK * NDIM * 4);
  float* yba    = (float*)alloc((size_t)NTOK * NDIM * 4);
  f16*   y16    = (f16*)alloc((size_t)NTOK * NDIM * 2);

  k_prep<<<dim3(1), dim3(256), 0, stream>>>(timep, hl_w, hl_b, g1, g2, g3, tl);
  k_ac_logits<<<dim3(512), dim3(256), 0, stream>>>(acoustic, ac_gate_w, ac_gate_b, al);
  k_cvt_split<<<dim3(2304), dim3(256), 0, stream>>>(x, xhi, xlo, NTOK * NDIM);
  k_cvt_split<<<dim3(288), dim3(256), 0, stream>>>(caption, caphi, caplo, NCAP * NDIM);
  k_gemm_qkv<<<dim3(18, 32, 3), dim3(256), 0, stream>>>(xhi, xlo, caphi, caplo,
                                                        attn_in_w, attn_in_b,
                                                        qhi, qlo, khi, klo, vthi, vtlo);
  k_attn<<<dim3(16, 16), dim3(256), 0, stream>>>(qhi, qlo, khi, klo, vthi, vtlo, ohi, olo);
  k_ca<<<dim3(18, 32), dim3(256), 0, stream>>>(ohi, olo, attn_out_w, attn_out_b, ca32);
  k_ac_logits<<<dim3(512), dim3(256), 0, stream>>>(ca32, cap_gate_w, cap_gate_b, cl);
  k_route<<<dim3(1), dim3(1024), 0, stream>>>(cl, al, g1, g2, g3, tl,
                                              cmv, amv, lists, counts, loss);
  k_gemm1<<<dim3(12, 16, 8), dim3(256), 0, stream>>>(xhi, y16, cap_w1, cap_w3, ac_w1, ac_w3,
                                                     fr_w1, fr_w3, lists, counts, tbuf, 0);
  k_gemm2<<<dim3(18, 32, 8), dim3(256), 0, stream>>>(tbuf, cap_w2, ac_w2, lists, counts,
                                                     cmv, amv, ybc, yba);
  k_cvt_add<<<dim3(2304), dim3(256), 0, stream>>>(ybc, yba, y16, NTOK * NDIM);
  k_gemm1<<<dim3(12, 16, 4), dim3(256), 0, stream>>>(xhi, y16, cap_w1, cap_w3, ac_w1, ac_w3,
                                                     fr_w1, fr_w3, lists, counts, tbuf, 8);
  k_gemm2_fr<<<dim3(5, 32, 4), dim3(256), 0, stream>>>(tbuf, fr_w2, zout);
}

// Round 3
// 491.357 us; speedup vs baseline: 1.2057x; 1.0702x over previous
//
#include <hip/hip_runtime.h>
#include <stdint.h>

#define NDIM 1152
#define NEXP 4
#define NHID 768
#define NHEAD 8
#define HDIM 144
#define NB 2
#define NS 1024
#define NSC 128
#define NTOK 2048
#define NCAP 256

typedef _Float16 f16;
typedef _Float16 f16x4 __attribute__((ext_vector_type(4)));
typedef _Float16 f16x8 __attribute__((ext_vector_type(8)));
typedef float f32x4 __attribute__((ext_vector_type(4)));

#define MFMA16(a, b, c) __builtin_amdgcn_mfma_f32_16x16x32_f16(a, b, c, 0, 0, 0)

#define WSZ ((size_t)NEXP * NHID * NDIM)  // elems per weight tensor (3,538,944)

// ---------------- Threefry2x32 (exact JAX replication) ----------------
__device__ inline uint2 tfry(uint32_t k0, uint32_t k1, uint32_t x0, uint32_t x1) {
  uint32_t k2 = k0 ^ k1 ^ 0x1BD11BDAu;
#define RND(r) { x0 += x1; x1 = (x1 << r) | (x1 >> (32 - r)); x1 ^= x0; }
  x0 += k0; x1 += k1;
  RND(13) RND(15) RND(26) RND(6)
  x0 += k1; x1 += k2 + 1u;
  RND(17) RND(29) RND(16) RND(24)
  x0 += k2; x1 += k0 + 2u;
  RND(13) RND(15) RND(26) RND(6)
  x0 += k0; x1 += k1 + 3u;
  RND(17) RND(29) RND(16) RND(24)
  x0 += k1; x1 += k2 + 4u;
  RND(13) RND(15) RND(26) RND(6)
  x0 += k2; x1 += k0 + 5u;
#undef RND
  return make_uint2(x0, x1);
}

__device__ inline float b2g(uint32_t bits) {
  uint32_t fb = (bits >> 9) | 0x3f800000u;
  float f = __uint_as_float(fb) - 1.0f;
  const float tiny = 1.1754943508222875e-38f;
  float u = f * 1.0f + tiny;
  u = fmaxf(tiny, u);
  return -logf(-logf(u));
}

// ---------------- prep: keys, gumbels, time-logits ----------------
__global__ void k_prep(const float* __restrict__ timep, const float* __restrict__ hlw,
                       const float* __restrict__ hlb,
                       float* __restrict__ g1, float* __restrict__ g2, float* __restrict__ g3,
                       float* __restrict__ tl) {
  int t = threadIdx.x;  // 256
  uint2 k1 = tfry(0u, 42u, 0u, 0u);
  uint2 k2 = tfry(0u, 42u, 0u, 1u);
  uint2 k3 = tfry(0u, 42u, 0u, 2u);
  for (int p = t; p < 4096; p += 256) {
    uint2 o = tfry(k1.x, k1.y, 0u, (uint32_t)p);
    g1[p] = b2g(o.x ^ o.y);
  }
  for (int p = t; p < 8192; p += 256) {
    uint2 o2 = tfry(k2.x, k2.y, 0u, (uint32_t)p);
    g2[p] = b2g(o2.x ^ o2.y);
    uint2 o3 = tfry(k3.x, k3.y, 0u, (uint32_t)p);
    g3[p] = b2g(o3.x ^ o3.y);
  }
  int wv = t >> 6, lane = t & 63;
  {
    int b = wv >> 1, j = wv & 1;
    float s = 0.f;
    for (int k = lane; k < NDIM; k += 64) s += timep[b * NDIM + k] * hlw[j * NDIM + k];
    for (int m = 32; m; m >>= 1) s += __shfl_xor(s, m);
    if (lane == 0) tl[b * 2 + j] = s + hlb[j];
  }
}

// ---------------- generic 4-logit head: out[n,e] = in[n,:]·w[e,:] + b[e] ----------------
__global__ void k_ac_logits(const float* __restrict__ ac, const float* __restrict__ agw,
                            const float* __restrict__ agb, float* __restrict__ al) {
  int wv = threadIdx.x >> 6, lane = threadIdx.x & 63;
  int n = blockIdx.x * 4 + wv;
  float s[NEXP] = {0.f, 0.f, 0.f, 0.f};
  for (int d = lane; d < NDIM; d += 64) {
    float a = ac[(size_t)n * NDIM + d];
#pragma unroll
    for (int e = 0; e < NEXP; ++e) s[e] += a * agw[e * NDIM + d];
  }
#pragma unroll
  for (int e = 0; e < NEXP; ++e)
    for (int m = 32; m; m >>= 1) s[e] += __shfl_xor(s[e], m);
  if (lane == 0) {
#pragma unroll
    for (int e = 0; e < NEXP; ++e) al[n * NEXP + e] = s[e] + agb[e];
  }
}

// ---------------- weight preconversion: 9 tensors f32 -> f16 ----------------
__global__ void k_cvt_w(const float* __restrict__ s0, const float* __restrict__ s1,
                        const float* __restrict__ s2, const float* __restrict__ s3,
                        const float* __restrict__ s4, const float* __restrict__ s5,
                        const float* __restrict__ s6, const float* __restrict__ s7,
                        const float* __restrict__ s8, f16* __restrict__ dst) {
  int slot = blockIdx.y;
  const float* src;
  switch (slot) {
    case 0: src = s0; break; case 1: src = s1; break; case 2: src = s2; break;
    case 3: src = s3; break; case 4: src = s4; break; case 5: src = s5; break;
    case 6: src = s6; break; case 7: src = s7; break; default: src = s8; break;
  }
  size_t i = ((size_t)blockIdx.x * 256 + threadIdx.x) * 4;
  if (i + 3 < WSZ) {
    float4 v = *(const float4*)(src + i);
    f16x4 h; h[0] = (f16)v.x; h[1] = (f16)v.y; h[2] = (f16)v.z; h[3] = (f16)v.w;
    *(f16x4*)(dst + slot * WSZ + i) = h;
  }
}

// ---------------- fp32 + fp32 -> fp16 convert (fused add) ----------------
__global__ void k_cvt_add(const float* __restrict__ srca, const float* __restrict__ srcb,
                          f16* __restrict__ dst, int n) {
  int i = (blockIdx.x * 256 + threadIdx.x) * 4;
  if (i + 3 < n) {
    float4 va = *(const float4*)(srca + i);
    float4 vb = *(const float4*)(srcb + i);
    f16x4 h;
    h[0] = (f16)(va.x + vb.x); h[1] = (f16)(va.y + vb.y);
    h[2] = (f16)(va.z + vb.z); h[3] = (f16)(va.w + vb.w);
    *(f16x4*)(dst + i) = h;
  }
}

// ---------------- fp32 -> fp16 hi/lo split convert (lo pre-scaled by 2048) ----------------
__global__ void k_cvt_split(const float* __restrict__ src, f16* __restrict__ hi,
                            f16* __restrict__ lo, int n) {
  int i = (blockIdx.x * 256 + threadIdx.x) * 4;
  if (i + 3 < n) {
    float4 v = *(const float4*)(src + i);
    f16x4 h, l;
    h[0] = (f16)v.x; l[0] = (f16)((v.x - (float)h[0]) * 2048.f);
    h[1] = (f16)v.y; l[1] = (f16)((v.y - (float)h[1]) * 2048.f);
    h[2] = (f16)v.z; l[2] = (f16)((v.z - (float)h[2]) * 2048.f);
    h[3] = (f16)v.w; l[3] = (f16)((v.w - (float)h[3]) * 2048.f);
    *(f16x4*)(hi + i) = h;
    *(f16x4*)(lo + i) = l;
  }
}

// ---------------- QKV projection, split-fp16 (~fp32 accurate), 2-phase prefetch ------
// z==2 (V) emits transposed split-fp16: vT[b][dd (0..1151)][kv (0..127)]
__global__ __launch_bounds__(256) void k_gemm_qkv(
    const f16* __restrict__ xhi, const f16* __restrict__ xlo,
    const f16* __restrict__ caphi, const f16* __restrict__ caplo,
    const float* __restrict__ inw, const float* __restrict__ inb,
    f16* __restrict__ qhi, f16* __restrict__ qlo,
    f16* __restrict__ khi, f16* __restrict__ klo,
    f16* __restrict__ vthi, f16* __restrict__ vtlo) {
  int z = blockIdx.z;
  int M = (z == 0) ? NTOK : NCAP;
  int mt = blockIdx.y, nt = blockIdx.x;
  if (mt * 64 >= M) return;
  const f16* Ah_g = (z == 0) ? xhi : caphi;
  const f16* Al_g = (z == 0) ? xlo : caplo;
  __shared__ f16 Ash[64 * 72];
  __shared__ f16 Asl[64 * 72];
  __shared__ f16 Bsh[64 * 72];
  __shared__ f16 Bsl[64 * 72];
  int t = threadIdx.x;
  int wv = t >> 6, lane = t & 63, m16 = lane & 15, quad = lane >> 4;
  int r0 = t >> 3, ak = (t & 7) * 8;
  size_t a0o = (size_t)(mt * 64 + r0) * NDIM;
  size_t a1o = (size_t)(mt * 64 + r0 + 32) * NDIM;
  f32x4 zf = {0.f, 0.f, 0.f, 0.f};
  f32x4 ah[2][2] = {{zf, zf}, {zf, zf}};
  f32x4 am[2][2] = {{zf, zf}, {zf, zf}};
  uint4 rah0, rah1, ral0, ral1;
  float4 rbw[4];
  rah0 = *(const uint4*)(Ah_g + a0o + ak);
  rah1 = *(const uint4*)(Ah_g + a1o + ak);
  ral0 = *(const uint4*)(Al_g + a0o + ak);
  ral1 = *(const uint4*)(Al_g + a1o + ak);
#pragma unroll
  for (int uu = 0; uu < 4; ++uu) {
    int u = t + uu * 256;
    int rr = u >> 4, kp = (u & 15) * 4;
    rbw[uu] = *(const float4*)(inw + (size_t)(z * NDIM + nt * 64 + rr) * NDIM + kp);
  }
  for (int kc = 0; kc < NDIM; kc += 64) {
    __syncthreads();
    *(uint4*)&Ash[r0 * 72 + ak] = rah0;
    *(uint4*)&Ash[(r0 + 32) * 72 + ak] = rah1;
    *(uint4*)&Asl[r0 * 72 + ak] = ral0;
    *(uint4*)&Asl[(r0 + 32) * 72 + ak] = ral1;
#pragma unroll
    for (int uu = 0; uu < 4; ++uu) {
      int u = t + uu * 256;
      int rr = u >> 4, kp = (u & 15) * 4;
      f16x4 hb, lb;
      hb[0] = (f16)rbw[uu].x; lb[0] = (f16)((rbw[uu].x - (float)hb[0]) * 2048.f);
      hb[1] = (f16)rbw[uu].y; lb[1] = (f16)((rbw[uu].y - (float)hb[1]) * 2048.f);
      hb[2] = (f16)rbw[uu].z; lb[2] = (f16)((rbw[uu].z - (float)hb[2]) * 2048.f);
      hb[3] = (f16)rbw[uu].w; lb[3] = (f16)((rbw[uu].w - (float)hb[3]) * 2048.f);
      *(f16x4*)&Bsh[rr * 72 + kp] = hb;
      *(f16x4*)&Bsl[rr * 72 + kp] = lb;
    }
    __syncthreads();
    int kn = kc + 64;
    if (kn < NDIM) {
      rah0 = *(const uint4*)(Ah_g + a0o + kn + ak);
      rah1 = *(const uint4*)(Ah_g + a1o + kn + ak);
      ral0 = *(const uint4*)(Al_g + a0o + kn + ak);
      ral1 = *(const uint4*)(Al_g + a1o + kn + ak);
#pragma unroll
      for (int uu = 0; uu < 4; ++uu) {
        int u = t + uu * 256;
        int rr = u >> 4, kp = (u & 15) * 4;
        rbw[uu] = *(const float4*)(inw + (size_t)(z * NDIM + nt * 64 + rr) * NDIM + kn + kp);
      }
    }
#pragma unroll
    for (int ks = 0; ks < 2; ++ks) {
      int aoff = ((wv & 1) * 32 + m16) * 72 + ks * 32 + quad * 8;
      int boff = ((wv >> 1) * 32 + m16) * 72 + ks * 32 + quad * 8;
      f16x8 a0h = *(const f16x8*)&Ash[aoff];
      f16x8 a1h = *(const f16x8*)&Ash[aoff + 16 * 72];
      f16x8 a0l = *(const f16x8*)&Asl[aoff];
      f16x8 a1l = *(const f16x8*)&Asl[aoff + 16 * 72];
      f16x8 b0h = *(const f16x8*)&Bsh[boff];
      f16x8 b1h = *(const f16x8*)&Bsh[boff + 16 * 72];
      f16x8 b0l = *(const f16x8*)&Bsl[boff];
      f16x8 b1l = *(const f16x8*)&Bsl[boff + 16 * 72];
      ah[0][0] = MFMA16(a0h, b0h, ah[0][0]);
      ah[0][1] = MFMA16(a0h, b1h, ah[0][1]);
      ah[1][0] = MFMA16(a1h, b0h, ah[1][0]);
      ah[1][1] = MFMA16(a1h, b1h, ah[1][1]);
      am[0][0] = MFMA16(a0h, b0l, am[0][0]);
      am[0][1] = MFMA16(a0h, b1l, am[0][1]);
      am[1][0] = MFMA16(a1h, b0l, am[1][0]);
      am[1][1] = MFMA16(a1h, b1l, am[1][1]);
      am[0][0] = MFMA16(a0l, b0h, am[0][0]);
      am[0][1] = MFMA16(a0l, b1h, am[0][1]);
      am[1][0] = MFMA16(a1l, b0h, am[1][0]);
      am[1][1] = MFMA16(a1l, b1h, am[1][1]);
    }
  }
#pragma unroll
  for (int mi = 0; mi < 2; ++mi)
#pragma unroll
    for (int ni = 0; ni < 2; ++ni)
#pragma unroll
      for (int r = 0; r < 4; ++r) {
        int row = mt * 64 + (wv & 1) * 32 + mi * 16 + quad * 4 + r;
        int col = nt * 64 + (wv >> 1) * 32 + ni * 16 + m16;
        float v = ah[mi][ni][r] + am[mi][ni][r] * (1.f / 2048.f) + inb[z * NDIM + col];
        size_t idx = (size_t)row * NDIM + col;
        if (z == 0) {
          f16 hq = (f16)v;
          qhi[idx] = hq;
          qlo[idx] = (f16)((v - (float)hq) * 2048.f);
        } else if (z == 1) {
          f16 hk = (f16)v;
          khi[idx] = hk;
          klo[idx] = (f16)((v - (float)hk) * 2048.f);
        } else {
          f16 hv = (f16)v;
          int bb = row >> 7, kv = row & 127;
          size_t ti = (size_t)(bb * NDIM + col) * NSC + kv;
          vthi[ti] = hv;
          vtlo[ti] = (f16)((v - (float)hv) * 2048.f);
        }
      }
}

// ---------------- fused attention: QK^T + softmax + PV, split-fp16, writes o hi/lo ----
__global__ __launch_bounds__(256) void k_attn(
    const f16* __restrict__ qhi, const f16* __restrict__ qlo,
    const f16* __restrict__ khi, const f16* __restrict__ klo,
    const f16* __restrict__ vthi, const f16* __restrict__ vtlo,
    f16* __restrict__ ohi, f16* __restrict__ olo) {
  int mt = blockIdx.x, bh = blockIdx.y;
  int b = bh >> 3, h = bh & 7;
  __shared__ f16 Ah[64 * 160];
  __shared__ f16 Al[64 * 160];
  __shared__ f16 Bh[32 * 160];
  __shared__ f16 Bl[32 * 160];
  __shared__ f16 Ph[64 * 136];
  __shared__ f16 Pl[64 * 136];
  int t = threadIdx.x;
  int wv = t >> 6, lane = t & 63, m16 = lane & 15, quad = lane >> 4;
  for (int u = t; u < 64 * 20; u += 256) {
    int r = u / 20, kp = (u % 20) * 8;
    uint4 vh = make_uint4(0u, 0u, 0u, 0u), vl = vh;
    if (kp < HDIM) {
      size_t gi = (size_t)(b * NS + mt * 64 + r) * NDIM + h * HDIM + kp;
      vh = *(const uint4*)&qhi[gi];
      vl = *(const uint4*)&qlo[gi];
    }
    *(uint4*)&Ah[r * 160 + kp] = vh;
    *(uint4*)&Al[r * 160 + kp] = vl;
  }
  __syncthreads();
  f16x8 ahf[5], alf[5];
#pragma unroll
  for (int ks = 0; ks < 5; ++ks) {
    int ao = (wv * 16 + m16) * 160 + ks * 32 + quad * 8;
    ahf[ks] = *(const f16x8*)&Ah[ao];
    alf[ks] = *(const f16x8*)&Al[ao];
  }
  f32x4 zf = {0.f, 0.f, 0.f, 0.f};
  f32x4 sh_[4][2], sm_[4][2];
#pragma unroll
  for (int kt = 0; kt < 4; ++kt)
#pragma unroll
    for (int ni = 0; ni < 2; ++ni) { sh_[kt][ni] = zf; sm_[kt][ni] = zf; }
  for (int kt = 0; kt < 4; ++kt) {
    if (kt) __syncthreads();
    for (int u = t; u < 32 * 20; u += 256) {
      int r = u / 20, kp = (u % 20) * 8;
      uint4 vh = make_uint4(0u, 0u, 0u, 0u), vl = vh;
      if (kp < HDIM) {
        size_t gi = (size_t)(b * NSC + kt * 32 + r) * NDIM + h * HDIM + kp;
        vh = *(const uint4*)&khi[gi];
        vl = *(const uint4*)&klo[gi];
      }
      *(uint4*)&Bh[r * 160 + kp] = vh;
      *(uint4*)&Bl[r * 160 + kp] = vl;
    }
    __syncthreads();
#pragma unroll
    for (int ks = 0; ks < 5; ++ks) {
#pragma unroll
      for (int ni = 0; ni < 2; ++ni) {
        int bo = (ni * 16 + m16) * 160 + ks * 32 + quad * 8;
        f16x8 bhf = *(const f16x8*)&Bh[bo];
        f16x8 blf = *(const f16x8*)&Bl[bo];
        sh_[kt][ni] = MFMA16(ahf[ks], bhf, sh_[kt][ni]);
        sm_[kt][ni] = MFMA16(ahf[ks], blf, sm_[kt][ni]);
        sm_[kt][ni] = MFMA16(alf[ks], bhf, sm_[kt][ni]);
      }
    }
  }
  float sv[4][2][4];
  float mx[4] = {-1e30f, -1e30f, -1e30f, -1e30f};
#pragma unroll
  for (int kt = 0; kt < 4; ++kt)
#pragma unroll
    for (int ni = 0; ni < 2; ++ni)
#pragma unroll
      for (int r = 0; r < 4; ++r) {
        float s = (sh_[kt][ni][r] + sm_[kt][ni][r] * (1.f / 2048.f)) * (1.f / 12.f);
        sv[kt][ni][r] = s;
        mx[r] = fmaxf(mx[r], s);
      }
#pragma unroll
  for (int r = 0; r < 4; ++r) {
    mx[r] = fmaxf(mx[r], __shfl_xor(mx[r], 1));
    mx[r] = fmaxf(mx[r], __shfl_xor(mx[r], 2));
    mx[r] = fmaxf(mx[r], __shfl_xor(mx[r], 4));
    mx[r] = fmaxf(mx[r], __shfl_xor(mx[r], 8));
  }
  float sum[4] = {0.f, 0.f, 0.f, 0.f};
#pragma unroll
  for (int kt = 0; kt < 4; ++kt)
#pragma unroll
    for (int ni = 0; ni < 2; ++ni)
#pragma unroll
      for (int r = 0; r < 4; ++r) {
        float e = expf(sv[kt][ni][r] - mx[r]);
        sv[kt][ni][r] = e;
        sum[r] += e;
      }
  float inv[4];
#pragma unroll
  for (int r = 0; r < 4; ++r) {
    sum[r] += __shfl_xor(sum[r], 1);
    sum[r] += __shfl_xor(sum[r], 2);
    sum[r] += __shfl_xor(sum[r], 4);
    sum[r] += __shfl_xor(sum[r], 8);
    inv[r] = 1.0f / sum[r];
  }
#pragma unroll
  for (int kt = 0; kt < 4; ++kt)
#pragma unroll
    for (int ni = 0; ni < 2; ++ni)
#pragma unroll
      for (int r = 0; r < 4; ++r) {
        float p = sv[kt][ni][r] * inv[r];
        int row = wv * 16 + quad * 4 + r;
        int col = kt * 32 + ni * 16 + m16;
        f16 ph = (f16)p;
        Ph[row * 136 + col] = ph;
        Pl[row * 136 + col] = (f16)((p - (float)ph) * 2048.f);
      }
  const f16* vbh = vthi + (size_t)(b * NDIM + h * HDIM) * NSC;
  const f16* vbl = vtlo + (size_t)(b * NDIM + h * HDIM) * NSC;
  f32x4 oh_[9], om_[9];
#pragma unroll
  for (int nb = 0; nb < 9; ++nb) { oh_[nb] = zf; om_[nb] = zf; }
#pragma unroll
  for (int ks = 0; ks < 4; ++ks) {
    int po = (wv * 16 + m16) * 136 + ks * 32 + quad * 8;
    f16x8 pah = *(const f16x8*)&Ph[po];
    f16x8 pal = *(const f16x8*)&Pl[po];
#pragma unroll
    for (int nb = 0; nb < 9; ++nb) {
      size_t vo = (size_t)(nb * 16 + m16) * NSC + ks * 32 + quad * 8;
      f16x8 bvh = *(const f16x8*)&vbh[vo];
      f16x8 bvl = *(const f16x8*)&vbl[vo];
      oh_[nb] = MFMA16(pah, bvh, oh_[nb]);
      om_[nb] = MFMA16(pah, bvl, om_[nb]);
      om_[nb] = MFMA16(pal, bvh, om_[nb]);
    }
  }
#pragma unroll
  for (int nb = 0; nb < 9; ++nb)
#pragma unroll
    for (int r = 0; r < 4; ++r) {
      int row = mt * 64 + wv * 16 + quad * 4 + r;
      int col = h * HDIM + nb * 16 + m16;
      float v = oh_[nb][r] + om_[nb][r] * (1.f / 2048.f);
      size_t idx = (size_t)(b * NS + row) * NDIM + col;
      f16 hv = (f16)v;
      ohi[idx] = hv;
      olo[idx] = (f16)((v - (float)hv) * 2048.f);
    }
}

// ---------------- ca = o @ out_w^T + out_b  (split-fp16, fp32 out), 2-phase prefetch --
__global__ __launch_bounds__(256) void k_ca(
    const f16* __restrict__ ohi, const f16* __restrict__ olo,
    const float* __restrict__ ow, const float* __restrict__ ob,
    float* __restrict__ ca) {
  int mt = blockIdx.y, nt = blockIdx.x;
  __shared__ f16 Ash[64 * 72];
  __shared__ f16 Asl[64 * 72];
  __shared__ f16 Bsh[64 * 72];
  __shared__ f16 Bsl[64 * 72];
  int t = threadIdx.x;
  int wv = t >> 6, lane = t & 63, m16 = lane & 15, quad = lane >> 4;
  int r0 = t >> 3, ak = (t & 7) * 8;
  size_t a0o = (size_t)(mt * 64 + r0) * NDIM;
  size_t a1o = (size_t)(mt * 64 + r0 + 32) * NDIM;
  f32x4 zf = {0.f, 0.f, 0.f, 0.f};
  f32x4 ah[2][2] = {{zf, zf}, {zf, zf}};
  f32x4 am[2][2] = {{zf, zf}, {zf, zf}};
  uint4 rah0, rah1, ral0, ral1;
  float4 rbw[4];
  rah0 = *(const uint4*)(ohi + a0o + ak);
  rah1 = *(const uint4*)(ohi + a1o + ak);
  ral0 = *(const uint4*)(olo + a0o + ak);
  ral1 = *(const uint4*)(olo + a1o + ak);
#pragma unroll
  for (int uu = 0; uu < 4; ++uu) {
    int u = t + uu * 256;
    int rr = u >> 4, kp = (u & 15) * 4;
    rbw[uu] = *(const float4*)(ow + (size_t)(nt * 64 + rr) * NDIM + kp);
  }
  for (int kc = 0; kc < NDIM; kc += 64) {
    __syncthreads();
    *(uint4*)&Ash[r0 * 72 + ak] = rah0;
    *(uint4*)&Ash[(r0 + 32) * 72 + ak] = rah1;
    *(uint4*)&Asl[r0 * 72 + ak] = ral0;
    *(uint4*)&Asl[(r0 + 32) * 72 + ak] = ral1;
#pragma unroll
    for (int uu = 0; uu < 4; ++uu) {
      int u = t + uu * 256;
      int rr = u >> 4, kp = (u & 15) * 4;
      f16x4 hb, lb;
      hb[0] = (f16)rbw[uu].x; lb[0] = (f16)((rbw[uu].x - (float)hb[0]) * 2048.f);
      hb[1] = (f16)rbw[uu].y; lb[1] = (f16)((rbw[uu].y - (float)hb[1]) * 2048.f);
      hb[2] = (f16)rbw[uu].z; lb[2] = (f16)((rbw[uu].z - (float)hb[2]) * 2048.f);
      hb[3] = (f16)rbw[uu].w; lb[3] = (f16)((rbw[uu].w - (float)hb[3]) * 2048.f);
      *(f16x4*)&Bsh[rr * 72 + kp] = hb;
      *(f16x4*)&Bsl[rr * 72 + kp] = lb;
    }
    __syncthreads();
    int kn = kc + 64;
    if (kn < NDIM) {
      rah0 = *(const uint4*)(ohi + a0o + kn + ak);
      rah1 = *(const uint4*)(ohi + a1o + kn + ak);
      ral0 = *(const uint4*)(olo + a0o + kn + ak);
      ral1 = *(const uint4*)(olo + a1o + kn + ak);
#pragma unroll
      for (int uu = 0; uu < 4; ++uu) {
        int u = t + uu * 256;
        int rr = u >> 4, kp = (u & 15) * 4;
        rbw[uu] = *(const float4*)(ow + (size_t)(nt * 64 + rr) * NDIM + kn + kp);
      }
    }
#pragma unroll
    for (int ks = 0; ks < 2; ++ks) {
      int aoff = ((wv & 1) * 32 + m16) * 72 + ks * 32 + quad * 8;
      int boff = ((wv >> 1) * 32 + m16) * 72 + ks * 32 + quad * 8;
      f16x8 a0h = *(const f16x8*)&Ash[aoff];
      f16x8 a1h = *(const f16x8*)&Ash[aoff + 16 * 72];
      f16x8 a0l = *(const f16x8*)&Asl[aoff];
      f16x8 a1l = *(const f16x8*)&Asl[aoff + 16 * 72];
      f16x8 b0h = *(const f16x8*)&Bsh[boff];
      f16x8 b1h = *(const f16x8*)&Bsh[boff + 16 * 72];
      f16x8 b0l = *(const f16x8*)&Bsl[boff];
      f16x8 b1l = *(const f16x8*)&Bsl[boff + 16 * 72];
      ah[0][0] = MFMA16(a0h, b0h, ah[0][0]);
      ah[0][1] = MFMA16(a0h, b1h, ah[0][1]);
      ah[1][0] = MFMA16(a1h, b0h, ah[1][0]);
      ah[1][1] = MFMA16(a1h, b1h, ah[1][1]);
      am[0][0] = MFMA16(a0h, b0l, am[0][0]);
      am[0][1] = MFMA16(a0h, b1l, am[0][1]);
      am[1][0] = MFMA16(a1h, b0l, am[1][0]);
      am[1][1] = MFMA16(a1h, b1l, am[1][1]);
      am[0][0] = MFMA16(a0l, b0h, am[0][0]);
      am[0][1] = MFMA16(a0l, b1h, am[0][1]);
      am[1][0] = MFMA16(a1l, b0h, am[1][0]);
      am[1][1] = MFMA16(a1l, b1h, am[1][1]);
    }
  }
#pragma unroll
  for (int mi = 0; mi < 2; ++mi)
#pragma unroll
    for (int ni = 0; ni < 2; ++ni)
#pragma unroll
      for (int r = 0; r < 4; ++r) {
        int row = mt * 64 + (wv & 1) * 32 + mi * 16 + quad * 4 + r;
        int col = nt * 64 + (wv >> 1) * 32 + ni * 16 + m16;
        ca[(size_t)row * NDIM + col] =
            ah[mi][ni][r] + am[mi][ni][r] * (1.f / 2048.f) + ob[col];
      }
}

// ---------------- routing: argmax gates, cm/am, lists, loss ----------------
__global__ __launch_bounds__(1024) void k_route(
    const float* __restrict__ cl, const float* __restrict__ al,
    const float* __restrict__ g1, const float* __restrict__ g2,
    const float* __restrict__ g3, const float* __restrict__ tl,
    float* __restrict__ cmv, float* __restrict__ amv,
    int* __restrict__ lists, int* __restrict__ counts, float* __restrict__ out_loss) {
  __shared__ int lcnt[8];
  __shared__ float bins[8];
  __shared__ float ssum[2];
  int t = threadIdx.x;
  if (t < 8) { lcnt[t] = 0; bins[t] = 0.f; }
  if (t < 2) ssum[t] = 0.f;
  __syncthreads();
  for (int n = t; n < NTOK; n += 1024) {
    float lc[NEXP];
#pragma unroll
    for (int e = 0; e < NEXP; ++e) lc[e] = cl[n * NEXP + e] + g2[n * 4 + e];
    int ec = 0; float bv = lc[0];
#pragma unroll
    for (int e = 1; e < NEXP; ++e) if (lc[e] > bv) { bv = lc[e]; ec = e; }
    float la[NEXP];
#pragma unroll
    for (int e = 0; e < NEXP; ++e) la[e] = al[n * NEXP + e] + g3[n * 4 + e];
    int ea = 0; float bva = la[0];
#pragma unroll
    for (int e = 1; e < NEXP; ++e) if (la[e] > bva) { bva = la[e]; ea = e; }
    int b = n >> 10;
    float a0 = tl[b * 2 + 0] + g1[n * 2 + 0];
    float a1 = tl[b * 2 + 1] + g1[n * 2 + 1];
    float mx = fmaxf(a0, a1);
    float e0 = expf(a0 - mx), e1 = expf(a1 - mx);
    float cm = e0 / (e0 + e1), am = e1 / (e0 + e1);
    cmv[n] = cm; amv[n] = am;
    int p0 = atomicAdd(&lcnt[ec], 1);
    lists[ec * NTOK + p0] = n;
    int p1 = atomicAdd(&lcnt[4 + ea], 1);
    lists[(4 + ea) * NTOK + p1] = n;
    atomicAdd(&bins[ec], cm);
    atomicAdd(&bins[4 + ea], am);
    atomicAdd(&ssum[0], cm);
    atomicAdd(&ssum[1], am);
  }
  __syncthreads();
  if (t < 8) counts[t] = lcnt[t];
  if (t == 0) {
    float denom = 4.f * (ssum[0] + ssum[1]) + 1e-10f;
    float acc = 0.f;
    for (int j = 0; j < 8; ++j) {
      float u = bins[j] / denom;
      acc += u * logf(u + 1e-10f);
    }
    out_loss[0] = acc / 8.f;
  }
}

// ---------------- GEMM1: M64, f16 weights, XCD-grouped remap, 2-phase prefetch --------
// grid: 1D, G*12*32 blocks. xcd=bid&7 owns a slice of (g,nt) pairs; mt fastest.
__global__ __launch_bounds__(256) void k_gemm1(
    const f16* __restrict__ x16, const f16* __restrict__ y16,
    const f16* __restrict__ wf,
    const int* __restrict__ lists, const int* __restrict__ counts,
    f16* __restrict__ tbuf, int gbase, int G) {
  int bid = blockIdx.x;
  int xcd = bid & 7;
  int local = bid >> 3;
  int ppx = (G * 12) >> 3;               // pairs per xcd (8->12, 4->6)
  int pair = xcd * ppx + (local >> 5);   // MT = 32
  int mt = local & 31;
  int g = gbase + pair / 12;
  int nt = pair % 12;
  const f16* A; const f16* B1; const f16* B3; f16* tout;
  const int* list = nullptr;
  int cnt, koff, K;
  if (g < 8) {
    int e = g & 3;
    cnt = counts[g];
    list = lists + g * NTOK;
    A = x16; koff = 0; K = NDIM;
    B1 = wf + (size_t)((g < 4) ? 0 : 2) * WSZ + (size_t)e * NHID * NDIM;
    B3 = wf + (size_t)((g < 4) ? 1 : 3) * WSZ + (size_t)e * NHID * NDIM;
    tout = tbuf + (size_t)g * NTOK * NHID;
  } else {
    int e = g - 8;
    cnt = NTOK;
    A = y16; koff = e * 288; K = 288;
    B1 = wf + (size_t)4 * WSZ + (size_t)e * NHID * NDIM + koff;
    B3 = wf + (size_t)5 * WSZ + (size_t)e * NHID * NDIM + koff;
    tout = tbuf + (size_t)e * NTOK * NHID;
  }
  if (mt * 64 >= cnt) return;
  int t = threadIdx.x;
  int wv = t >> 6, lane = t & 63, m16 = lane & 15, quad = lane >> 4;
  int r0 = t >> 3, ak = (t & 7) * 8;
  int m0 = mt * 64 + r0, m1 = m0 + 32;
  int tok0, tok1;
  if (list) { tok0 = list[min(m0, cnt - 1)]; tok1 = list[min(m1, cnt - 1)]; }
  else { tok0 = m0; tok1 = m1; }
  const f16* ar0 = A + (size_t)tok0 * NDIM + koff;
  const f16* ar1 = A + (size_t)tok1 * NDIM + koff;
  const f16* b1r0 = B1 + (size_t)(nt * 64 + r0) * NDIM;
  const f16* b1r1 = B1 + (size_t)(nt * 64 + r0 + 32) * NDIM;
  const f16* b3r0 = B3 + (size_t)(nt * 64 + r0) * NDIM;
  const f16* b3r1 = B3 + (size_t)(nt * 64 + r0 + 32) * NDIM;
  __shared__ f16 As[64 * 72];
  __shared__ f16 Bs1[64 * 72];
  __shared__ f16 Bs2[64 * 72];
  f32x4 zf = {0.f, 0.f, 0.f, 0.f};
  f32x4 ac1[2][2] = {{zf, zf}, {zf, zf}};
  f32x4 ac2[2][2] = {{zf, zf}, {zf, zf}};
  uint4 z4u = make_uint4(0u, 0u, 0u, 0u);
  uint4 ra0, ra1, rb10, rb11, rb30, rb31;
  {
    bool v = (ak < K);
    ra0  = v ? *(const uint4*)(ar0 + ak) : z4u;
    ra1  = v ? *(const uint4*)(ar1 + ak) : z4u;
    rb10 = v ? *(const uint4*)(b1r0 + ak) : z4u;
    rb11 = v ? *(const uint4*)(b1r1 + ak) : z4u;
    rb30 = v ? *(const uint4*)(b3r0 + ak) : z4u;
    rb31 = v ? *(const uint4*)(b3r1 + ak) : z4u;
  }
  for (int kc = 0; kc < K; kc += 64) {
    __syncthreads();
    *(uint4*)&As[r0 * 72 + ak] = ra0;
    *(uint4*)&As[(r0 + 32) * 72 + ak] = ra1;
    *(uint4*)&Bs1[r0 * 72 + ak] = rb10;
    *(uint4*)&Bs1[(r0 + 32) * 72 + ak] = rb11;
    *(uint4*)&Bs2[r0 * 72 + ak] = rb30;
    *(uint4*)&Bs2[(r0 + 32) * 72 + ak] = rb31;
    __syncthreads();
    int kn = kc + 64;
    if (kn < K) {
      bool v = (kn + ak < K);
      ra0  = v ? *(const uint4*)(ar0 + kn + ak) : z4u;
      ra1  = v ? *(const uint4*)(ar1 + kn + ak) : z4u;
      rb10 = v ? *(const uint4*)(b1r0 + kn + ak) : z4u;
      rb11 = v ? *(const uint4*)(b1r1 + kn + ak) : z4u;
      rb30 = v ? *(const uint4*)(b3r0 + kn + ak) : z4u;
      rb31 = v ? *(const uint4*)(b3r1 + kn + ak) : z4u;
    }
#pragma unroll
    for (int ks = 0; ks < 2; ++ks) {
      int aoff = ((wv & 1) * 32 + m16) * 72 + ks * 32 + quad * 8;
      int boff = ((wv >> 1) * 32 + m16) * 72 + ks * 32 + quad * 8;
      f16x8 a0 = *(const f16x8*)&As[aoff];
      f16x8 a1 = *(const f16x8*)&As[aoff + 16 * 72];
      f16x8 b10 = *(const f16x8*)&Bs1[boff];
      f16x8 b11 = *(const f16x8*)&Bs1[boff + 16 * 72];
      f16x8 b30 = *(const f16x8*)&Bs2[boff];
      f16x8 b31 = *(const f16x8*)&Bs2[boff + 16 * 72];
      ac1[0][0] = MFMA16(a0, b10, ac1[0][0]);
      ac1[0][1] = MFMA16(a0, b11, ac1[0][1]);
      ac1[1][0] = MFMA16(a1, b10, ac1[1][0]);
      ac1[1][1] = MFMA16(a1, b11, ac1[1][1]);
      ac2[0][0] = MFMA16(a0, b30, ac2[0][0]);
      ac2[0][1] = MFMA16(a0, b31, ac2[0][1]);
      ac2[1][0] = MFMA16(a1, b30, ac2[1][0]);
      ac2[1][1] = MFMA16(a1, b31, ac2[1][1]);
    }
  }
#pragma unroll
  for (int mi = 0; mi < 2; ++mi)
#pragma unroll
    for (int ni = 0; ni < 2; ++ni)
#pragma unroll
      for (int r = 0; r < 4; ++r) {
        int row = mt * 64 + (wv & 1) * 32 + mi * 16 + quad * 4 + r;
        int col = nt * 64 + (wv >> 1) * 32 + ni * 16 + m16;
        float h1 = ac1[mi][ni][r];
        float h3 = ac2[mi][ni][r];
        float sl = h1 / (1.0f + expf(-h1));
        tout[(size_t)row * NHID + col] = (f16)(sl * h3);
      }
}

// ---------------- GEMM2 (MoE): f16 weights, XCD-grouped remap, 2-phase ----------------
// grid: 1D, 8*18*32 blocks. xcd owns group g=xcd, 18 nt panels, mt fastest.
__global__ __launch_bounds__(256) void k_gemm2(
    const f16* __restrict__ tbuf, const f16* __restrict__ wf,
    const int* __restrict__ lists, const int* __restrict__ counts,
    const float* __restrict__ cmv, const float* __restrict__ amv,
    float* __restrict__ yc, float* __restrict__ ya) {
  int bid = blockIdx.x;
  int xcd = bid & 7;
  int local = bid >> 3;
  int pair = xcd * 18 + (local >> 5);
  int mt = local & 31;
  int g = pair / 18;
  int nt = pair % 18;
  int e = g & 3;
  int cnt = counts[g];
  if (mt * 64 >= cnt) return;
  const int* list = lists + g * NTOK;
  const f16* A = tbuf + (size_t)g * NTOK * NHID;
  const f16* Bw = wf + (size_t)((g < 4) ? 6 : 7) * WSZ + (size_t)e * NDIM * NHID;
  const float* sc = (g < 4) ? cmv : amv;
  float* y = (g < 4) ? yc : ya;
  int t = threadIdx.x;
  int wv = t >> 6, lane = t & 63, m16 = lane & 15, quad = lane >> 4;
  int r0 = t >> 3, ak = (t & 7) * 8;
  const f16* ar0 = A + (size_t)(mt * 64 + r0) * NHID;
  const f16* ar1 = A + (size_t)(mt * 64 + r0 + 32) * NHID;
  const f16* br0 = Bw + (size_t)(nt * 64 + r0) * NHID;
  const f16* br1 = Bw + (size_t)(nt * 64 + r0 + 32) * NHID;
  __shared__ f16 As[64 * 72];
  __shared__ f16 Bs[64 * 72];
  f32x4 zf = {0.f, 0.f, 0.f, 0.f};
  f32x4 acc[2][2] = {{zf, zf}, {zf, zf}};
  uint4 ra0, ra1, rb0, rb1;
  ra0 = *(const uint4*)(ar0 + ak);
  ra1 = *(const uint4*)(ar1 + ak);
  rb0 = *(const uint4*)(br0 + ak);
  rb1 = *(const uint4*)(br1 + ak);
  for (int kc = 0; kc < NHID; kc += 64) {
    __syncthreads();
    *(uint4*)&As[r0 * 72 + ak] = ra0;
    *(uint4*)&As[(r0 + 32) * 72 + ak] = ra1;
    *(uint4*)&Bs[r0 * 72 + ak] = rb0;
    *(uint4*)&Bs[(r0 + 32) * 72 + ak] = rb1;
    __syncthreads();
    int kn = kc + 64;
    if (kn < NHID) {
      ra0 = *(const uint4*)(ar0 + kn + ak);
      ra1 = *(const uint4*)(ar1 + kn + ak);
      rb0 = *(const uint4*)(br0 + kn + ak);
      rb1 = *(const uint4*)(br1 + kn + ak);
    }
#pragma unroll
    for (int ks = 0; ks < 2; ++ks) {
      int aoff = ((wv & 1) * 32 + m16) * 72 + ks * 32 + quad * 8;
      int boff = ((wv >> 1) * 32 + m16) * 72 + ks * 32 + quad * 8;
      f16x8 a0 = *(const f16x8*)&As[aoff];
      f16x8 a1 = *(const f16x8*)&As[aoff + 16 * 72];
      f16x8 b0 = *(const f16x8*)&Bs[boff];
      f16x8 b1 = *(const f16x8*)&Bs[boff + 16 * 72];
      acc[0][0] = MFMA16(a0, b0, acc[0][0]);
      acc[0][1] = MFMA16(a0, b1, acc[0][1]);
      acc[1][0] = MFMA16(a1, b0, acc[1][0]);
      acc[1][1] = MFMA16(a1, b1, acc[1][1]);
    }
  }
#pragma unroll
  for (int mi = 0; mi < 2; ++mi)
#pragma unroll
    for (int ni = 0; ni < 2; ++ni)
#pragma unroll
      for (int r = 0; r < 4; ++r) {
        int mg = mt * 64 + (wv & 1) * 32 + mi * 16 + quad * 4 + r;
        if (mg < cnt) {
          int tok = list[mg];
          int col = nt * 64 + (wv >> 1) * 32 + ni * 16 + m16;
          float v = acc[mi][ni][r] * sc[tok];
          y[(size_t)tok * NDIM + col] = v;
        }
      }
}

// ---------------- GEMM2 (fr): f16 weights, t16 @ fr_w2 slice -> z, 2-phase ------------
__global__ __launch_bounds__(256) void k_gemm2_fr(
    const f16* __restrict__ tbuf, const f16* __restrict__ wf, float* __restrict__ zz) {
  int e = blockIdx.z;
  int mt = blockIdx.y, nt = blockIdx.x;
  const f16* A = tbuf + (size_t)e * NTOK * NHID;
  const f16* Bw = wf + (size_t)8 * WSZ + (size_t)e * NDIM * NHID;
  int t = threadIdx.x;
  int wv = t >> 6, lane = t & 63, m16 = lane & 15, quad = lane >> 4;
  int r0 = t >> 3, ak = (t & 7) * 8;
  const f16* ar0 = A + (size_t)(mt * 64 + r0) * NHID;
  const f16* ar1 = A + (size_t)(mt * 64 + r0 + 32) * NHID;
  int ne0 = min(nt * 64 + r0, 287), ne1 = min(nt * 64 + r0 + 32, 287);
  const f16* br0 = Bw + (size_t)(e * 288 + ne0) * NHID;
  const f16* br1 = Bw + (size_t)(e * 288 + ne1) * NHID;
  __shared__ f16 As[64 * 72];
  __shared__ f16 Bs[64 * 72];
  f32x4 zf = {0.f, 0.f, 0.f, 0.f};
  f32x4 acc[2][2] = {{zf, zf}, {zf, zf}};
  uint4 ra0, ra1, rb0, rb1;
  ra0 = *(const uint4*)(ar0 + ak);
  ra1 = *(const uint4*)(ar1 + ak);
  rb0 = *(const uint4*)(br0 + ak);
  rb1 = *(const uint4*)(br1 + ak);
  for (int kc = 0; kc < NHID; kc += 64) {
    __syncthreads();
    *(uint4*)&As[r0 * 72 + ak] = ra0;
    *(uint4*)&As[(r0 + 32) * 72 + ak] = ra1;
    *(uint4*)&Bs[r0 * 72 + ak] = rb0;
    *(uint4*)&Bs[(r0 + 32) * 72 + ak] = rb1;
    __syncthreads();
    int kn = kc + 64;
    if (kn < NHID) {
      ra0 = *(const uint4*)(ar0 + kn + ak);
      ra1 = *(const uint4*)(ar1 + kn + ak);
      rb0 = *(const uint4*)(br0 + kn + ak);
      rb1 = *(const uint4*)(br1 + kn + ak);
    }
#pragma unroll
    for (int ks = 0; ks < 2; ++ks) {
      int aoff = ((wv & 1) * 32 + m16) * 72 + ks * 32 + quad * 8;
      int boff = ((wv >> 1) * 32 + m16) * 72 + ks * 32 + quad * 8;
      f16x8 a0 = *(const f16x8*)&As[aoff];
      f16x8 a1 = *(const f16x8*)&As[aoff + 16 * 72];
      f16x8 b0 = *(const f16x8*)&Bs[boff];
      f16x8 b1 = *(const f16x8*)&Bs[boff + 16 * 72];
      acc[0][0] = MFMA16(a0, b0, acc[0][0]);
      acc[0][1] = MFMA16(a0, b1, acc[0][1]);
      acc[1][0] = MFMA16(a1, b0, acc[1][0]);
      acc[1][1] = MFMA16(a1, b1, acc[1][1]);
    }
  }
#pragma unroll
  for (int mi = 0; mi < 2; ++mi)
#pragma unroll
    for (int ni = 0; ni < 2; ++ni)
#pragma unroll
      for (int r = 0; r < 4; ++r) {
        int cg = nt * 64 + (wv >> 1) * 32 + ni * 16 + m16;
        if (cg < 288) {
          int row = mt * 64 + (wv & 1) * 32 + mi * 16 + quad * 4 + r;
          zz[(size_t)row * NDIM + e * 288 + cg] = acc[mi][ni][r];
        }
      }
}

// ---------------- host ----------------
extern "C" void kernel_launch(void* const* d_in, const int* in_sizes, int n_in,
                              void* d_out, int out_size, void* d_ws, size_t ws_size,
                              hipStream_t stream) {
  const float* x          = (const float*)d_in[0];
  const float* timep      = (const float*)d_in[1];
  const float* caption    = (const float*)d_in[2];
  const float* acoustic   = (const float*)d_in[3];
  const float* attn_in_w  = (const float*)d_in[4];
  const float* attn_in_b  = (const float*)d_in[5];
  const float* attn_out_w = (const float*)d_in[6];
  const float* attn_out_b = (const float*)d_in[7];
  const float* hl_w       = (const float*)d_in[8];
  const float* hl_b       = (const float*)d_in[9];
  const float* cap_gate_w = (const float*)d_in[10];
  const float* cap_gate_b = (const float*)d_in[11];
  const float* ac_gate_w  = (const float*)d_in[12];
  const float* ac_gate_b  = (const float*)d_in[13];
  const float* cap_w1     = (const float*)d_in[14];
  const float* cap_w2     = (const float*)d_in[15];
  const float* cap_w3     = (const float*)d_in[16];
  const float* ac_w1      = (const float*)d_in[17];
  const float* ac_w2      = (const float*)d_in[18];
  const float* ac_w3      = (const float*)d_in[19];
  const float* fr_w1      = (const float*)d_in[20];
  const float* fr_w2      = (const float*)d_in[21];
  const float* fr_w3      = (const float*)d_in[22];
  (void)in_sizes; (void)n_in; (void)out_size; (void)ws_size;

  float* zout = (float*)d_out;
  float* loss = zout + (size_t)NTOK * NDIM;

  char* wsb = (char*)d_ws;
  size_t off = 0;
  auto alloc = [&](size_t bytes) -> void* {
    void* p = wsb + off;
    off = (off + bytes + 255) & ~(size_t)255;
    return p;
  };
  // persistent small + xhi + converted weights
  float* g1     = (float*)alloc(4096 * 4);
  float* g2     = (float*)alloc(8192 * 4);
  float* g3     = (float*)alloc(8192 * 4);
  float* tl     = (float*)alloc(4 * 4);
  float* al     = (float*)alloc((size_t)NTOK * NEXP * 4);
  float* cl     = (float*)alloc((size_t)NTOK * NEXP * 4);
  float* cmv    = (float*)alloc((size_t)NTOK * 4);
  float* amv    = (float*)alloc((size_t)NTOK * 4);
  int*   lists  = (int*)alloc((size_t)8 * NTOK * 4);
  int*   counts = (int*)alloc(8 * 4);
  f16*   xhi    = (f16*)alloc((size_t)NTOK * NDIM * 2);
  f16*   wf16   = (f16*)alloc((size_t)9 * WSZ * 2);
  size_t region = off;
  // phase 1 (attention / routing inputs)
  f16*   xlo    = (f16*)alloc((size_t)NTOK * NDIM * 2);
  f16*   caphi  = (f16*)alloc((size_t)NCAP * NDIM * 2);
  f16*   caplo  = (f16*)alloc((size_t)NCAP * NDIM * 2);
  f16*   qhi    = (f16*)alloc((size_t)NTOK * NDIM * 2);
  f16*   qlo    = (f16*)alloc((size_t)NTOK * NDIM * 2);
  f16*   khi    = (f16*)alloc((size_t)NCAP * NDIM * 2);
  f16*   klo    = (f16*)alloc((size_t)NCAP * NDIM * 2);
  f16*   vthi   = (f16*)alloc((size_t)NB * NDIM * NSC * 2);
  f16*   vtlo   = (f16*)alloc((size_t)NB * NDIM * NSC * 2);
  f16*   ohi    = (f16*)alloc((size_t)NTOK * NDIM * 2);
  f16*   olo    = (f16*)alloc((size_t)NTOK * NDIM * 2);
  float* ca32   = (float*)alloc((size_t)NTOK * NDIM * 4);
  // phase 2 (MoE / fr) — reuses phase-1 region (all phase-1 buffers dead)
  off = region;
  f16*   tbuf   = (f16*)alloc((size_t)8 * NTOK * NHID * 2);
  float* ybc    = (float*)alloc((size_t)NTOK * NDIM * 4);
  float* yba    = (float*)alloc((size_t)NTOK * NDIM * 4);
  f16*   y16    = (f16*)alloc((size_t)NTOK * NDIM * 2);

  k_prep<<<dim3(1), dim3(256), 0, stream>>>(timep, hl_w, hl_b, g1, g2, g3, tl);
  k_ac_logits<<<dim3(512), dim3(256), 0, stream>>>(acoustic, ac_gate_w, ac_gate_b, al);
  k_cvt_split<<<dim3(2304), dim3(256), 0, stream>>>(x, xhi, xlo, NTOK * NDIM);
  k_cvt_split<<<dim3(288), dim3(256), 0, stream>>>(caption, caphi, caplo, NCAP * NDIM);
  k_gemm_qkv<<<dim3(18, 32, 3), dim3(256), 0, stream>>>(xhi, xlo, caphi, caplo,
                                                        attn_in_w, attn_in_b,
                                                        qhi, qlo, khi, klo, vthi, vtlo);
  k_attn<<<dim3(16, 16), dim3(256), 0, stream>>>(qhi, qlo, khi, klo, vthi, vtlo, ohi, olo);
  k_ca<<<dim3(18, 32), dim3(256), 0, stream>>>(ohi, olo, attn_out_w, attn_out_b, ca32);
  k_ac_logits<<<dim3(512), dim3(256), 0, stream>>>(ca32, cap_gate_w, cap_gate_b, cl);
  k_route<<<dim3(1), dim3(1024), 0, stream>>>(cl, al, g1, g2, g3, tl,
                                              cmv, amv, lists, counts, loss);
  k_cvt_w<<<dim3(3456, 9), dim3(256), 0, stream>>>(cap_w1, cap_w3, ac_w1, ac_w3,
                                                   fr_w1, fr_w3, cap_w2, ac_w2, fr_w2,
                                                   wf16);
  k_gemm1<<<dim3(3072), dim3(256), 0, stream>>>(xhi, y16, wf16, lists, counts, tbuf, 0, 8);
  k_gemm2<<<dim3(4608), dim3(256), 0, stream>>>(tbuf, wf16, lists, counts,
                                                cmv, amv, ybc, yba);
  k_cvt_add<<<dim3(2304), dim3(256), 0, stream>>>(ybc, yba, y16, NTOK * NDIM);
  k_gemm1<<<dim3(1536), dim3(256), 0, stream>>>(xhi, y16, wf16, lists, counts, tbuf, 8, 4);
  k_gemm2_fr<<<dim3(5, 32, 4), dim3(256), 0, stream>>>(tbuf, wf16, zout);
}

// Round 4
// 476.445 us; speedup vs baseline: 1.2434x; 1.0313x over previous
//
#include <hip/hip_runtime.h>
#include <stdint.h>

#define NDIM 1152
#define NEXP 4
#define NHID 768
#define NHEAD 8
#define HDIM 144
#define NB 2
#define NS 1024
#define NSC 128
#define NTOK 2048
#define NCAP 256

typedef _Float16 f16;
typedef _Float16 f16x4 __attribute__((ext_vector_type(4)));
typedef _Float16 f16x8 __attribute__((ext_vector_type(8)));
typedef float f32x4 __attribute__((ext_vector_type(4)));

#define MFMA16(a, b, c) __builtin_amdgcn_mfma_f32_16x16x32_f16(a, b, c, 0, 0, 0)

#define WSZ ((size_t)NEXP * NHID * NDIM)  // elems per weight tensor (3,538,944)
#define CVT_BLOCKS 15552                  // 9 * WSZ / 2048
#define CVT_ZS 27                         // CVT_BLOCKS / (18*32)

// ---------------- Threefry2x32 (exact JAX replication) ----------------
__device__ inline uint2 tfry(uint32_t k0, uint32_t k1, uint32_t x0, uint32_t x1) {
  uint32_t k2 = k0 ^ k1 ^ 0x1BD11BDAu;
#define RND(r) { x0 += x1; x1 = (x1 << r) | (x1 >> (32 - r)); x1 ^= x0; }
  x0 += k0; x1 += k1;
  RND(13) RND(15) RND(26) RND(6)
  x0 += k1; x1 += k2 + 1u;
  RND(17) RND(29) RND(16) RND(24)
  x0 += k2; x1 += k0 + 2u;
  RND(13) RND(15) RND(26) RND(6)
  x0 += k0; x1 += k1 + 3u;
  RND(17) RND(29) RND(16) RND(24)
  x0 += k1; x1 += k2 + 4u;
  RND(13) RND(15) RND(26) RND(6)
  x0 += k2; x1 += k0 + 5u;
#undef RND
  return make_uint2(x0, x1);
}

__device__ inline float b2g(uint32_t bits) {
  uint32_t fb = (bits >> 9) | 0x3f800000u;
  float f = __uint_as_float(fb) - 1.0f;
  const float tiny = 1.1754943508222875e-38f;
  float u = f * 1.0f + tiny;
  u = fmaxf(tiny, u);
  return -logf(-logf(u));
}

// ---------------- prep: keys, gumbels, time-logits ----------------
__global__ void k_prep(const float* __restrict__ timep, const float* __restrict__ hlw,
                       const float* __restrict__ hlb,
                       float* __restrict__ g1, float* __restrict__ g2, float* __restrict__ g3,
                       float* __restrict__ tl) {
  int t = threadIdx.x;  // 256
  uint2 k1 = tfry(0u, 42u, 0u, 0u);
  uint2 k2 = tfry(0u, 42u, 0u, 1u);
  uint2 k3 = tfry(0u, 42u, 0u, 2u);
  for (int p = t; p < 4096; p += 256) {
    uint2 o = tfry(k1.x, k1.y, 0u, (uint32_t)p);
    g1[p] = b2g(o.x ^ o.y);
  }
  for (int p = t; p < 8192; p += 256) {
    uint2 o2 = tfry(k2.x, k2.y, 0u, (uint32_t)p);
    g2[p] = b2g(o2.x ^ o2.y);
    uint2 o3 = tfry(k3.x, k3.y, 0u, (uint32_t)p);
    g3[p] = b2g(o3.x ^ o3.y);
  }
  int wv = t >> 6, lane = t & 63;
  {
    int b = wv >> 1, j = wv & 1;
    float s = 0.f;
    for (int k = lane; k < NDIM; k += 64) s += timep[b * NDIM + k] * hlw[j * NDIM + k];
    for (int m = 32; m; m >>= 1) s += __shfl_xor(s, m);
    if (lane == 0) tl[b * 2 + j] = s + hlb[j];
  }
}

// ---------------- generic 4-logit head: out[n,e] = in[n,:]·w[e,:] + b[e] ----------------
__global__ void k_ac_logits(const float* __restrict__ ac, const float* __restrict__ agw,
                            const float* __restrict__ agb, float* __restrict__ al) {
  int wv = threadIdx.x >> 6, lane = threadIdx.x & 63;
  int n = blockIdx.x * 4 + wv;
  float s[NEXP] = {0.f, 0.f, 0.f, 0.f};
  for (int d = lane; d < NDIM; d += 64) {
    float a = ac[(size_t)n * NDIM + d];
#pragma unroll
    for (int e = 0; e < NEXP; ++e) s[e] += a * agw[e * NDIM + d];
  }
#pragma unroll
  for (int e = 0; e < NEXP; ++e)
    for (int m = 32; m; m >>= 1) s[e] += __shfl_xor(s[e], m);
  if (lane == 0) {
#pragma unroll
    for (int e = 0; e < NEXP; ++e) al[n * NEXP + e] = s[e] + agb[e];
  }
}

// ---------------- fp32 + fp32 -> fp16 convert (fused add) ----------------
__global__ void k_cvt_add(const float* __restrict__ srca, const float* __restrict__ srcb,
                          f16* __restrict__ dst, int n) {
  int i = (blockIdx.x * 256 + threadIdx.x) * 4;
  if (i + 3 < n) {
    float4 va = *(const float4*)(srca + i);
    float4 vb = *(const float4*)(srcb + i);
    f16x4 h;
    h[0] = (f16)(va.x + vb.x); h[1] = (f16)(va.y + vb.y);
    h[2] = (f16)(va.z + vb.z); h[3] = (f16)(va.w + vb.w);
    *(f16x4*)(dst + i) = h;
  }
}

// ---------------- fp32 -> fp16 hi/lo split convert (lo pre-scaled by 2048) ----------------
__global__ void k_cvt_split(const float* __restrict__ src, f16* __restrict__ hi,
                            f16* __restrict__ lo, int n) {
  int i = (blockIdx.x * 256 + threadIdx.x) * 4;
  if (i + 3 < n) {
    float4 v = *(const float4*)(src + i);
    f16x4 h, l;
    h[0] = (f16)v.x; l[0] = (f16)((v.x - (float)h[0]) * 2048.f);
    h[1] = (f16)v.y; l[1] = (f16)((v.y - (float)h[1]) * 2048.f);
    h[2] = (f16)v.z; l[2] = (f16)((v.z - (float)h[2]) * 2048.f);
    h[3] = (f16)v.w; l[3] = (f16)((v.w - (float)h[3]) * 2048.f);
    *(f16x4*)(hi + i) = h;
    *(f16x4*)(lo + i) = l;
  }
}

// ---------------- QKV projection + fused weight f32->f16 conversion ----------------
// z<3: split-fp16 QKV GEMM (2-phase prefetch). z==2 (V) emits transposed split-fp16.
// z>=3: weight conversion slices (9 tensors -> wf16), co-scheduled for free BW.
__global__ __launch_bounds__(256) void k_gemm_qkv(
    const f16* __restrict__ xhi, const f16* __restrict__ xlo,
    const f16* __restrict__ caphi, const f16* __restrict__ caplo,
    const float* __restrict__ inw, const float* __restrict__ inb,
    f16* __restrict__ qhi, f16* __restrict__ qlo,
    f16* __restrict__ khi, f16* __restrict__ klo,
    f16* __restrict__ vthi, f16* __restrict__ vtlo,
    const float* __restrict__ w0, const float* __restrict__ w1,
    const float* __restrict__ w2, const float* __restrict__ w3,
    const float* __restrict__ w4, const float* __restrict__ w5,
    const float* __restrict__ w6, const float* __restrict__ w7,
    const float* __restrict__ w8, f16* __restrict__ wf16) {
  int z = blockIdx.z;
  if (z >= 3) {
    // -------- weight conversion path: 2048 elems per block, 8 per thread --------
    int gid = (z - 3) * 576 + blockIdx.y * 18 + blockIdx.x;
    int slot = gid / 1728;
    const float* src;
    switch (slot) {
      case 0: src = w0; break; case 1: src = w1; break; case 2: src = w2; break;
      case 3: src = w3; break; case 4: src = w4; break; case 5: src = w5; break;
      case 6: src = w6; break; case 7: src = w7; break; default: src = w8; break;
    }
    size_t off = (size_t)(gid % 1728) * 2048 + (size_t)threadIdx.x * 8;
    float4 v0 = *(const float4*)(src + off);
    float4 v1 = *(const float4*)(src + off + 4);
    f16x8 h;
    h[0] = (f16)v0.x; h[1] = (f16)v0.y; h[2] = (f16)v0.z; h[3] = (f16)v0.w;
    h[4] = (f16)v1.x; h[5] = (f16)v1.y; h[6] = (f16)v1.z; h[7] = (f16)v1.w;
    *(f16x8*)(wf16 + (size_t)slot * WSZ + off) = h;
    return;
  }
  int M = (z == 0) ? NTOK : NCAP;
  int mt = blockIdx.y, nt = blockIdx.x;
  if (mt * 64 >= M) return;
  const f16* Ah_g = (z == 0) ? xhi : caphi;
  const f16* Al_g = (z == 0) ? xlo : caplo;
  __shared__ f16 Ash[64 * 72];
  __shared__ f16 Asl[64 * 72];
  __shared__ f16 Bsh[64 * 72];
  __shared__ f16 Bsl[64 * 72];
  int t = threadIdx.x;
  int wv = t >> 6, lane = t & 63, m16 = lane & 15, quad = lane >> 4;
  int r0 = t >> 3, ak = (t & 7) * 8;
  size_t a0o = (size_t)(mt * 64 + r0) * NDIM;
  size_t a1o = (size_t)(mt * 64 + r0 + 32) * NDIM;
  f32x4 zf = {0.f, 0.f, 0.f, 0.f};
  f32x4 ah[2][2] = {{zf, zf}, {zf, zf}};
  f32x4 am[2][2] = {{zf, zf}, {zf, zf}};
  uint4 rah0, rah1, ral0, ral1;
  float4 rbw[4];
  rah0 = *(const uint4*)(Ah_g + a0o + ak);
  rah1 = *(const uint4*)(Ah_g + a1o + ak);
  ral0 = *(const uint4*)(Al_g + a0o + ak);
  ral1 = *(const uint4*)(Al_g + a1o + ak);
#pragma unroll
  for (int uu = 0; uu < 4; ++uu) {
    int u = t + uu * 256;
    int rr = u >> 4, kp = (u & 15) * 4;
    rbw[uu] = *(const float4*)(inw + (size_t)(z * NDIM + nt * 64 + rr) * NDIM + kp);
  }
  for (int kc = 0; kc < NDIM; kc += 64) {
    __syncthreads();
    *(uint4*)&Ash[r0 * 72 + ak] = rah0;
    *(uint4*)&Ash[(r0 + 32) * 72 + ak] = rah1;
    *(uint4*)&Asl[r0 * 72 + ak] = ral0;
    *(uint4*)&Asl[(r0 + 32) * 72 + ak] = ral1;
#pragma unroll
    for (int uu = 0; uu < 4; ++uu) {
      int u = t + uu * 256;
      int rr = u >> 4, kp = (u & 15) * 4;
      f16x4 hb, lb;
      hb[0] = (f16)rbw[uu].x; lb[0] = (f16)((rbw[uu].x - (float)hb[0]) * 2048.f);
      hb[1] = (f16)rbw[uu].y; lb[1] = (f16)((rbw[uu].y - (float)hb[1]) * 2048.f);
      hb[2] = (f16)rbw[uu].z; lb[2] = (f16)((rbw[uu].z - (float)hb[2]) * 2048.f);
      hb[3] = (f16)rbw[uu].w; lb[3] = (f16)((rbw[uu].w - (float)hb[3]) * 2048.f);
      *(f16x4*)&Bsh[rr * 72 + kp] = hb;
      *(f16x4*)&Bsl[rr * 72 + kp] = lb;
    }
    __syncthreads();
    int kn = kc + 64;
    if (kn < NDIM) {
      rah0 = *(const uint4*)(Ah_g + a0o + kn + ak);
      rah1 = *(const uint4*)(Ah_g + a1o + kn + ak);
      ral0 = *(const uint4*)(Al_g + a0o + kn + ak);
      ral1 = *(const uint4*)(Al_g + a1o + kn + ak);
#pragma unroll
      for (int uu = 0; uu < 4; ++uu) {
        int u = t + uu * 256;
        int rr = u >> 4, kp = (u & 15) * 4;
        rbw[uu] = *(const float4*)(inw + (size_t)(z * NDIM + nt * 64 + rr) * NDIM + kn + kp);
      }
    }
#pragma unroll
    for (int ks = 0; ks < 2; ++ks) {
      int aoff = ((wv & 1) * 32 + m16) * 72 + ks * 32 + quad * 8;
      int boff = ((wv >> 1) * 32 + m16) * 72 + ks * 32 + quad * 8;
      f16x8 a0h = *(const f16x8*)&Ash[aoff];
      f16x8 a1h = *(const f16x8*)&Ash[aoff + 16 * 72];
      f16x8 a0l = *(const f16x8*)&Asl[aoff];
      f16x8 a1l = *(const f16x8*)&Asl[aoff + 16 * 72];
      f16x8 b0h = *(const f16x8*)&Bsh[boff];
      f16x8 b1h = *(const f16x8*)&Bsh[boff + 16 * 72];
      f16x8 b0l = *(const f16x8*)&Bsl[boff];
      f16x8 b1l = *(const f16x8*)&Bsl[boff + 16 * 72];
      ah[0][0] = MFMA16(a0h, b0h, ah[0][0]);
      ah[0][1] = MFMA16(a0h, b1h, ah[0][1]);
      ah[1][0] = MFMA16(a1h, b0h, ah[1][0]);
      ah[1][1] = MFMA16(a1h, b1h, ah[1][1]);
      am[0][0] = MFMA16(a0h, b0l, am[0][0]);
      am[0][1] = MFMA16(a0h, b1l, am[0][1]);
      am[1][0] = MFMA16(a1h, b0l, am[1][0]);
      am[1][1] = MFMA16(a1h, b1l, am[1][1]);
      am[0][0] = MFMA16(a0l, b0h, am[0][0]);
      am[0][1] = MFMA16(a0l, b1h, am[0][1]);
      am[1][0] = MFMA16(a1l, b0h, am[1][0]);
      am[1][1] = MFMA16(a1l, b1h, am[1][1]);
    }
  }
#pragma unroll
  for (int mi = 0; mi < 2; ++mi)
#pragma unroll
    for (int ni = 0; ni < 2; ++ni)
#pragma unroll
      for (int r = 0; r < 4; ++r) {
        int row = mt * 64 + (wv & 1) * 32 + mi * 16 + quad * 4 + r;
        int col = nt * 64 + (wv >> 1) * 32 + ni * 16 + m16;
        float v = ah[mi][ni][r] + am[mi][ni][r] * (1.f / 2048.f) + inb[z * NDIM + col];
        size_t idx = (size_t)row * NDIM + col;
        if (z == 0) {
          f16 hq = (f16)v;
          qhi[idx] = hq;
          qlo[idx] = (f16)((v - (float)hq) * 2048.f);
        } else if (z == 1) {
          f16 hk = (f16)v;
          khi[idx] = hk;
          klo[idx] = (f16)((v - (float)hk) * 2048.f);
        } else {
          f16 hv = (f16)v;
          int bb = row >> 7, kv = row & 127;
          size_t ti = (size_t)(bb * NDIM + col) * NSC + kv;
          vthi[ti] = hv;
          vtlo[ti] = (f16)((v - (float)hv) * 2048.f);
        }
      }
}

// ---------------- fused attention: QK^T + softmax + PV, split-fp16, writes o hi/lo ----
__global__ __launch_bounds__(256) void k_attn(
    const f16* __restrict__ qhi, const f16* __restrict__ qlo,
    const f16* __restrict__ khi, const f16* __restrict__ klo,
    const f16* __restrict__ vthi, const f16* __restrict__ vtlo,
    f16* __restrict__ ohi, f16* __restrict__ olo) {
  int mt = blockIdx.x, bh = blockIdx.y;
  int b = bh >> 3, h = bh & 7;
  __shared__ f16 Ah[64 * 160];
  __shared__ f16 Al[64 * 160];
  __shared__ f16 Bh[32 * 160];
  __shared__ f16 Bl[32 * 160];
  __shared__ f16 Ph[64 * 136];
  __shared__ f16 Pl[64 * 136];
  int t = threadIdx.x;
  int wv = t >> 6, lane = t & 63, m16 = lane & 15, quad = lane >> 4;
  for (int u = t; u < 64 * 20; u += 256) {
    int r = u / 20, kp = (u % 20) * 8;
    uint4 vh = make_uint4(0u, 0u, 0u, 0u), vl = vh;
    if (kp < HDIM) {
      size_t gi = (size_t)(b * NS + mt * 64 + r) * NDIM + h * HDIM + kp;
      vh = *(const uint4*)&qhi[gi];
      vl = *(const uint4*)&qlo[gi];
    }
    *(uint4*)&Ah[r * 160 + kp] = vh;
    *(uint4*)&Al[r * 160 + kp] = vl;
  }
  __syncthreads();
  f16x8 ahf[5], alf[5];
#pragma unroll
  for (int ks = 0; ks < 5; ++ks) {
    int ao = (wv * 16 + m16) * 160 + ks * 32 + quad * 8;
    ahf[ks] = *(const f16x8*)&Ah[ao];
    alf[ks] = *(const f16x8*)&Al[ao];
  }
  f32x4 zf = {0.f, 0.f, 0.f, 0.f};
  f32x4 sh_[4][2], sm_[4][2];
#pragma unroll
  for (int kt = 0; kt < 4; ++kt)
#pragma unroll
    for (int ni = 0; ni < 2; ++ni) { sh_[kt][ni] = zf; sm_[kt][ni] = zf; }
  for (int kt = 0; kt < 4; ++kt) {
    if (kt) __syncthreads();
    for (int u = t; u < 32 * 20; u += 256) {
      int r = u / 20, kp = (u % 20) * 8;
      uint4 vh = make_uint4(0u, 0u, 0u, 0u), vl = vh;
      if (kp < HDIM) {
        size_t gi = (size_t)(b * NSC + kt * 32 + r) * NDIM + h * HDIM + kp;
        vh = *(const uint4*)&khi[gi];
        vl = *(const uint4*)&klo[gi];
      }
      *(uint4*)&Bh[r * 160 + kp] = vh;
      *(uint4*)&Bl[r * 160 + kp] = vl;
    }
    __syncthreads();
#pragma unroll
    for (int ks = 0; ks < 5; ++ks) {
#pragma unroll
      for (int ni = 0; ni < 2; ++ni) {
        int bo = (ni * 16 + m16) * 160 + ks * 32 + quad * 8;
        f16x8 bhf = *(const f16x8*)&Bh[bo];
        f16x8 blf = *(const f16x8*)&Bl[bo];
        sh_[kt][ni] = MFMA16(ahf[ks], bhf, sh_[kt][ni]);
        sm_[kt][ni] = MFMA16(ahf[ks], blf, sm_[kt][ni]);
        sm_[kt][ni] = MFMA16(alf[ks], bhf, sm_[kt][ni]);
      }
    }
  }
  float sv[4][2][4];
  float mx[4] = {-1e30f, -1e30f, -1e30f, -1e30f};
#pragma unroll
  for (int kt = 0; kt < 4; ++kt)
#pragma unroll
    for (int ni = 0; ni < 2; ++ni)
#pragma unroll
      for (int r = 0; r < 4; ++r) {
        float s = (sh_[kt][ni][r] + sm_[kt][ni][r] * (1.f / 2048.f)) * (1.f / 12.f);
        sv[kt][ni][r] = s;
        mx[r] = fmaxf(mx[r], s);
      }
#pragma unroll
  for (int r = 0; r < 4; ++r) {
    mx[r] = fmaxf(mx[r], __shfl_xor(mx[r], 1));
    mx[r] = fmaxf(mx[r], __shfl_xor(mx[r], 2));
    mx[r] = fmaxf(mx[r], __shfl_xor(mx[r], 4));
    mx[r] = fmaxf(mx[r], __shfl_xor(mx[r], 8));
  }
  float sum[4] = {0.f, 0.f, 0.f, 0.f};
#pragma unroll
  for (int kt = 0; kt < 4; ++kt)
#pragma unroll
    for (int ni = 0; ni < 2; ++ni)
#pragma unroll
      for (int r = 0; r < 4; ++r) {
        float e = expf(sv[kt][ni][r] - mx[r]);
        sv[kt][ni][r] = e;
        sum[r] += e;
      }
  float inv[4];
#pragma unroll
  for (int r = 0; r < 4; ++r) {
    sum[r] += __shfl_xor(sum[r], 1);
    sum[r] += __shfl_xor(sum[r], 2);
    sum[r] += __shfl_xor(sum[r], 4);
    sum[r] += __shfl_xor(sum[r], 8);
    inv[r] = 1.0f / sum[r];
  }
#pragma unroll
  for (int kt = 0; kt < 4; ++kt)
#pragma unroll
    for (int ni = 0; ni < 2; ++ni)
#pragma unroll
      for (int r = 0; r < 4; ++r) {
        float p = sv[kt][ni][r] * inv[r];
        int row = wv * 16 + quad * 4 + r;
        int col = kt * 32 + ni * 16 + m16;
        f16 ph = (f16)p;
        Ph[row * 136 + col] = ph;
        Pl[row * 136 + col] = (f16)((p - (float)ph) * 2048.f);
      }
  const f16* vbh = vthi + (size_t)(b * NDIM + h * HDIM) * NSC;
  const f16* vbl = vtlo + (size_t)(b * NDIM + h * HDIM) * NSC;
  f32x4 oh_[9], om_[9];
#pragma unroll
  for (int nb = 0; nb < 9; ++nb) { oh_[nb] = zf; om_[nb] = zf; }
#pragma unroll
  for (int ks = 0; ks < 4; ++ks) {
    int po = (wv * 16 + m16) * 136 + ks * 32 + quad * 8;
    f16x8 pah = *(const f16x8*)&Ph[po];
    f16x8 pal = *(const f16x8*)&Pl[po];
#pragma unroll
    for (int nb = 0; nb < 9; ++nb) {
      size_t vo = (size_t)(nb * 16 + m16) * NSC + ks * 32 + quad * 8;
      f16x8 bvh = *(const f16x8*)&vbh[vo];
      f16x8 bvl = *(const f16x8*)&vbl[vo];
      oh_[nb] = MFMA16(pah, bvh, oh_[nb]);
      om_[nb] = MFMA16(pah, bvl, om_[nb]);
      om_[nb] = MFMA16(pal, bvh, om_[nb]);
    }
  }
#pragma unroll
  for (int nb = 0; nb < 9; ++nb)
#pragma unroll
    for (int r = 0; r < 4; ++r) {
      int row = mt * 64 + wv * 16 + quad * 4 + r;
      int col = h * HDIM + nb * 16 + m16;
      float v = oh_[nb][r] + om_[nb][r] * (1.f / 2048.f);
      size_t idx = (size_t)(b * NS + row) * NDIM + col;
      f16 hv = (f16)v;
      ohi[idx] = hv;
      olo[idx] = (f16)((v - (float)hv) * 2048.f);
    }
}

// ---------------- ca = o @ out_w^T + out_b  (split-fp16, fp32 out), 2-phase prefetch --
__global__ __launch_bounds__(256) void k_ca(
    const f16* __restrict__ ohi, const f16* __restrict__ olo,
    const float* __restrict__ ow, const float* __restrict__ ob,
    float* __restrict__ ca) {
  int mt = blockIdx.y, nt = blockIdx.x;
  __shared__ f16 Ash[64 * 72];
  __shared__ f16 Asl[64 * 72];
  __shared__ f16 Bsh[64 * 72];
  __shared__ f16 Bsl[64 * 72];
  int t = threadIdx.x;
  int wv = t >> 6, lane = t & 63, m16 = lane & 15, quad = lane >> 4;
  int r0 = t >> 3, ak = (t & 7) * 8;
  size_t a0o = (size_t)(mt * 64 + r0) * NDIM;
  size_t a1o = (size_t)(mt * 64 + r0 + 32) * NDIM;
  f32x4 zf = {0.f, 0.f, 0.f, 0.f};
  f32x4 ah[2][2] = {{zf, zf}, {zf, zf}};
  f32x4 am[2][2] = {{zf, zf}, {zf, zf}};
  uint4 rah0, rah1, ral0, ral1;
  float4 rbw[4];
  rah0 = *(const uint4*)(ohi + a0o + ak);
  rah1 = *(const uint4*)(ohi + a1o + ak);
  ral0 = *(const uint4*)(olo + a0o + ak);
  ral1 = *(const uint4*)(olo + a1o + ak);
#pragma unroll
  for (int uu = 0; uu < 4; ++uu) {
    int u = t + uu * 256;
    int rr = u >> 4, kp = (u & 15) * 4;
    rbw[uu] = *(const float4*)(ow + (size_t)(nt * 64 + rr) * NDIM + kp);
  }
  for (int kc = 0; kc < NDIM; kc += 64) {
    __syncthreads();
    *(uint4*)&Ash[r0 * 72 + ak] = rah0;
    *(uint4*)&Ash[(r0 + 32) * 72 + ak] = rah1;
    *(uint4*)&Asl[r0 * 72 + ak] = ral0;
    *(uint4*)&Asl[(r0 + 32) * 72 + ak] = ral1;
#pragma unroll
    for (int uu = 0; uu < 4; ++uu) {
      int u = t + uu * 256;
      int rr = u >> 4, kp = (u & 15) * 4;
      f16x4 hb, lb;
      hb[0] = (f16)rbw[uu].x; lb[0] = (f16)((rbw[uu].x - (float)hb[0]) * 2048.f);
      hb[1] = (f16)rbw[uu].y; lb[1] = (f16)((rbw[uu].y - (float)hb[1]) * 2048.f);
      hb[2] = (f16)rbw[uu].z; lb[2] = (f16)((rbw[uu].z - (float)hb[2]) * 2048.f);
      hb[3] = (f16)rbw[uu].w; lb[3] = (f16)((rbw[uu].w - (float)hb[3]) * 2048.f);
      *(f16x4*)&Bsh[rr * 72 + kp] = hb;
      *(f16x4*)&Bsl[rr * 72 + kp] = lb;
    }
    __syncthreads();
    int kn = kc + 64;
    if (kn < NDIM) {
      rah0 = *(const uint4*)(ohi + a0o + kn + ak);
      rah1 = *(const uint4*)(ohi + a1o + kn + ak);
      ral0 = *(const uint4*)(olo + a0o + kn + ak);
      ral1 = *(const uint4*)(olo + a1o + kn + ak);
#pragma unroll
      for (int uu = 0; uu < 4; ++uu) {
        int u = t + uu * 256;
        int rr = u >> 4, kp = (u & 15) * 4;
        rbw[uu] = *(const float4*)(ow + (size_t)(nt * 64 + rr) * NDIM + kn + kp);
      }
    }
#pragma unroll
    for (int ks = 0; ks < 2; ++ks) {
      int aoff = ((wv & 1) * 32 + m16) * 72 + ks * 32 + quad * 8;
      int boff = ((wv >> 1) * 32 + m16) * 72 + ks * 32 + quad * 8;
      f16x8 a0h = *(const f16x8*)&Ash[aoff];
      f16x8 a1h = *(const f16x8*)&Ash[aoff + 16 * 72];
      f16x8 a0l = *(const f16x8*)&Asl[aoff];
      f16x8 a1l = *(const f16x8*)&Asl[aoff + 16 * 72];
      f16x8 b0h = *(const f16x8*)&Bsh[boff];
      f16x8 b1h = *(const f16x8*)&Bsh[boff + 16 * 72];
      f16x8 b0l = *(const f16x8*)&Bsl[boff];
      f16x8 b1l = *(const f16x8*)&Bsl[boff + 16 * 72];
      ah[0][0] = MFMA16(a0h, b0h, ah[0][0]);
      ah[0][1] = MFMA16(a0h, b1h, ah[0][1]);
      ah[1][0] = MFMA16(a1h, b0h, ah[1][0]);
      ah[1][1] = MFMA16(a1h, b1h, ah[1][1]);
      am[0][0] = MFMA16(a0h, b0l, am[0][0]);
      am[0][1] = MFMA16(a0h, b1l, am[0][1]);
      am[1][0] = MFMA16(a1h, b0l, am[1][0]);
      am[1][1] = MFMA16(a1h, b1l, am[1][1]);
      am[0][0] = MFMA16(a0l, b0h, am[0][0]);
      am[0][1] = MFMA16(a0l, b1h, am[0][1]);
      am[1][0] = MFMA16(a1l, b0h, am[1][0]);
      am[1][1] = MFMA16(a1l, b1h, am[1][1]);
    }
  }
#pragma unroll
  for (int mi = 0; mi < 2; ++mi)
#pragma unroll
    for (int ni = 0; ni < 2; ++ni)
#pragma unroll
      for (int r = 0; r < 4; ++r) {
        int row = mt * 64 + (wv & 1) * 32 + mi * 16 + quad * 4 + r;
        int col = nt * 64 + (wv >> 1) * 32 + ni * 16 + m16;
        ca[(size_t)row * NDIM + col] =
            ah[mi][ni][r] + am[mi][ni][r] * (1.f / 2048.f) + ob[col];
      }
}

// ---------------- routing: argmax gates, cm/am, lists, loss ----------------
__global__ __launch_bounds__(1024) void k_route(
    const float* __restrict__ cl, const float* __restrict__ al,
    const float* __restrict__ g1, const float* __restrict__ g2,
    const float* __restrict__ g3, const float* __restrict__ tl,
    float* __restrict__ cmv, float* __restrict__ amv,
    int* __restrict__ lists, int* __restrict__ counts, float* __restrict__ out_loss) {
  __shared__ int lcnt[8];
  __shared__ float bins[8];
  __shared__ float ssum[2];
  int t = threadIdx.x;
  if (t < 8) { lcnt[t] = 0; bins[t] = 0.f; }
  if (t < 2) ssum[t] = 0.f;
  __syncthreads();
  for (int n = t; n < NTOK; n += 1024) {
    float lc[NEXP];
#pragma unroll
    for (int e = 0; e < NEXP; ++e) lc[e] = cl[n * NEXP + e] + g2[n * 4 + e];
    int ec = 0; float bv = lc[0];
#pragma unroll
    for (int e = 1; e < NEXP; ++e) if (lc[e] > bv) { bv = lc[e]; ec = e; }
    float la[NEXP];
#pragma unroll
    for (int e = 0; e < NEXP; ++e) la[e] = al[n * NEXP + e] + g3[n * 4 + e];
    int ea = 0; float bva = la[0];
#pragma unroll
    for (int e = 1; e < NEXP; ++e) if (la[e] > bva) { bva = la[e]; ea = e; }
    int b = n >> 10;
    float a0 = tl[b * 2 + 0] + g1[n * 2 + 0];
    float a1 = tl[b * 2 + 1] + g1[n * 2 + 1];
    float mx = fmaxf(a0, a1);
    float e0 = expf(a0 - mx), e1 = expf(a1 - mx);
    float cm = e0 / (e0 + e1), am = e1 / (e0 + e1);
    cmv[n] = cm; amv[n] = am;
    int p0 = atomicAdd(&lcnt[ec], 1);
    lists[ec * NTOK + p0] = n;
    int p1 = atomicAdd(&lcnt[4 + ea], 1);
    lists[(4 + ea) * NTOK + p1] = n;
    atomicAdd(&bins[ec], cm);
    atomicAdd(&bins[4 + ea], am);
    atomicAdd(&ssum[0], cm);
    atomicAdd(&ssum[1], am);
  }
  __syncthreads();
  if (t < 8) counts[t] = lcnt[t];
  if (t == 0) {
    float denom = 4.f * (ssum[0] + ssum[1]) + 1e-10f;
    float acc = 0.f;
    for (int j = 0; j < 8; ++j) {
      float u = bins[j] / denom;
      acc += u * logf(u + 1e-10f);
    }
    out_loss[0] = acc / 8.f;
  }
}

// ---------------- GEMM1: M64, f16 weights, XCD-grouped remap, 2-phase prefetch --------
__global__ __launch_bounds__(256) void k_gemm1(
    const f16* __restrict__ x16, const f16* __restrict__ y16,
    const f16* __restrict__ wf,
    const int* __restrict__ lists, const int* __restrict__ counts,
    f16* __restrict__ tbuf, int gbase, int G) {
  int bid = blockIdx.x;
  int xcd = bid & 7;
  int local = bid >> 3;
  int ppx = (G * 12) >> 3;               // pairs per xcd (8->12, 4->6)
  int pair = xcd * ppx + (local >> 5);   // MT = 32
  int mt = local & 31;
  int g = gbase + pair / 12;
  int nt = pair % 12;
  const f16* A; const f16* B1; const f16* B3; f16* tout;
  const int* list = nullptr;
  int cnt, koff, K;
  if (g < 8) {
    int e = g & 3;
    cnt = counts[g];
    list = lists + g * NTOK;
    A = x16; koff = 0; K = NDIM;
    B1 = wf + (size_t)((g < 4) ? 0 : 2) * WSZ + (size_t)e * NHID * NDIM;
    B3 = wf + (size_t)((g < 4) ? 1 : 3) * WSZ + (size_t)e * NHID * NDIM;
    tout = tbuf + (size_t)g * NTOK * NHID;
  } else {
    int e = g - 8;
    cnt = NTOK;
    A = y16; koff = e * 288; K = 288;
    B1 = wf + (size_t)4 * WSZ + (size_t)e * NHID * NDIM + koff;
    B3 = wf + (size_t)5 * WSZ + (size_t)e * NHID * NDIM + koff;
    tout = tbuf + (size_t)e * NTOK * NHID;
  }
  if (mt * 64 >= cnt) return;
  int t = threadIdx.x;
  int wv = t >> 6, lane = t & 63, m16 = lane & 15, quad = lane >> 4;
  int r0 = t >> 3, ak = (t & 7) * 8;
  int m0 = mt * 64 + r0, m1 = m0 + 32;
  int tok0, tok1;
  if (list) { tok0 = list[min(m0, cnt - 1)]; tok1 = list[min(m1, cnt - 1)]; }
  else { tok0 = m0; tok1 = m1; }
  const f16* ar0 = A + (size_t)tok0 * NDIM + koff;
  const f16* ar1 = A + (size_t)tok1 * NDIM + koff;
  const f16* b1r0 = B1 + (size_t)(nt * 64 + r0) * NDIM;
  const f16* b1r1 = B1 + (size_t)(nt * 64 + r0 + 32) * NDIM;
  const f16* b3r0 = B3 + (size_t)(nt * 64 + r0) * NDIM;
  const f16* b3r1 = B3 + (size_t)(nt * 64 + r0 + 32) * NDIM;
  __shared__ f16 As[64 * 72];
  __shared__ f16 Bs1[64 * 72];
  __shared__ f16 Bs2[64 * 72];
  f32x4 zf = {0.f, 0.f, 0.f, 0.f};
  f32x4 ac1[2][2] = {{zf, zf}, {zf, zf}};
  f32x4 ac2[2][2] = {{zf, zf}, {zf, zf}};
  uint4 z4u = make_uint4(0u, 0u, 0u, 0u);
  uint4 ra0, ra1, rb10, rb11, rb30, rb31;
  {
    bool v = (ak < K);
    ra0  = v ? *(const uint4*)(ar0 + ak) : z4u;
    ra1  = v ? *(const uint4*)(ar1 + ak) : z4u;
    rb10 = v ? *(const uint4*)(b1r0 + ak) : z4u;
    rb11 = v ? *(const uint4*)(b1r1 + ak) : z4u;
    rb30 = v ? *(const uint4*)(b3r0 + ak) : z4u;
    rb31 = v ? *(const uint4*)(b3r1 + ak) : z4u;
  }
  for (int kc = 0; kc < K; kc += 64) {
    __syncthreads();
    *(uint4*)&As[r0 * 72 + ak] = ra0;
    *(uint4*)&As[(r0 + 32) * 72 + ak] = ra1;
    *(uint4*)&Bs1[r0 * 72 + ak] = rb10;
    *(uint4*)&Bs1[(r0 + 32) * 72 + ak] = rb11;
    *(uint4*)&Bs2[r0 * 72 + ak] = rb30;
    *(uint4*)&Bs2[(r0 + 32) * 72 + ak] = rb31;
    __syncthreads();
    int kn = kc + 64;
    if (kn < K) {
      bool v = (kn + ak < K);
      ra0  = v ? *(const uint4*)(ar0 + kn + ak) : z4u;
      ra1  = v ? *(const uint4*)(ar1 + kn + ak) : z4u;
      rb10 = v ? *(const uint4*)(b1r0 + kn + ak) : z4u;
      rb11 = v ? *(const uint4*)(b1r1 + kn + ak) : z4u;
      rb30 = v ? *(const uint4*)(b3r0 + kn + ak) : z4u;
      rb31 = v ? *(const uint4*)(b3r1 + kn + ak) : z4u;
    }
#pragma unroll
    for (int ks = 0; ks < 2; ++ks) {
      int aoff = ((wv & 1) * 32 + m16) * 72 + ks * 32 + quad * 8;
      int boff = ((wv >> 1) * 32 + m16) * 72 + ks * 32 + quad * 8;
      f16x8 a0 = *(const f16x8*)&As[aoff];
      f16x8 a1 = *(const f16x8*)&As[aoff + 16 * 72];
      f16x8 b10 = *(const f16x8*)&Bs1[boff];
      f16x8 b11 = *(const f16x8*)&Bs1[boff + 16 * 72];
      f16x8 b30 = *(const f16x8*)&Bs2[boff];
      f16x8 b31 = *(const f16x8*)&Bs2[boff + 16 * 72];
      ac1[0][0] = MFMA16(a0, b10, ac1[0][0]);
      ac1[0][1] = MFMA16(a0, b11, ac1[0][1]);
      ac1[1][0] = MFMA16(a1, b10, ac1[1][0]);
      ac1[1][1] = MFMA16(a1, b11, ac1[1][1]);
      ac2[0][0] = MFMA16(a0, b30, ac2[0][0]);
      ac2[0][1] = MFMA16(a0, b31, ac2[0][1]);
      ac2[1][0] = MFMA16(a1, b30, ac2[1][0]);
      ac2[1][1] = MFMA16(a1, b31, ac2[1][1]);
    }
  }
#pragma unroll
  for (int mi = 0; mi < 2; ++mi)
#pragma unroll
    for (int ni = 0; ni < 2; ++ni)
#pragma unroll
      for (int r = 0; r < 4; ++r) {
        int row = mt * 64 + (wv & 1) * 32 + mi * 16 + quad * 4 + r;
        int col = nt * 64 + (wv >> 1) * 32 + ni * 16 + m16;
        float h1 = ac1[mi][ni][r];
        float h3 = ac2[mi][ni][r];
        float sl = h1 / (1.0f + expf(-h1));
        tout[(size_t)row * NHID + col] = (f16)(sl * h3);
      }
}

// ---------------- GEMM2 (MoE): f16 weights, XCD-grouped remap, 2-phase ----------------
__global__ __launch_bounds__(256) void k_gemm2(
    const f16* __restrict__ tbuf, const f16* __restrict__ wf,
    const int* __restrict__ lists, const int* __restrict__ counts,
    const float* __restrict__ cmv, const float* __restrict__ amv,
    float* __restrict__ yc, float* __restrict__ ya) {
  int bid = blockIdx.x;
  int xcd = bid & 7;
  int local = bid >> 3;
  int pair = xcd * 18 + (local >> 5);
  int mt = local & 31;
  int g = pair / 18;
  int nt = pair % 18;
  int e = g & 3;
  int cnt = counts[g];
  if (mt * 64 >= cnt) return;
  const int* list = lists + g * NTOK;
  const f16* A = tbuf + (size_t)g * NTOK * NHID;
  const f16* Bw = wf + (size_t)((g < 4) ? 6 : 7) * WSZ + (size_t)e * NDIM * NHID;
  const float* sc = (g < 4) ? cmv : amv;
  float* y = (g < 4) ? yc : ya;
  int t = threadIdx.x;
  int wv = t >> 6, lane = t & 63, m16 = lane & 15, quad = lane >> 4;
  int r0 = t >> 3, ak = (t & 7) * 8;
  const f16* ar0 = A + (size_t)(mt * 64 + r0) * NHID;
  const f16* ar1 = A + (size_t)(mt * 64 + r0 + 32) * NHID;
  const f16* br0 = Bw + (size_t)(nt * 64 + r0) * NHID;
  const f16* br1 = Bw + (size_t)(nt * 64 + r0 + 32) * NHID;
  __shared__ f16 As[64 * 72];
  __shared__ f16 Bs[64 * 72];
  f32x4 zf = {0.f, 0.f, 0.f, 0.f};
  f32x4 acc[2][2] = {{zf, zf}, {zf, zf}};
  uint4 ra0, ra1, rb0, rb1;
  ra0 = *(const uint4*)(ar0 + ak);
  ra1 = *(const uint4*)(ar1 + ak);
  rb0 = *(const uint4*)(br0 + ak);
  rb1 = *(const uint4*)(br1 + ak);
  for (int kc = 0; kc < NHID; kc += 64) {
    __syncthreads();
    *(uint4*)&As[r0 * 72 + ak] = ra0;
    *(uint4*)&As[(r0 + 32) * 72 + ak] = ra1;
    *(uint4*)&Bs[r0 * 72 + ak] = rb0;
    *(uint4*)&Bs[(r0 + 32) * 72 + ak] = rb1;
    __syncthreads();
    int kn = kc + 64;
    if (kn < NHID) {
      ra0 = *(const uint4*)(ar0 + kn + ak);
      ra1 = *(const uint4*)(ar1 + kn + ak);
      rb0 = *(const uint4*)(br0 + kn + ak);
      rb1 = *(const uint4*)(br1 + kn + ak);
    }
#pragma unroll
    for (int ks = 0; ks < 2; ++ks) {
      int aoff = ((wv & 1) * 32 + m16) * 72 + ks * 32 + quad * 8;
      int boff = ((wv >> 1) * 32 + m16) * 72 + ks * 32 + quad * 8;
      f16x8 a0 = *(const f16x8*)&As[aoff];
      f16x8 a1 = *(const f16x8*)&As[aoff + 16 * 72];
      f16x8 b0 = *(const f16x8*)&Bs[boff];
      f16x8 b1 = *(const f16x8*)&Bs[boff + 16 * 72];
      acc[0][0] = MFMA16(a0, b0, acc[0][0]);
      acc[0][1] = MFMA16(a0, b1, acc[0][1]);
      acc[1][0] = MFMA16(a1, b0, acc[1][0]);
      acc[1][1] = MFMA16(a1, b1, acc[1][1]);
    }
  }
#pragma unroll
  for (int mi = 0; mi < 2; ++mi)
#pragma unroll
    for (int ni = 0; ni < 2; ++ni)
#pragma unroll
      for (int r = 0; r < 4; ++r) {
        int mg = mt * 64 + (wv & 1) * 32 + mi * 16 + quad * 4 + r;
        if (mg < cnt) {
          int tok = list[mg];
          int col = nt * 64 + (wv >> 1) * 32 + ni * 16 + m16;
          float v = acc[mi][ni][r] * sc[tok];
          y[(size_t)tok * NDIM + col] = v;
        }
      }
}

// ---------------- GEMM2 (fr): f16 weights, t16 @ fr_w2 slice -> z, 2-phase ------------
__global__ __launch_bounds__(256) void k_gemm2_fr(
    const f16* __restrict__ tbuf, const f16* __restrict__ wf, float* __restrict__ zz) {
  int e = blockIdx.z;
  int mt = blockIdx.y, nt = blockIdx.x;
  const f16* A = tbuf + (size_t)e * NTOK * NHID;
  const f16* Bw = wf + (size_t)8 * WSZ + (size_t)e * NDIM * NHID;
  int t = threadIdx.x;
  int wv = t >> 6, lane = t & 63, m16 = lane & 15, quad = lane >> 4;
  int r0 = t >> 3, ak = (t & 7) * 8;
  const f16* ar0 = A + (size_t)(mt * 64 + r0) * NHID;
  const f16* ar1 = A + (size_t)(mt * 64 + r0 + 32) * NHID;
  int ne0 = min(nt * 64 + r0, 287), ne1 = min(nt * 64 + r0 + 32, 287);
  const f16* br0 = Bw + (size_t)(e * 288 + ne0) * NHID;
  const f16* br1 = Bw + (size_t)(e * 288 + ne1) * NHID;
  __shared__ f16 As[64 * 72];
  __shared__ f16 Bs[64 * 72];
  f32x4 zf = {0.f, 0.f, 0.f, 0.f};
  f32x4 acc[2][2] = {{zf, zf}, {zf, zf}};
  uint4 ra0, ra1, rb0, rb1;
  ra0 = *(const uint4*)(ar0 + ak);
  ra1 = *(const uint4*)(ar1 + ak);
  rb0 = *(const uint4*)(br0 + ak);
  rb1 = *(const uint4*)(br1 + ak);
  for (int kc = 0; kc < NHID; kc += 64) {
    __syncthreads();
    *(uint4*)&As[r0 * 72 + ak] = ra0;
    *(uint4*)&As[(r0 + 32) * 72 + ak] = ra1;
    *(uint4*)&Bs[r0 * 72 + ak] = rb0;
    *(uint4*)&Bs[(r0 + 32) * 72 + ak] = rb1;
    __syncthreads();
    int kn = kc + 64;
    if (kn < NHID) {
      ra0 = *(const uint4*)(ar0 + kn + ak);
      ra1 = *(const uint4*)(ar1 + kn + ak);
      rb0 = *(const uint4*)(br0 + kn + ak);
      rb1 = *(const uint4*)(br1 + kn + ak);
    }
#pragma unroll
    for (int ks = 0; ks < 2; ++ks) {
      int aoff = ((wv & 1) * 32 + m16) * 72 + ks * 32 + quad * 8;
      int boff = ((wv >> 1) * 32 + m16) * 72 + ks * 32 + quad * 8;
      f16x8 a0 = *(const f16x8*)&As[aoff];
      f16x8 a1 = *(const f16x8*)&As[aoff + 16 * 72];
      f16x8 b0 = *(const f16x8*)&Bs[boff];
      f16x8 b1 = *(const f16x8*)&Bs[boff + 16 * 72];
      acc[0][0] = MFMA16(a0, b0, acc[0][0]);
      acc[0][1] = MFMA16(a0, b1, acc[0][1]);
      acc[1][0] = MFMA16(a1, b0, acc[1][0]);
      acc[1][1] = MFMA16(a1, b1, acc[1][1]);
    }
  }
#pragma unroll
  for (int mi = 0; mi < 2; ++mi)
#pragma unroll
    for (int ni = 0; ni < 2; ++ni)
#pragma unroll
      for (int r = 0; r < 4; ++r) {
        int cg = nt * 64 + (wv >> 1) * 32 + ni * 16 + m16;
        if (cg < 288) {
          int row = mt * 64 + (wv & 1) * 32 + mi * 16 + quad * 4 + r;
          zz[(size_t)row * NDIM + e * 288 + cg] = acc[mi][ni][r];
        }
      }
}

// ---------------- host ----------------
extern "C" void kernel_launch(void* const* d_in, const int* in_sizes, int n_in,
                              void* d_out, int out_size, void* d_ws, size_t ws_size,
                              hipStream_t stream) {
  const float* x          = (const float*)d_in[0];
  const float* timep      = (const float*)d_in[1];
  const float* caption    = (const float*)d_in[2];
  const float* acoustic   = (const float*)d_in[3];
  const float* attn_in_w  = (const float*)d_in[4];
  const float* attn_in_b  = (const float*)d_in[5];
  const float* attn_out_w = (const float*)d_in[6];
  const float* attn_out_b = (const float*)d_in[7];
  const float* hl_w       = (const float*)d_in[8];
  const float* hl_b       = (const float*)d_in[9];
  const float* cap_gate_w = (const float*)d_in[10];
  const float* cap_gate_b = (const float*)d_in[11];
  const float* ac_gate_w  = (const float*)d_in[12];
  const float* ac_gate_b  = (const float*)d_in[13];
  const float* cap_w1     = (const float*)d_in[14];
  const float* cap_w2     = (const float*)d_in[15];
  const float* cap_w3     = (const float*)d_in[16];
  const float* ac_w1      = (const float*)d_in[17];
  const float* ac_w2      = (const float*)d_in[18];
  const float* ac_w3      = (const float*)d_in[19];
  const float* fr_w1      = (const float*)d_in[20];
  const float* fr_w2      = (const float*)d_in[21];
  const float* fr_w3      = (const float*)d_in[22];
  (void)in_sizes; (void)n_in; (void)out_size; (void)ws_size;

  float* zout = (float*)d_out;
  float* loss = zout + (size_t)NTOK * NDIM;

  char* wsb = (char*)d_ws;
  size_t off = 0;
  auto alloc = [&](size_t bytes) -> void* {
    void* p = wsb + off;
    off = (off + bytes + 255) & ~(size_t)255;
    return p;
  };
  // persistent small + xhi + converted weights
  float* g1     = (float*)alloc(4096 * 4);
  float* g2     = (float*)alloc(8192 * 4);
  float* g3     = (float*)alloc(8192 * 4);
  float* tl     = (float*)alloc(4 * 4);
  float* al     = (float*)alloc((size_t)NTOK * NEXP * 4);
  float* cl     = (float*)alloc((size_t)NTOK * NEXP * 4);
  float* cmv    = (float*)alloc((size_t)NTOK * 4);
  float* amv    = (float*)alloc((size_t)NTOK * 4);
  int*   lists  = (int*)alloc((size_t)8 * NTOK * 4);
  int*   counts = (int*)alloc(8 * 4);
  f16*   xhi    = (f16*)alloc((size_t)NTOK * NDIM * 2);
  f16*   wf16   = (f16*)alloc((size_t)9 * WSZ * 2);
  size_t region = off;
  // phase 1 (attention / routing inputs)
  f16*   xlo    = (f16*)alloc((size_t)NTOK * NDIM * 2);
  f16*   caphi  = (f16*)alloc((size_t)NCAP * NDIM * 2);
  f16*   caplo  = (f16*)alloc((size_t)NCAP * NDIM * 2);
  f16*   qhi    = (f16*)alloc((size_t)NTOK * NDIM * 2);
  f16*   qlo    = (f16*)alloc((size_t)NTOK * NDIM * 2);
  f16*   khi    = (f16*)alloc((size_t)NCAP * NDIM * 2);
  f16*   klo    = (f16*)alloc((size_t)NCAP * NDIM * 2);
  f16*   vthi   = (f16*)alloc((size_t)NB * NDIM * NSC * 2);
  f16*   vtlo   = (f16*)alloc((size_t)NB * NDIM * NSC * 2);
  f16*   ohi    = (f16*)alloc((size_t)NTOK * NDIM * 2);
  f16*   olo    = (f16*)alloc((size_t)NTOK * NDIM * 2);
  float* ca32   = (float*)alloc((size_t)NTOK * NDIM * 4);
  // phase 2 (MoE / fr) — reuses phase-1 region (all phase-1 buffers dead)
  off = region;
  f16*   tbuf   = (f16*)alloc((size_t)8 * NTOK * NHID * 2);
  float* ybc    = (float*)alloc((size_t)NTOK * NDIM * 4);
  float* yba    = (float*)alloc((size_t)NTOK * NDIM * 4);
  f16*   y16    = (f16*)alloc((size_t)NTOK * NDIM * 2);

  k_prep<<<dim3(1), dim3(256), 0, stream>>>(timep, hl_w, hl_b, g1, g2, g3, tl);
  k_ac_logits<<<dim3(512), dim3(256), 0, stream>>>(acoustic, ac_gate_w, ac_gate_b, al);
  k_cvt_split<<<dim3(2304), dim3(256), 0, stream>>>(x, xhi, xlo, NTOK * NDIM);
  k_cvt_split<<<dim3(288), dim3(256), 0, stream>>>(caption, caphi, caplo, NCAP * NDIM);
  // fused: QKV projection (z<3) + 9-tensor weight f32->f16 conversion (z>=3)
  k_gemm_qkv<<<dim3(18, 32, 3 + CVT_ZS), dim3(256), 0, stream>>>(
      xhi, xlo, caphi, caplo, attn_in_w, attn_in_b,
      qhi, qlo, khi, klo, vthi, vtlo,
      cap_w1, cap_w3, ac_w1, ac_w3, fr_w1, fr_w3, cap_w2, ac_w2, fr_w2, wf16);
  k_attn<<<dim3(16, 16), dim3(256), 0, stream>>>(qhi, qlo, khi, klo, vthi, vtlo, ohi, olo);
  k_ca<<<dim3(18, 32), dim3(256), 0, stream>>>(ohi, olo, attn_out_w, attn_out_b, ca32);
  k_ac_logits<<<dim3(512), dim3(256), 0, stream>>>(ca32, cap_gate_w, cap_gate_b, cl);
  k_route<<<dim3(1), dim3(1024), 0, stream>>>(cl, al, g1, g2, g3, tl,
                                              cmv, amv, lists, counts, loss);
  k_gemm1<<<dim3(3072), dim3(256), 0, stream>>>(xhi, y16, wf16, lists, counts, tbuf, 0, 8);
  k_gemm2<<<dim3(4608), dim3(256), 0, stream>>>(tbuf, wf16, lists, counts,
                                                cmv, amv, ybc, yba);
  k_cvt_add<<<dim3(2304), dim3(256), 0, stream>>>(ybc, yba, y16, NTOK * NDIM);
  k_gemm1<<<dim3(1536), dim3(256), 0, stream>>>(xhi, y16, wf16, lists, counts, tbuf, 8, 4);
  k_gemm2_fr<<<dim3(5, 32, 4), dim3(256), 0, stream>>>(tbuf, wf16, zout);
}